// Round 1
// baseline (1825.706 us; speedup 1.0000x reference)
//
#include <hip/hip_runtime.h>

namespace {

constexpr int THREADS = 256;
constexpr int HdC = 64, WdC = 96, HuC = 128, WuC = 192;

constexpr int CTX_S = 80;   // ctxT[128][80]  (72 rows + pad)
constexpr int KV_S  = 132;  // kvb[72][132]
constexpr int XS_S  = 132;  // xs[32][132]
constexpr int XN_S  = 32;   // xnT[128][32]
constexpr int OB_S  = 144;  // outb[32][144]

// scratch layout (floats); regions are time-disjoint where they overlap
constexpr int SC_ATT = 0;     // [32][4][9] = 1152 attn probs
constexpr int SC_RED = 0;     // 768 LN partials
constexpr int SC_MU  = 768;   // 96
constexpr int SC_RS  = 864;   // 96
constexpr int SC_NC  = 1152;  // 256 (ncw[128], ncb[128])
constexpr int SC_LG  = 0;     // [32][12] final logits

struct alignas(16) Smem {
  float ctxT[128 * CTX_S];
  float kvb[72 * KV_S];
  float xs[32 * XS_S];
  float xnT[128 * XN_S];
  float outb[32 * OB_S];
  float wbuf[32 * 128];
  float scratch[1536];
};
static_assert(sizeof(Smem) <= 160 * 1024, "LDS budget");

__device__ __forceinline__ float gelu_tanh(float x) {
  float z = 0.7978845608028654f * (x + 0.044715f * x * x * x);
  float e = __expf(2.0f * z);
  float t = 1.0f - 2.0f / (e + 1.0f);
  return 0.5f * x * (1.0f + t);
}

__device__ __forceinline__ void stage_w(const float* __restrict__ W, int wstride,
                                        int kc, float* wbuf, int tid) {
#pragma unroll
  for (int p = 0; p < 4; ++p) {
    int e = tid + p * THREADS;      // 0..1023 float4 slots
    int r = e >> 5;                 // 0..31
    int c4 = (e & 31) << 2;         // 0..124
    const float4 v = *reinterpret_cast<const float4*>(W + (kc * 32 + r) * wstride + c4);
    *reinterpret_cast<float4*>(wbuf + r * 128 + c4) = v;
  }
}

#define FMA_ROW(ac, s, w)                                            \
  {                                                                  \
    (ac)[0] += (s) * (w).x; (ac)[1] += (s) * (w).y;                  \
    (ac)[2] += (s) * (w).z; (ac)[3] += (s) * (w).w;                  \
  }

// acc[16] = A(32x128; AT in LDS, [c][row], stride XN_S) @ W(128x128, row stride wstride)
__device__ __forceinline__ void gemm32(const float* __restrict__ W, int wstride,
                                       const float* AT, float* wbuf, int tid,
                                       float acc[16]) {
  const int row0 = (tid >> 5) << 2;
  const int col0 = (tid & 31) << 2;
#pragma unroll
  for (int i = 0; i < 16; ++i) acc[i] = 0.f;
  for (int kc = 0; kc < 4; ++kc) {
    __syncthreads();
    stage_w(W, wstride, kc, wbuf, tid);
    __syncthreads();
#pragma unroll 4
    for (int cl = 0; cl < 32; ++cl) {
      const int c = (kc << 5) + cl;
      const float4 a = *reinterpret_cast<const float4*>(AT + c * XN_S + row0);
      const float4 w = *reinterpret_cast<const float4*>(wbuf + cl * 128 + col0);
      FMA_ROW(acc + 0, a.x, w);
      FMA_ROW(acc + 4, a.y, w);
      FMA_ROW(acc + 8, a.z, w);
      FMA_ROW(acc + 12, a.w, w);
    }
  }
}

// ctx rows (72, padded to 96 tiles) @ W(128x128) -> kvb (+bias). NC: apply nc_w/nc_b to A.
template <bool NC>
__device__ __forceinline__ void gemm96(const float* __restrict__ W, int wstride,
                                       const float* ctxT, float* wbuf, float* kvb,
                                       const float* __restrict__ bias,
                                       const float* nc, int tid) {
  const int rt4 = (tid >> 5) << 2;   // 0..28
  const int col0 = (tid & 31) << 2;
  float acc[48];
#pragma unroll
  for (int i = 0; i < 48; ++i) acc[i] = 0.f;
  for (int kc = 0; kc < 4; ++kc) {
    __syncthreads();
    stage_w(W, wstride, kc, wbuf, tid);
    __syncthreads();
#pragma unroll 2
    for (int cl = 0; cl < 32; ++cl) {
      const int c = (kc << 5) + cl;
      const float4 w = *reinterpret_cast<const float4*>(wbuf + cl * 128 + col0);
      float s = 0.f, t = 0.f;
      if (NC) { s = nc[c]; t = nc[128 + c]; }
      const float* base = ctxT + c * CTX_S;
#pragma unroll
      for (int p = 0; p < 3; ++p) {
        int r0 = p * 32 + rt4;
        if (r0 > 76) r0 = 76;  // clamp into allocated pad; results discarded
        float4 a = *reinterpret_cast<const float4*>(base + r0);
        if (NC) {
          a.x = a.x * s + t; a.y = a.y * s + t;
          a.z = a.z * s + t; a.w = a.w * s + t;
        }
        float* ac = acc + p * 16;
        FMA_ROW(ac + 0, a.x, w);
        FMA_ROW(ac + 4, a.y, w);
        FMA_ROW(ac + 8, a.z, w);
        FMA_ROW(ac + 12, a.w, w);
      }
    }
  }
  const float4 bv = *reinterpret_cast<const float4*>(bias + col0);
#pragma unroll
  for (int p = 0; p < 3; ++p) {
    const int r0 = p * 32 + rt4;
    if (r0 < 72) {
#pragma unroll
      for (int i = 0; i < 4; ++i) {
        float4 o;
        o.x = acc[p * 16 + i * 4 + 0] + bv.x;
        o.y = acc[p * 16 + i * 4 + 1] + bv.y;
        o.z = acc[p * 16 + i * 4 + 2] + bv.z;
        o.w = acc[p * 16 + i * 4 + 3] + bv.w;
        *reinterpret_cast<float4*>(kvb + (r0 + i) * KV_S + col0) = o;
      }
    }
  }
}

// LN over c of xs rows -> xnT (transposed, no affine)
__device__ __forceinline__ void layernorm_x(const float* xs, float* xnT,
                                            float* scratch, int tid) {
  const int px = tid & 31;
  const int cg = tid >> 5;
  float s1 = 0.f, s2 = 0.f;
#pragma unroll
  for (int i = 0; i < 16; ++i) {
    const float v = xs[px * XS_S + cg * 16 + i];
    s1 += v; s2 += v * v;
  }
  scratch[SC_RED + cg * 96 + px] = s1;
  scratch[SC_RED + cg * 96 + 48 + px] = s2;
  __syncthreads();
  if (tid < 32) {
    float a = 0.f, b = 0.f;
#pragma unroll
    for (int g = 0; g < 8; ++g) {
      a += scratch[SC_RED + g * 96 + tid];
      b += scratch[SC_RED + g * 96 + 48 + tid];
    }
    const float m = a * (1.f / 128.f);
    const float v = b * (1.f / 128.f) - m * m;
    scratch[SC_MU + tid] = m;
    scratch[SC_RS + tid] = rsqrtf(v + 1e-6f);
  }
  __syncthreads();
  const float m = scratch[SC_MU + px];
  const float r = scratch[SC_RS + px];
#pragma unroll
  for (int i = 0; i < 16; ++i) {
    const int c = cg * 16 + i;
    xnT[c * XN_S + px] = (xs[px * XS_S + c] - m) * r;
  }
  // consumers are protected by the gemm's leading __syncthreads
}

__global__ __launch_bounds__(THREADS, 1) void fused_interp_kernel(
    const float* __restrict__ fm, const float* __restrict__ fmu,
    const float* __restrict__ nc_w, const float* __restrict__ nc_b,
    const float* __restrict__ wq, const float* __restrict__ bq,
    const float* __restrict__ wkv, const float* __restrict__ bkv,
    const float* __restrict__ wo, const float* __restrict__ bo,
    const float* __restrict__ w1, const float* __restrict__ b1,
    const float* __restrict__ w2, const float* __restrict__ b2,
    const float* __restrict__ wqf, const float* __restrict__ bqf,
    const float* __restrict__ wcf, const float* __restrict__ bcf,
    float* __restrict__ out) {
  __shared__ Smem sm;
  const int tid = threadIdx.x;
  const int bx = blockIdx.x;  // 0..23
  const int by = blockIdx.y;  // 0..31
  const int bz = blockIdx.z;  // batch
  const int lh0 = by * 2, lw0 = bx * 4;
  const int hu0 = by * 4, wu0 = bx * 8;

  // ---- phase 0a: load x tile (32 px x 128 c) ----
#pragma unroll
  for (int p = 0; p < 16; ++p) {
    const int idx = tid + p * THREADS;
    const int c = idx >> 5;
    const int px = idx & 31;
    const int hu = hu0 + (px >> 3);
    const int wu = wu0 + (px & 7);
    sm.xs[px * XS_S + c] = fmu[((bz * 128 + c) * HuC + hu) * WuC + wu];
  }

  // ---- phase 0b: context LN -> ctxT (transposed) ----
  for (int pass = 0; pass < 2; ++pass) {
    const int rl = tid >> 2;        // 0..63
    const int sub = tid & 3;
    const int r = pass * 64 + rl;
    const bool act = (r < 72);
    int base = 0;
    if (act) {
      const int lr = r / 9, kk = r % 9;
      const int hdp = lh0 + (lr >> 2);
      const int wdp = lw0 + (lr & 3);
      const int ki = kk / 3, kj = kk % 3;
      int hs = hdp + ki - 1; hs = hs < 0 ? 0 : (hs > HdC - 1 ? HdC - 1 : hs);
      int ws = wdp + kj - 1; ws = ws < 0 ? 0 : (ws > WdC - 1 ? WdC - 1 : ws);
      base = (bz * 128) * HdC * WdC + hs * WdC + ws;
      float s1 = 0.f, s2 = 0.f;
      for (int i = 0; i < 32; ++i) {
        const float v = fm[base + (sub * 32 + i) * (HdC * WdC)];
        s1 += v; s2 += v * v;
      }
      sm.scratch[SC_RED + sub * 64 + rl] = s1;
      sm.scratch[SC_RED + 384 + sub * 64 + rl] = s2;
    }
    __syncthreads();
    if (tid < 64 && pass * 64 + tid < 72) {
      float a = 0.f, b = 0.f;
#pragma unroll
      for (int s = 0; s < 4; ++s) {
        a += sm.scratch[SC_RED + s * 64 + tid];
        b += sm.scratch[SC_RED + 384 + s * 64 + tid];
      }
      const float m = a * (1.f / 128.f);
      const float v = b * (1.f / 128.f) - m * m;
      sm.scratch[SC_MU + pass * 64 + tid] = m;
      sm.scratch[SC_RS + pass * 64 + tid] = rsqrtf(v + 1e-6f);
    }
    __syncthreads();
    if (act) {
      const float m = sm.scratch[SC_MU + r];
      const float rr = sm.scratch[SC_RS + r];
      for (int i = 0; i < 32; ++i) {
        const int c = sub * 32 + i;
        const float v = fm[base + c * (HdC * WdC)];
        sm.ctxT[c * CTX_S + r] = (v - m) * rr;
      }
    }
    __syncthreads();
  }
  // zero the pad rows 72..79 of ctxT (read by discarded pad tiles)
  if (tid < 128) {
#pragma unroll
    for (int r = 72; r < 80; ++r) sm.ctxT[tid * CTX_S + r] = 0.f;
  }
  __syncthreads();

  const int row0 = (tid >> 5) << 2;
  const int col0 = (tid & 31) << 2;
  float acc[16];

  for (int l = 0; l < 2; ++l) {
    // stage nc_w/nc_b for this layer (disjoint scratch region)
    if (tid < 128) sm.scratch[SC_NC + tid] = nc_w[l * 128 + tid];
    else           sm.scratch[SC_NC + tid] = nc_b[l * 128 + (tid - 128)];

    // q = LN(x) @ wq + bq
    layernorm_x(sm.xs, sm.xnT, sm.scratch, tid);
    gemm32(wq + l * 16384, 128, sm.xnT, sm.wbuf, tid, acc);
    {
      const float4 bv = *reinterpret_cast<const float4*>(bq + l * 128 + col0);
#pragma unroll
      for (int i = 0; i < 4; ++i) {
        float4 o;
        o.x = acc[i * 4 + 0] + bv.x; o.y = acc[i * 4 + 1] + bv.y;
        o.z = acc[i * 4 + 2] + bv.z; o.w = acc[i * 4 + 3] + bv.w;
        *reinterpret_cast<float4*>(sm.outb + (row0 + i) * OB_S + col0) = o;
      }
    }
    // k = (LN(ctx)*ncw+ncb) @ wkv[:, :128] + bkv[:128]
    gemm96<true>(wkv + l * 32768, 256, sm.ctxT, sm.wbuf, sm.kvb,
                 bkv + l * 256, sm.scratch + SC_NC, tid);
    __syncthreads();
    // attention logits + softmax
    if (tid < 128) {
      const int px = tid >> 2, h = tid & 3;
      const int lr = (((px >> 3) >> 1) << 2) | ((px & 7) >> 1);
      const float* qrow = sm.outb + px * OB_S + h * 32;
      float4 q[8];
#pragma unroll
      for (int d = 0; d < 8; ++d) q[d] = *reinterpret_cast<const float4*>(qrow + d * 4);
      float lg[9];
      float mx = -1e30f;
#pragma unroll
      for (int kk = 0; kk < 9; ++kk) {
        const float* krow = sm.kvb + (lr * 9 + kk) * KV_S + h * 32;
        float s = 0.f;
#pragma unroll
        for (int d = 0; d < 8; ++d) {
          const float4 kv = *reinterpret_cast<const float4*>(krow + d * 4);
          s += q[d].x * kv.x + q[d].y * kv.y + q[d].z * kv.z + q[d].w * kv.w;
        }
        s *= 0.17677669529663687f;  // 1/sqrt(32)
        lg[kk] = s;
        mx = fmaxf(mx, s);
      }
      float sum = 0.f;
#pragma unroll
      for (int kk = 0; kk < 9; ++kk) { lg[kk] = __expf(lg[kk] - mx); sum += lg[kk]; }
      const float inv = 1.f / sum;
#pragma unroll
      for (int kk = 0; kk < 9; ++kk)
        sm.scratch[SC_ATT + (px * 4 + h) * 9 + kk] = lg[kk] * inv;
    }
    __syncthreads();
    // v = (LN(ctx)*ncw+ncb) @ wkv[:, 128:] + bkv[128:]  (overwrites k)
    gemm96<true>(wkv + l * 32768 + 128, 256, sm.ctxT, sm.wbuf, sm.kvb,
                 bkv + l * 256 + 128, sm.scratch + SC_NC, tid);
    __syncthreads();
    // oT[c][px] = sum_kk attn * v
    {
      const int c = tid & 127, pg = tid >> 7;
      const int h = c >> 5;
#pragma unroll 4
      for (int i = 0; i < 16; ++i) {
        const int px = pg * 16 + i;
        const int lr = (((px >> 3) >> 1) << 2) | ((px & 7) >> 1);
        const float* aw = sm.scratch + SC_ATT + (px * 4 + h) * 9;
        float s = 0.f;
#pragma unroll
        for (int kk = 0; kk < 9; ++kk) s += aw[kk] * sm.kvb[(lr * 9 + kk) * KV_S + c];
        sm.xnT[c * XN_S + px] = s;
      }
    }
    // x += o @ wo + bo   (gemm's leading barrier protects xnT)
    gemm32(wo + l * 16384, 128, sm.xnT, sm.wbuf, tid, acc);
    {
      const float4 bv = *reinterpret_cast<const float4*>(bo + l * 128 + col0);
#pragma unroll
      for (int i = 0; i < 4; ++i) {
        float* xr = sm.xs + (row0 + i) * XS_S + col0;
        float4 x = *reinterpret_cast<float4*>(xr);
        x.x += acc[i * 4 + 0] + bv.x; x.y += acc[i * 4 + 1] + bv.y;
        x.z += acc[i * 4 + 2] + bv.z; x.w += acc[i * 4 + 3] + bv.w;
        *reinterpret_cast<float4*>(xr) = x;
      }
    }
    __syncthreads();
    // MLP: x += gelu(LN(x)@w1+b1)@w2 + b2  (hidden 512 in 4 chunks of 128)
    layernorm_x(sm.xs, sm.xnT, sm.scratch, tid);
    float xd[16];
#pragma unroll
    for (int i = 0; i < 16; ++i) xd[i] = 0.f;
    for (int cc = 0; cc < 4; ++cc) {
      gemm32(w1 + l * 65536 + cc * 128, 512, sm.xnT, sm.wbuf, tid, acc);
      {
        const float4 bv = *reinterpret_cast<const float4*>(b1 + l * 512 + cc * 128 + col0);
#pragma unroll
        for (int i = 0; i < 4; ++i) {
          float4 o;
          o.x = gelu_tanh(acc[i * 4 + 0] + bv.x);
          o.y = gelu_tanh(acc[i * 4 + 1] + bv.y);
          o.z = gelu_tanh(acc[i * 4 + 2] + bv.z);
          o.w = gelu_tanh(acc[i * 4 + 3] + bv.w);
          *reinterpret_cast<float4*>(sm.outb + (row0 + i) * OB_S + col0) = o;
        }
      }
      __syncthreads();
      const float* w2c = w2 + l * 65536 + cc * 16384;
      for (int kc = 0; kc < 4; ++kc) {
        __syncthreads();
        stage_w(w2c, 128, kc, sm.wbuf, tid);
        __syncthreads();
#pragma unroll 4
        for (int cl = 0; cl < 32; ++cl) {
          const int c = (kc << 5) + cl;
          const float a0 = sm.outb[(row0 + 0) * OB_S + c];
          const float a1 = sm.outb[(row0 + 1) * OB_S + c];
          const float a2 = sm.outb[(row0 + 2) * OB_S + c];
          const float a3 = sm.outb[(row0 + 3) * OB_S + c];
          const float4 w = *reinterpret_cast<const float4*>(sm.wbuf + cl * 128 + col0);
          FMA_ROW(xd + 0, a0, w);
          FMA_ROW(xd + 4, a1, w);
          FMA_ROW(xd + 8, a2, w);
          FMA_ROW(xd + 12, a3, w);
        }
      }
    }
    {
      const float4 bv = *reinterpret_cast<const float4*>(b2 + l * 128 + col0);
#pragma unroll
      for (int i = 0; i < 4; ++i) {
        float* xr = sm.xs + (row0 + i) * XS_S + col0;
        float4 x = *reinterpret_cast<float4*>(xr);
        x.x += xd[i * 4 + 0] + bv.x; x.y += xd[i * 4 + 1] + bv.y;
        x.z += xd[i * 4 + 2] + bv.z; x.w += xd[i * 4 + 3] + bv.w;
        *reinterpret_cast<float4*>(xr) = x;
      }
    }
    __syncthreads();
  }  // layers

  // ---- final: xq = LN(x)@wqf+bqf ; ctxp = LN(ctx)@wcf+bcf ; softmax over 9 ----
  layernorm_x(sm.xs, sm.xnT, sm.scratch, tid);
  gemm32(wqf, 128, sm.xnT, sm.wbuf, tid, acc);
  {
    const float4 bv = *reinterpret_cast<const float4*>(bqf + col0);
#pragma unroll
    for (int i = 0; i < 4; ++i) {
      float4 o;
      o.x = acc[i * 4 + 0] + bv.x; o.y = acc[i * 4 + 1] + bv.y;
      o.z = acc[i * 4 + 2] + bv.z; o.w = acc[i * 4 + 3] + bv.w;
      *reinterpret_cast<float4*>(sm.outb + (row0 + i) * OB_S + col0) = o;
    }
  }
  gemm96<false>(wcf, 128, sm.ctxT, sm.wbuf, sm.kvb, bcf, nullptr, tid);
  __syncthreads();
  {
    const int px = tid >> 3, sub = tid & 7;
    const int lr = (((px >> 3) >> 1) << 2) | ((px & 7) >> 1);
    const float* qrow = sm.outb + px * OB_S;
    {
      const float* crow = sm.kvb + (lr * 9 + sub) * KV_S;
      float s = 0.f;
#pragma unroll 8
      for (int c = 0; c < 128; c += 4) {
        const float4 qv = *reinterpret_cast<const float4*>(qrow + c);
        const float4 cv = *reinterpret_cast<const float4*>(crow + c);
        s += qv.x * cv.x + qv.y * cv.y + qv.z * cv.z + qv.w * cv.w;
      }
      sm.scratch[SC_LG + px * 12 + sub] = s;
    }
    if (sub == 0) {
      const float* crow = sm.kvb + (lr * 9 + 8) * KV_S;
      float s = 0.f;
#pragma unroll 8
      for (int c = 0; c < 128; c += 4) {
        const float4 qv = *reinterpret_cast<const float4*>(qrow + c);
        const float4 cv = *reinterpret_cast<const float4*>(crow + c);
        s += qv.x * cv.x + qv.y * cv.y + qv.z * cv.z + qv.w * cv.w;
      }
      sm.scratch[SC_LG + px * 12 + 8] = s;
    }
  }
  __syncthreads();
  if (tid < 32) {
    const int px = tid;
    const int hu = hu0 + (px >> 3), wu = wu0 + (px & 7);
    float lg[9], mx = -1e30f;
#pragma unroll
    for (int kk = 0; kk < 9; ++kk) {
      lg[kk] = sm.scratch[SC_LG + px * 12 + kk] * 0.08838834764831845f;  // 1/sqrt(128)
      mx = fmaxf(mx, lg[kk]);
    }
    float sum = 0.f;
#pragma unroll
    for (int kk = 0; kk < 9; ++kk) { lg[kk] = __expf(lg[kk] - mx); sum += lg[kk]; }
    const float inv = 1.f / sum;
#pragma unroll
    for (int kk = 0; kk < 9; ++kk)
      out[((bz * 9 + kk) * HuC + hu) * WuC + wu] = lg[kk] * inv;
  }
}

}  // namespace

extern "C" void kernel_launch(void* const* d_in, const int* in_sizes, int n_in,
                              void* d_out, int out_size, void* d_ws, size_t ws_size,
                              hipStream_t stream) {
  const float* fm   = (const float*)d_in[0];
  const float* fmu  = (const float*)d_in[1];
  const float* nc_w = (const float*)d_in[2];
  const float* nc_b = (const float*)d_in[3];
  const float* wq   = (const float*)d_in[4];
  const float* bq   = (const float*)d_in[5];
  const float* wkv  = (const float*)d_in[6];
  const float* bkv  = (const float*)d_in[7];
  const float* wo   = (const float*)d_in[8];
  const float* bo   = (const float*)d_in[9];
  const float* w1   = (const float*)d_in[10];
  const float* b1   = (const float*)d_in[11];
  const float* w2   = (const float*)d_in[12];
  const float* b2   = (const float*)d_in[13];
  const float* wqf  = (const float*)d_in[14];
  const float* bqf  = (const float*)d_in[15];
  const float* wcf  = (const float*)d_in[16];
  const float* bcf  = (const float*)d_in[17];
  float* out = (float*)d_out;

  dim3 grid(24, 32, 2);  // (Wd/4, Hd/2, B): 4x8-pixel tiles = 2x4 low-res tiles
  fused_interp_kernel<<<grid, dim3(THREADS), 0, stream>>>(
      fm, fmu, nc_w, nc_b, wq, bq, wkv, bkv, wo, bo, w1, b1, w2, b2,
      wqf, bqf, wcf, bcf, out);
}

// Round 2
// 548.387 us; speedup vs baseline: 3.3292x; 3.3292x over previous
//
#include <hip/hip_runtime.h>

namespace {

constexpr int THREADS = 256;
constexpr int HdC = 64, WdC = 96, HuC = 128, WuC = 192;

// ======================= shared helpers =======================

__device__ __forceinline__ float gelu_tanh(float x) {
  float z = 0.7978845608028654f * (x + 0.044715f * x * x * x);
  float e = __expf(2.0f * z);
  float t = 1.0f - 2.0f / (e + 1.0f);
  return 0.5f * x * (1.0f + t);
}

__device__ __forceinline__ unsigned short f2bf(float f) {
  unsigned int u = __builtin_bit_cast(unsigned int, f);
  u = (u + 0x7FFFu + ((u >> 16) & 1u)) >> 16;  // RNE
  return (unsigned short)u;
}

// ======================= fp32 fallback path (round-1, verified) =======================

constexpr int CTX_S = 80;
constexpr int KV_S  = 132;
constexpr int XS_S  = 132;
constexpr int XN_S  = 32;
constexpr int OB_S  = 144;

constexpr int SC_ATT = 0;
constexpr int SC_RED = 0;
constexpr int SC_MU  = 768;
constexpr int SC_RS  = 864;
constexpr int SC_NC  = 1152;
constexpr int SC_LG  = 0;

struct alignas(16) Smem {
  float ctxT[128 * CTX_S];
  float kvb[72 * KV_S];
  float xs[32 * XS_S];
  float xnT[128 * XN_S];
  float outb[32 * OB_S];
  float wbuf[32 * 128];
  float scratch[1536];
};
static_assert(sizeof(Smem) <= 160 * 1024, "LDS budget");

__device__ __forceinline__ void stage_w(const float* __restrict__ W, int wstride,
                                        int kc, float* wbuf, int tid) {
#pragma unroll
  for (int p = 0; p < 4; ++p) {
    int e = tid + p * THREADS;
    int r = e >> 5;
    int c4 = (e & 31) << 2;
    const float4 v = *reinterpret_cast<const float4*>(W + (kc * 32 + r) * wstride + c4);
    *reinterpret_cast<float4*>(wbuf + r * 128 + c4) = v;
  }
}

#define FMA_ROW(ac, s, w)                                            \
  {                                                                  \
    (ac)[0] += (s) * (w).x; (ac)[1] += (s) * (w).y;                  \
    (ac)[2] += (s) * (w).z; (ac)[3] += (s) * (w).w;                  \
  }

__device__ __forceinline__ void gemm32(const float* __restrict__ W, int wstride,
                                       const float* AT, float* wbuf, int tid,
                                       float acc[16]) {
  const int row0 = (tid >> 5) << 2;
  const int col0 = (tid & 31) << 2;
#pragma unroll
  for (int i = 0; i < 16; ++i) acc[i] = 0.f;
  for (int kc = 0; kc < 4; ++kc) {
    __syncthreads();
    stage_w(W, wstride, kc, wbuf, tid);
    __syncthreads();
#pragma unroll 4
    for (int cl = 0; cl < 32; ++cl) {
      const int c = (kc << 5) + cl;
      const float4 a = *reinterpret_cast<const float4*>(AT + c * XN_S + row0);
      const float4 w = *reinterpret_cast<const float4*>(wbuf + cl * 128 + col0);
      FMA_ROW(acc + 0, a.x, w);
      FMA_ROW(acc + 4, a.y, w);
      FMA_ROW(acc + 8, a.z, w);
      FMA_ROW(acc + 12, a.w, w);
    }
  }
}

template <bool NC>
__device__ __forceinline__ void gemm96(const float* __restrict__ W, int wstride,
                                       const float* ctxT, float* wbuf, float* kvb,
                                       const float* __restrict__ bias,
                                       const float* nc, int tid) {
  const int rt4 = (tid >> 5) << 2;
  const int col0 = (tid & 31) << 2;
  float acc[48];
#pragma unroll
  for (int i = 0; i < 48; ++i) acc[i] = 0.f;
  for (int kc = 0; kc < 4; ++kc) {
    __syncthreads();
    stage_w(W, wstride, kc, wbuf, tid);
    __syncthreads();
#pragma unroll 2
    for (int cl = 0; cl < 32; ++cl) {
      const int c = (kc << 5) + cl;
      const float4 w = *reinterpret_cast<const float4*>(wbuf + cl * 128 + col0);
      float s = 0.f, t = 0.f;
      if (NC) { s = nc[c]; t = nc[128 + c]; }
      const float* base = ctxT + c * CTX_S;
#pragma unroll
      for (int p = 0; p < 3; ++p) {
        int r0 = p * 32 + rt4;
        if (r0 > 76) r0 = 76;
        float4 a = *reinterpret_cast<const float4*>(base + r0);
        if (NC) {
          a.x = a.x * s + t; a.y = a.y * s + t;
          a.z = a.z * s + t; a.w = a.w * s + t;
        }
        float* ac = acc + p * 16;
        FMA_ROW(ac + 0, a.x, w);
        FMA_ROW(ac + 4, a.y, w);
        FMA_ROW(ac + 8, a.z, w);
        FMA_ROW(ac + 12, a.w, w);
      }
    }
  }
  const float4 bv = *reinterpret_cast<const float4*>(bias + col0);
#pragma unroll
  for (int p = 0; p < 3; ++p) {
    const int r0 = p * 32 + rt4;
    if (r0 < 72) {
#pragma unroll
      for (int i = 0; i < 4; ++i) {
        float4 o;
        o.x = acc[p * 16 + i * 4 + 0] + bv.x;
        o.y = acc[p * 16 + i * 4 + 1] + bv.y;
        o.z = acc[p * 16 + i * 4 + 2] + bv.z;
        o.w = acc[p * 16 + i * 4 + 3] + bv.w;
        *reinterpret_cast<float4*>(kvb + (r0 + i) * KV_S + col0) = o;
      }
    }
  }
}

__device__ __forceinline__ void layernorm_x(const float* xs, float* xnT,
                                            float* scratch, int tid) {
  const int px = tid & 31;
  const int cg = tid >> 5;
  float s1 = 0.f, s2 = 0.f;
#pragma unroll
  for (int i = 0; i < 16; ++i) {
    const float v = xs[px * XS_S + cg * 16 + i];
    s1 += v; s2 += v * v;
  }
  scratch[SC_RED + cg * 96 + px] = s1;
  scratch[SC_RED + cg * 96 + 48 + px] = s2;
  __syncthreads();
  if (tid < 32) {
    float a = 0.f, b = 0.f;
#pragma unroll
    for (int g = 0; g < 8; ++g) {
      a += scratch[SC_RED + g * 96 + tid];
      b += scratch[SC_RED + g * 96 + 48 + tid];
    }
    const float m = a * (1.f / 128.f);
    const float v = b * (1.f / 128.f) - m * m;
    scratch[SC_MU + tid] = m;
    scratch[SC_RS + tid] = rsqrtf(v + 1e-6f);
  }
  __syncthreads();
  const float m = scratch[SC_MU + px];
  const float r = scratch[SC_RS + px];
#pragma unroll
  for (int i = 0; i < 16; ++i) {
    const int c = cg * 16 + i;
    xnT[c * XN_S + px] = (xs[px * XS_S + c] - m) * r;
  }
}

__global__ __launch_bounds__(THREADS, 1) void fused_interp_kernel(
    const float* __restrict__ fm, const float* __restrict__ fmu,
    const float* __restrict__ nc_w, const float* __restrict__ nc_b,
    const float* __restrict__ wq, const float* __restrict__ bq,
    const float* __restrict__ wkv, const float* __restrict__ bkv,
    const float* __restrict__ wo, const float* __restrict__ bo,
    const float* __restrict__ w1, const float* __restrict__ b1,
    const float* __restrict__ w2, const float* __restrict__ b2,
    const float* __restrict__ wqf, const float* __restrict__ bqf,
    const float* __restrict__ wcf, const float* __restrict__ bcf,
    float* __restrict__ out) {
  __shared__ Smem sm;
  const int tid = threadIdx.x;
  const int bx = blockIdx.x;
  const int by = blockIdx.y;
  const int bz = blockIdx.z;
  const int lh0 = by * 2, lw0 = bx * 4;
  const int hu0 = by * 4, wu0 = bx * 8;

#pragma unroll
  for (int p = 0; p < 16; ++p) {
    const int idx = tid + p * THREADS;
    const int c = idx >> 5;
    const int px = idx & 31;
    const int hu = hu0 + (px >> 3);
    const int wu = wu0 + (px & 7);
    sm.xs[px * XS_S + c] = fmu[((bz * 128 + c) * HuC + hu) * WuC + wu];
  }

  for (int pass = 0; pass < 2; ++pass) {
    const int rl = tid >> 2;
    const int sub = tid & 3;
    const int r = pass * 64 + rl;
    const bool act = (r < 72);
    int base = 0;
    if (act) {
      const int lr = r / 9, kk = r % 9;
      const int hdp = lh0 + (lr >> 2);
      const int wdp = lw0 + (lr & 3);
      const int ki = kk / 3, kj = kk % 3;
      int hs = hdp + ki - 1; hs = hs < 0 ? 0 : (hs > HdC - 1 ? HdC - 1 : hs);
      int ws = wdp + kj - 1; ws = ws < 0 ? 0 : (ws > WdC - 1 ? WdC - 1 : ws);
      base = (bz * 128) * HdC * WdC + hs * WdC + ws;
      float s1 = 0.f, s2 = 0.f;
      for (int i = 0; i < 32; ++i) {
        const float v = fm[base + (sub * 32 + i) * (HdC * WdC)];
        s1 += v; s2 += v * v;
      }
      sm.scratch[SC_RED + sub * 64 + rl] = s1;
      sm.scratch[SC_RED + 384 + sub * 64 + rl] = s2;
    }
    __syncthreads();
    if (tid < 64 && pass * 64 + tid < 72) {
      float a = 0.f, b = 0.f;
#pragma unroll
      for (int s = 0; s < 4; ++s) {
        a += sm.scratch[SC_RED + s * 64 + tid];
        b += sm.scratch[SC_RED + 384 + s * 64 + tid];
      }
      const float m = a * (1.f / 128.f);
      const float v = b * (1.f / 128.f) - m * m;
      sm.scratch[SC_MU + pass * 64 + tid] = m;
      sm.scratch[SC_RS + pass * 64 + tid] = rsqrtf(v + 1e-6f);
    }
    __syncthreads();
    if (act) {
      const float m = sm.scratch[SC_MU + r];
      const float rr = sm.scratch[SC_RS + r];
      for (int i = 0; i < 32; ++i) {
        const int c = sub * 32 + i;
        const float v = fm[base + c * (HdC * WdC)];
        sm.ctxT[c * CTX_S + r] = (v - m) * rr;
      }
    }
    __syncthreads();
  }
  if (tid < 128) {
#pragma unroll
    for (int r = 72; r < 80; ++r) sm.ctxT[tid * CTX_S + r] = 0.f;
  }
  __syncthreads();

  const int row0 = (tid >> 5) << 2;
  const int col0 = (tid & 31) << 2;
  float acc[16];

  for (int l = 0; l < 2; ++l) {
    if (tid < 128) sm.scratch[SC_NC + tid] = nc_w[l * 128 + tid];
    else           sm.scratch[SC_NC + tid] = nc_b[l * 128 + (tid - 128)];

    layernorm_x(sm.xs, sm.xnT, sm.scratch, tid);
    gemm32(wq + l * 16384, 128, sm.xnT, sm.wbuf, tid, acc);
    {
      const float4 bv = *reinterpret_cast<const float4*>(bq + l * 128 + col0);
#pragma unroll
      for (int i = 0; i < 4; ++i) {
        float4 o;
        o.x = acc[i * 4 + 0] + bv.x; o.y = acc[i * 4 + 1] + bv.y;
        o.z = acc[i * 4 + 2] + bv.z; o.w = acc[i * 4 + 3] + bv.w;
        *reinterpret_cast<float4*>(sm.outb + (row0 + i) * OB_S + col0) = o;
      }
    }
    gemm96<true>(wkv + l * 32768, 256, sm.ctxT, sm.wbuf, sm.kvb,
                 bkv + l * 256, sm.scratch + SC_NC, tid);
    __syncthreads();
    if (tid < 128) {
      const int px = tid >> 2, h = tid & 3;
      const int lr = (((px >> 3) >> 1) << 2) | ((px & 7) >> 1);
      const float* qrow = sm.outb + px * OB_S + h * 32;
      float4 q[8];
#pragma unroll
      for (int d = 0; d < 8; ++d) q[d] = *reinterpret_cast<const float4*>(qrow + d * 4);
      float lg[9];
      float mx = -1e30f;
#pragma unroll
      for (int kk = 0; kk < 9; ++kk) {
        const float* krow = sm.kvb + (lr * 9 + kk) * KV_S + h * 32;
        float s = 0.f;
#pragma unroll
        for (int d = 0; d < 8; ++d) {
          const float4 kv = *reinterpret_cast<const float4*>(krow + d * 4);
          s += q[d].x * kv.x + q[d].y * kv.y + q[d].z * kv.z + q[d].w * kv.w;
        }
        s *= 0.17677669529663687f;
        lg[kk] = s;
        mx = fmaxf(mx, s);
      }
      float sum = 0.f;
#pragma unroll
      for (int kk = 0; kk < 9; ++kk) { lg[kk] = __expf(lg[kk] - mx); sum += lg[kk]; }
      const float inv = 1.f / sum;
#pragma unroll
      for (int kk = 0; kk < 9; ++kk)
        sm.scratch[SC_ATT + (px * 4 + h) * 9 + kk] = lg[kk] * inv;
    }
    __syncthreads();
    gemm96<true>(wkv + l * 32768 + 128, 256, sm.ctxT, sm.wbuf, sm.kvb,
                 bkv + l * 256 + 128, sm.scratch + SC_NC, tid);
    __syncthreads();
    {
      const int c = tid & 127, pg = tid >> 7;
      const int h = c >> 5;
#pragma unroll 4
      for (int i = 0; i < 16; ++i) {
        const int px = pg * 16 + i;
        const int lr = (((px >> 3) >> 1) << 2) | ((px & 7) >> 1);
        const float* aw = sm.scratch + SC_ATT + (px * 4 + h) * 9;
        float s = 0.f;
#pragma unroll
        for (int kk = 0; kk < 9; ++kk) s += aw[kk] * sm.kvb[(lr * 9 + kk) * KV_S + c];
        sm.xnT[c * XN_S + px] = s;
      }
    }
    gemm32(wo + l * 16384, 128, sm.xnT, sm.wbuf, tid, acc);
    {
      const float4 bv = *reinterpret_cast<const float4*>(bo + l * 128 + col0);
#pragma unroll
      for (int i = 0; i < 4; ++i) {
        float* xr = sm.xs + (row0 + i) * XS_S + col0;
        float4 x = *reinterpret_cast<float4*>(xr);
        x.x += acc[i * 4 + 0] + bv.x; x.y += acc[i * 4 + 1] + bv.y;
        x.z += acc[i * 4 + 2] + bv.z; x.w += acc[i * 4 + 3] + bv.w;
        *reinterpret_cast<float4*>(xr) = x;
      }
    }
    __syncthreads();
    layernorm_x(sm.xs, sm.xnT, sm.scratch, tid);
    float xd[16];
#pragma unroll
    for (int i = 0; i < 16; ++i) xd[i] = 0.f;
    for (int cc = 0; cc < 4; ++cc) {
      gemm32(w1 + l * 65536 + cc * 128, 512, sm.xnT, sm.wbuf, tid, acc);
      {
        const float4 bv = *reinterpret_cast<const float4*>(b1 + l * 512 + cc * 128 + col0);
#pragma unroll
        for (int i = 0; i < 4; ++i) {
          float4 o;
          o.x = gelu_tanh(acc[i * 4 + 0] + bv.x);
          o.y = gelu_tanh(acc[i * 4 + 1] + bv.y);
          o.z = gelu_tanh(acc[i * 4 + 2] + bv.z);
          o.w = gelu_tanh(acc[i * 4 + 3] + bv.w);
          *reinterpret_cast<float4*>(sm.outb + (row0 + i) * OB_S + col0) = o;
        }
      }
      __syncthreads();
      const float* w2c = w2 + l * 65536 + cc * 16384;
      for (int kc = 0; kc < 4; ++kc) {
        __syncthreads();
        stage_w(w2c, 128, kc, sm.wbuf, tid);
        __syncthreads();
#pragma unroll 4
        for (int cl = 0; cl < 32; ++cl) {
          const int c = (kc << 5) + cl;
          const float a0 = sm.outb[(row0 + 0) * OB_S + c];
          const float a1 = sm.outb[(row0 + 1) * OB_S + c];
          const float a2 = sm.outb[(row0 + 2) * OB_S + c];
          const float a3 = sm.outb[(row0 + 3) * OB_S + c];
          const float4 w = *reinterpret_cast<const float4*>(sm.wbuf + cl * 128 + col0);
          FMA_ROW(xd + 0, a0, w);
          FMA_ROW(xd + 4, a1, w);
          FMA_ROW(xd + 8, a2, w);
          FMA_ROW(xd + 12, a3, w);
        }
      }
    }
    {
      const float4 bv = *reinterpret_cast<const float4*>(b2 + l * 128 + col0);
#pragma unroll
      for (int i = 0; i < 4; ++i) {
        float* xr = sm.xs + (row0 + i) * XS_S + col0;
        float4 x = *reinterpret_cast<float4*>(xr);
        x.x += xd[i * 4 + 0] + bv.x; x.y += xd[i * 4 + 1] + bv.y;
        x.z += xd[i * 4 + 2] + bv.z; x.w += xd[i * 4 + 3] + bv.w;
        *reinterpret_cast<float4*>(xr) = x;
      }
    }
    __syncthreads();
  }

  layernorm_x(sm.xs, sm.xnT, sm.scratch, tid);
  gemm32(wqf, 128, sm.xnT, sm.wbuf, tid, acc);
  {
    const float4 bv = *reinterpret_cast<const float4*>(bqf + col0);
#pragma unroll
    for (int i = 0; i < 4; ++i) {
      float4 o;
      o.x = acc[i * 4 + 0] + bv.x; o.y = acc[i * 4 + 1] + bv.y;
      o.z = acc[i * 4 + 2] + bv.z; o.w = acc[i * 4 + 3] + bv.w;
      *reinterpret_cast<float4*>(sm.outb + (row0 + i) * OB_S + col0) = o;
    }
  }
  gemm96<false>(wcf, 128, sm.ctxT, sm.wbuf, sm.kvb, bcf, nullptr, tid);
  __syncthreads();
  {
    const int px = tid >> 3, sub = tid & 7;
    const int lr = (((px >> 3) >> 1) << 2) | ((px & 7) >> 1);
    const float* qrow = sm.outb + px * OB_S;
    {
      const float* crow = sm.kvb + (lr * 9 + sub) * KV_S;
      float s = 0.f;
#pragma unroll 8
      for (int c = 0; c < 128; c += 4) {
        const float4 qv = *reinterpret_cast<const float4*>(qrow + c);
        const float4 cv = *reinterpret_cast<const float4*>(crow + c);
        s += qv.x * cv.x + qv.y * cv.y + qv.z * cv.z + qv.w * cv.w;
      }
      sm.scratch[SC_LG + px * 12 + sub] = s;
    }
    if (sub == 0) {
      const float* crow = sm.kvb + (lr * 9 + 8) * KV_S;
      float s = 0.f;
#pragma unroll 8
      for (int c = 0; c < 128; c += 4) {
        const float4 qv = *reinterpret_cast<const float4*>(qrow + c);
        const float4 cv = *reinterpret_cast<const float4*>(crow + c);
        s += qv.x * cv.x + qv.y * cv.y + qv.z * cv.z + qv.w * cv.w;
      }
      sm.scratch[SC_LG + px * 12 + 8] = s;
    }
  }
  __syncthreads();
  if (tid < 32) {
    const int px = tid;
    const int hu = hu0 + (px >> 3), wu = wu0 + (px & 7);
    float lg[9], mx = -1e30f;
#pragma unroll
    for (int kk = 0; kk < 9; ++kk) {
      lg[kk] = sm.scratch[SC_LG + px * 12 + kk] * 0.08838834764831845f;
      mx = fmaxf(mx, lg[kk]);
    }
    float sum = 0.f;
#pragma unroll
    for (int kk = 0; kk < 9; ++kk) { lg[kk] = __expf(lg[kk] - mx); sum += lg[kk]; }
    const float inv = 1.f / sum;
#pragma unroll
    for (int kk = 0; kk < 9; ++kk)
      out[((bz * 9 + kk) * HuC + hu) * WuC + wu] = lg[kk] * inv;
  }
}

// ======================= MFMA path =======================

constexpr int PANEL_U16 = 18432;          // 36864 B per panel
constexpr int N_PANELS  = 26;
constexpr size_t WS_NEEDED = (size_t)N_PANELS * PANEL_U16 * 2 + 2048;
constexpr int BSTR = 136;                 // bf16 row stride (all bf16 LDS buffers & panels)
constexpr int QB_S = 132;                 // fp32 q/xq buffer stride

typedef __attribute__((ext_vector_type(8))) short bf16x8;
typedef __attribute__((ext_vector_type(4))) float f32x4;
typedef __attribute__((ext_vector_type(8))) unsigned short u16x8;

struct alignas(16) SmemM {
  unsigned short ctxn[96 * BSTR];   // 26112 B  (rows 72..95 garbage, never stored)
  unsigned short wbuf[PANEL_U16];   // 36864 B  weight panel [n][k] bf16
  float kvb[72 * KV_S];             // 38016 B  k or v (fp32), then ctxp
  float xs[32 * XS_S];              // 16896 B  residual x
  unsigned short xn[32 * BSTR];     //  8704 B  LN(x) / o  (MFMA A operand)
  unsigned short hb[32 * BSTR];     //  8704 B  gelu chunk (MFMA A operand)
  float outb[32 * QB_S];            // 16896 B  q / xq fp32
  float scratch[1536];              //  6144 B
};
static_assert(sizeof(SmemM) <= 160 * 1024, "LDS budget (mfma)");

// prep: transpose+convert weights into ws panels [n][k] bf16 (stride BSTR),
// folding nc_w into kv panels; adjusted kv bias into wsb.
__global__ void prep_weights(
    const float* __restrict__ nc_w, const float* __restrict__ nc_b,
    const float* __restrict__ wq, const float* __restrict__ wkv,
    const float* __restrict__ bkv,
    const float* __restrict__ wo, const float* __restrict__ w1,
    const float* __restrict__ w2, const float* __restrict__ wqf,
    const float* __restrict__ wcf,
    unsigned short* __restrict__ wsp, float* __restrict__ wsb) {
  const int b = blockIdx.x;
  const int t = threadIdx.x;
  if (b >= 104) {  // adjusted kv bias: b' = bkv + nc_b @ wkv
    const int l = b - 104;
    float acc = bkv[l * 256 + t];
    for (int k = 0; k < 128; ++k)
      acc += nc_b[l * 128 + k] * wkv[l * 32768 + k * 256 + t];
    wsb[l * 256 + t] = acc;
    return;
  }
  const int pid = b >> 2, qtr = b & 3;
  const float* src = wqf; int N = 128, koff = 0, noff = 0;
  const float* sc = nullptr;
  if (pid < 24) {
    const int l = pid / 12, loc = pid % 12;
    if (loc == 0)      { src = wq + l * 16384;  N = 128; }
    else if (loc == 1) { src = wkv + l * 32768; N = 256; sc = nc_w + l * 128; }
    else if (loc == 2) { src = wkv + l * 32768; N = 256; noff = 128; sc = nc_w + l * 128; }
    else if (loc == 3) { src = wo + l * 16384;  N = 128; }
    else if (loc < 8)  { src = w1 + l * 65536;  N = 512; noff = (loc - 4) * 128; }
    else               { src = w2 + l * 65536;  N = 128; koff = (loc - 8) * 128; }
  } else if (pid == 25) { src = wcf; }
  unsigned short* dst = wsp + pid * PANEL_U16;
  const int k = qtr * 32 + (t >> 3);
  const int n0 = (t & 7) * 16;
  const float s = sc ? sc[k] : 1.f;
  const float* sp = src + (k + koff) * N + noff + n0;
#pragma unroll
  for (int i = 0; i < 16; ++i) dst[(n0 + i) * BSTR + k] = f2bf(sp[i] * s);
}

__device__ __forceinline__ void stage_panel(const unsigned short* __restrict__ p,
                                            unsigned short* wbuf, int tid) {
  const float4* s4 = reinterpret_cast<const float4*>(p);
  float4* d4 = reinterpret_cast<float4*>(wbuf);
#pragma unroll
  for (int i = 0; i < 9; ++i) d4[tid + i * 256] = s4[tid + i * 256];
}

// 32x128 @ 128x128: wave -> row tile rt (0/1), col tiles ct0..ct0+3
__device__ __forceinline__ void mfma_g32(const unsigned short* A, const unsigned short* W,
                                         f32x4 acc[4], int lane, int rt, int ct0, bool init) {
  const int nl = lane & 15;
  const int q8 = (lane >> 4) * 8;
  const unsigned short* arow = A + (rt * 16 + nl) * BSTR;
  if (init) {
#pragma unroll
    for (int i = 0; i < 4; ++i) acc[i] = (f32x4){0.f, 0.f, 0.f, 0.f};
  }
#pragma unroll
  for (int ks = 0; ks < 4; ++ks) {
    const bf16x8 a = *reinterpret_cast<const bf16x8*>(arow + ks * 32 + q8);
#pragma unroll
    for (int t = 0; t < 4; ++t) {
      const bf16x8 b = *reinterpret_cast<const bf16x8*>(
          W + ((ct0 + t) * 16 + nl) * BSTR + ks * 32 + q8);
      acc[t] = __builtin_amdgcn_mfma_f32_16x16x32_bf16(a, b, acc[t], 0, 0, 0);
    }
  }
}

// 96x128 @ 128x128: wave -> col tiles ct96, ct96+1; all 6 row tiles
__device__ __forceinline__ void mfma_g96(const unsigned short* Ctx, const unsigned short* W,
                                         f32x4 acc[12], int lane, int ct96) {
  const int nl = lane & 15;
  const int q8 = (lane >> 4) * 8;
#pragma unroll
  for (int i = 0; i < 12; ++i) acc[i] = (f32x4){0.f, 0.f, 0.f, 0.f};
#pragma unroll
  for (int ks = 0; ks < 4; ++ks) {
    const bf16x8 b0 = *reinterpret_cast<const bf16x8*>(
        W + (ct96 * 16 + nl) * BSTR + ks * 32 + q8);
    const bf16x8 b1 = *reinterpret_cast<const bf16x8*>(
        W + ((ct96 + 1) * 16 + nl) * BSTR + ks * 32 + q8);
#pragma unroll
    for (int r6 = 0; r6 < 6; ++r6) {
      const bf16x8 a = *reinterpret_cast<const bf16x8*>(
          Ctx + (r6 * 16 + nl) * BSTR + ks * 32 + q8);
      acc[r6 * 2 + 0] = __builtin_amdgcn_mfma_f32_16x16x32_bf16(a, b0, acc[r6 * 2 + 0], 0, 0, 0);
      acc[r6 * 2 + 1] = __builtin_amdgcn_mfma_f32_16x16x32_bf16(a, b1, acc[r6 * 2 + 1], 0, 0, 0);
    }
  }
}

// LN over xs rows -> xn bf16 [px][c]
__device__ __forceinline__ void layernorm_x_bf(const float* xs, unsigned short* xn,
                                               float* scratch, int tid) {
  const int px = tid & 31;
  const int cg = tid >> 5;
  float s1 = 0.f, s2 = 0.f;
#pragma unroll
  for (int i = 0; i < 16; ++i) {
    const float v = xs[px * XS_S + cg * 16 + i];
    s1 += v; s2 += v * v;
  }
  scratch[SC_RED + cg * 96 + px] = s1;
  scratch[SC_RED + cg * 96 + 48 + px] = s2;
  __syncthreads();
  if (tid < 32) {
    float a = 0.f, b = 0.f;
#pragma unroll
    for (int g = 0; g < 8; ++g) {
      a += scratch[SC_RED + g * 96 + tid];
      b += scratch[SC_RED + g * 96 + 48 + tid];
    }
    const float m = a * (1.f / 128.f);
    const float v = b * (1.f / 128.f) - m * m;
    scratch[SC_MU + tid] = m;
    scratch[SC_RS + tid] = rsqrtf(v + 1e-6f);
  }
  __syncthreads();
  const float m = scratch[SC_MU + px];
  const float r = scratch[SC_RS + px];
  unsigned short tmp[16];
#pragma unroll
  for (int i = 0; i < 16; ++i)
    tmp[i] = f2bf((xs[px * XS_S + cg * 16 + i] - m) * r);
  *reinterpret_cast<u16x8*>(xn + px * BSTR + cg * 16) = *reinterpret_cast<u16x8*>(tmp);
  *reinterpret_cast<u16x8*>(xn + px * BSTR + cg * 16 + 8) = *reinterpret_cast<u16x8*>(tmp + 8);
}

__global__ __launch_bounds__(THREADS, 1) void fused_interp_mfma(
    const float* __restrict__ fm, const float* __restrict__ fmu,
    const float* __restrict__ bq, const float* __restrict__ bo,
    const float* __restrict__ b1, const float* __restrict__ b2,
    const float* __restrict__ bqf, const float* __restrict__ bcf,
    const unsigned short* __restrict__ wsp, const float* __restrict__ wsb,
    float* __restrict__ out) {
  __shared__ SmemM sm;
  const int tid = threadIdx.x;
  const int bx = blockIdx.x, by = blockIdx.y, bz = blockIdx.z;
  const int lh0 = by * 2, lw0 = bx * 4;
  const int hu0 = by * 4, wu0 = bx * 8;

  // phase 0a: residual x tile (fp32)
#pragma unroll
  for (int p = 0; p < 16; ++p) {
    const int idx = tid + p * THREADS;
    const int c = idx >> 5;
    const int px = idx & 31;
    const int hu = hu0 + (px >> 3);
    const int wu = wu0 + (px & 7);
    sm.xs[px * XS_S + c] = fmu[((bz * 128 + c) * HuC + hu) * WuC + wu];
  }

  // phase 0b: context LN -> ctxn bf16 [r][c]
  for (int pass = 0; pass < 2; ++pass) {
    const int rl = tid >> 2;
    const int sub = tid & 3;
    const int r = pass * 64 + rl;
    const bool act = (r < 72);
    int base = 0;
    if (act) {
      const int lr = r / 9, kk = r % 9;
      const int hdp = lh0 + (lr >> 2);
      const int wdp = lw0 + (lr & 3);
      const int ki = kk / 3, kj = kk % 3;
      int hs = hdp + ki - 1; hs = hs < 0 ? 0 : (hs > HdC - 1 ? HdC - 1 : hs);
      int ws = wdp + kj - 1; ws = ws < 0 ? 0 : (ws > WdC - 1 ? WdC - 1 : ws);
      base = (bz * 128) * HdC * WdC + hs * WdC + ws;
      float s1 = 0.f, s2 = 0.f;
      for (int i = 0; i < 32; ++i) {
        const float v = fm[base + (sub * 32 + i) * (HdC * WdC)];
        s1 += v; s2 += v * v;
      }
      sm.scratch[SC_RED + sub * 64 + rl] = s1;
      sm.scratch[SC_RED + 384 + sub * 64 + rl] = s2;
    }
    __syncthreads();
    if (tid < 64 && pass * 64 + tid < 72) {
      float a = 0.f, b = 0.f;
#pragma unroll
      for (int s = 0; s < 4; ++s) {
        a += sm.scratch[SC_RED + s * 64 + tid];
        b += sm.scratch[SC_RED + 384 + s * 64 + tid];
      }
      const float m = a * (1.f / 128.f);
      const float v = b * (1.f / 128.f) - m * m;
      sm.scratch[SC_MU + pass * 64 + tid] = m;
      sm.scratch[SC_RS + pass * 64 + tid] = rsqrtf(v + 1e-6f);
    }
    __syncthreads();
    if (act) {
      const float m = sm.scratch[SC_MU + r];
      const float rr = sm.scratch[SC_RS + r];
      unsigned short tmp[32];
      for (int i = 0; i < 32; ++i) {
        const float v = fm[base + (sub * 32 + i) * (HdC * WdC)];
        tmp[i] = f2bf((v - m) * rr);
      }
#pragma unroll
      for (int j = 0; j < 4; ++j)
        *reinterpret_cast<u16x8*>(sm.ctxn + r * BSTR + sub * 32 + j * 8) =
            *reinterpret_cast<u16x8*>(tmp + j * 8);
    }
    __syncthreads();
  }

  const int lane = tid & 63;
  const int wave = tid >> 6;
  const int nl = lane & 15;
  const int qm = (lane >> 4) * 4;       // C/D row base within tile
  const int rt = wave & 1;              // gemm32 row tile
  const int ct0 = (wave >> 1) * 4;      // gemm32 col tiles (4)
  const int ct96 = wave * 2;            // gemm96 col tiles (2)
  f32x4 acc[12];

  for (int l = 0; l < 2; ++l) {
    const unsigned short* P = wsp + (l * 12) * PANEL_U16;

    // ---- q = LN(x) @ wq + bq ----
    layernorm_x_bf(sm.xs, sm.xn, sm.scratch, tid);
    __syncthreads();
    stage_panel(P + 0 * PANEL_U16, sm.wbuf, tid);
    __syncthreads();
    mfma_g32(sm.xn, sm.wbuf, acc, lane, rt, ct0, true);
#pragma unroll
    for (int t = 0; t < 4; ++t) {
      const int n = (ct0 + t) * 16 + nl;
      const float bb = bq[l * 128 + n];
#pragma unroll
      for (int r = 0; r < 4; ++r)
        sm.outb[(rt * 16 + qm + r) * QB_S + n] = acc[t][r] + bb;
    }
    // ---- k = ctx_n @ wkv[:, :128] + b' ----
    __syncthreads();
    stage_panel(P + 1 * PANEL_U16, sm.wbuf, tid);
    __syncthreads();
    mfma_g96(sm.ctxn, sm.wbuf, acc, lane, ct96);
#pragma unroll
    for (int t = 0; t < 2; ++t) {
      const int n = (ct96 + t) * 16 + nl;
      const float bb = wsb[l * 256 + n];
#pragma unroll
      for (int r6 = 0; r6 < 6; ++r6) {
#pragma unroll
        for (int r = 0; r < 4; ++r) {
          const int row = r6 * 16 + qm + r;
          if (row < 72) sm.kvb[row * KV_S + n] = acc[r6 * 2 + t][r] + bb;
        }
      }
    }
    __syncthreads();
    // ---- attention softmax ----
    if (tid < 128) {
      const int px = tid >> 2, h = tid & 3;
      const int lr = (px >> 4) * 4 + ((px & 7) >> 1);
      const float* qrow = sm.outb + px * QB_S + h * 32;
      float4 q[8];
#pragma unroll
      for (int d = 0; d < 8; ++d) q[d] = *reinterpret_cast<const float4*>(qrow + d * 4);
      float lg[9];
      float mx = -1e30f;
#pragma unroll
      for (int kk = 0; kk < 9; ++kk) {
        const float* krow = sm.kvb + (lr * 9 + kk) * KV_S + h * 32;
        float s = 0.f;
#pragma unroll
        for (int d = 0; d < 8; ++d) {
          const float4 kv = *reinterpret_cast<const float4*>(krow + d * 4);
          s += q[d].x * kv.x + q[d].y * kv.y + q[d].z * kv.z + q[d].w * kv.w;
        }
        s *= 0.17677669529663687f;
        lg[kk] = s;
        mx = fmaxf(mx, s);
      }
      float sum = 0.f;
#pragma unroll
      for (int kk = 0; kk < 9; ++kk) { lg[kk] = __expf(lg[kk] - mx); sum += lg[kk]; }
      const float inv = 1.f / sum;
#pragma unroll
      for (int kk = 0; kk < 9; ++kk)
        sm.scratch[SC_ATT + (px * 4 + h) * 9 + kk] = lg[kk] * inv;
    }
    // ---- v = ctx_n @ wkv[:, 128:] + b' ----
    __syncthreads();
    stage_panel(P + 2 * PANEL_U16, sm.wbuf, tid);
    __syncthreads();
    mfma_g96(sm.ctxn, sm.wbuf, acc, lane, ct96);
#pragma unroll
    for (int t = 0; t < 2; ++t) {
      const int n = (ct96 + t) * 16 + nl;
      const float bb = wsb[l * 256 + 128 + n];
#pragma unroll
      for (int r6 = 0; r6 < 6; ++r6) {
#pragma unroll
        for (int r = 0; r < 4; ++r) {
          const int row = r6 * 16 + qm + r;
          if (row < 72) sm.kvb[row * KV_S + n] = acc[r6 * 2 + t][r] + bb;
        }
      }
    }
    __syncthreads();
    // ---- o = attn @ v -> xn (bf16, A-operand layout) ----
    {
      const int px = tid >> 3, cg = tid & 7, c0 = cg * 16;
      const int lr = (px >> 4) * 4 + ((px & 7) >> 1);
      const float* awp = sm.scratch + SC_ATT + (px * 4 + (cg >> 1)) * 9;
      float o[16];
#pragma unroll
      for (int j = 0; j < 16; ++j) o[j] = 0.f;
#pragma unroll
      for (int kk = 0; kk < 9; ++kk) {
        const float a = awp[kk];
        const float4* vr = reinterpret_cast<const float4*>(sm.kvb + (lr * 9 + kk) * KV_S + c0);
#pragma unroll
        for (int j = 0; j < 4; ++j) {
          const float4 v = vr[j];
          o[j * 4 + 0] += a * v.x; o[j * 4 + 1] += a * v.y;
          o[j * 4 + 2] += a * v.z; o[j * 4 + 3] += a * v.w;
        }
      }
      unsigned short tmp[16];
#pragma unroll
      for (int j = 0; j < 16; ++j) tmp[j] = f2bf(o[j]);
      *reinterpret_cast<u16x8*>(sm.xn + px * BSTR + c0) = *reinterpret_cast<u16x8*>(tmp);
      *reinterpret_cast<u16x8*>(sm.xn + px * BSTR + c0 + 8) = *reinterpret_cast<u16x8*>(tmp + 8);
    }
    // ---- x += o @ wo + bo ----
    __syncthreads();
    stage_panel(P + 3 * PANEL_U16, sm.wbuf, tid);
    __syncthreads();
    mfma_g32(sm.xn, sm.wbuf, acc, lane, rt, ct0, true);
#pragma unroll
    for (int t = 0; t < 4; ++t) {
      const int n = (ct0 + t) * 16 + nl;
      const float bb = bo[l * 128 + n];
#pragma unroll
      for (int r = 0; r < 4; ++r)
        sm.xs[(rt * 16 + qm + r) * XS_S + n] += acc[t][r] + bb;
    }
    __syncthreads();
    // ---- MLP ----
    layernorm_x_bf(sm.xs, sm.xn, sm.scratch, tid);
    f32x4 xd[4];
    for (int cc = 0; cc < 4; ++cc) {
      __syncthreads();
      stage_panel(P + (4 + cc) * PANEL_U16, sm.wbuf, tid);
      __syncthreads();
      mfma_g32(sm.xn, sm.wbuf, acc, lane, rt, ct0, true);
#pragma unroll
      for (int t = 0; t < 4; ++t) {
        const int n = (ct0 + t) * 16 + nl;
        const float bb = b1[l * 512 + cc * 128 + n];
#pragma unroll
        for (int r = 0; r < 4; ++r)
          sm.hb[(rt * 16 + qm + r) * BSTR + n] = f2bf(gelu_tanh(acc[t][r] + bb));
      }
      __syncthreads();
      stage_panel(P + (8 + cc) * PANEL_U16, sm.wbuf, tid);
      __syncthreads();
      mfma_g32(sm.hb, sm.wbuf, xd, lane, rt, ct0, cc == 0);
    }
#pragma unroll
    for (int t = 0; t < 4; ++t) {
      const int n = (ct0 + t) * 16 + nl;
      const float bb = b2[l * 128 + n];
#pragma unroll
      for (int r = 0; r < 4; ++r)
        sm.xs[(rt * 16 + qm + r) * XS_S + n] += xd[t][r] + bb;
    }
    __syncthreads();
  }  // layers

  // ---- final ----
  layernorm_x_bf(sm.xs, sm.xn, sm.scratch, tid);
  __syncthreads();
  stage_panel(wsp + 24 * PANEL_U16, sm.wbuf, tid);
  __syncthreads();
  mfma_g32(sm.xn, sm.wbuf, acc, lane, rt, ct0, true);
#pragma unroll
  for (int t = 0; t < 4; ++t) {
    const int n = (ct0 + t) * 16 + nl;
    const float bb = bqf[n];
#pragma unroll
    for (int r = 0; r < 4; ++r)
      sm.outb[(rt * 16 + qm + r) * QB_S + n] = acc[t][r] + bb;
  }
  __syncthreads();
  stage_panel(wsp + 25 * PANEL_U16, sm.wbuf, tid);
  __syncthreads();
  mfma_g96(sm.ctxn, sm.wbuf, acc, lane, ct96);
#pragma unroll
  for (int t = 0; t < 2; ++t) {
    const int n = (ct96 + t) * 16 + nl;
    const float bb = bcf[n];
#pragma unroll
    for (int r6 = 0; r6 < 6; ++r6) {
#pragma unroll
      for (int r = 0; r < 4; ++r) {
        const int row = r6 * 16 + qm + r;
        if (row < 72) sm.kvb[row * KV_S + n] = acc[r6 * 2 + t][r] + bb;
      }
    }
  }
  __syncthreads();
  {
    const int px = tid >> 3, sub = tid & 7;
    const int lr = (px >> 4) * 4 + ((px & 7) >> 1);
    const float* qrow = sm.outb + px * QB_S;
    {
      const float* crow = sm.kvb + (lr * 9 + sub) * KV_S;
      float s = 0.f;
#pragma unroll 8
      for (int c = 0; c < 128; c += 4) {
        const float4 qv = *reinterpret_cast<const float4*>(qrow + c);
        const float4 cv = *reinterpret_cast<const float4*>(crow + c);
        s += qv.x * cv.x + qv.y * cv.y + qv.z * cv.z + qv.w * cv.w;
      }
      sm.scratch[SC_LG + px * 12 + sub] = s;
    }
    if (sub == 0) {
      const float* crow = sm.kvb + (lr * 9 + 8) * KV_S;
      float s = 0.f;
#pragma unroll 8
      for (int c = 0; c < 128; c += 4) {
        const float4 qv = *reinterpret_cast<const float4*>(qrow + c);
        const float4 cv = *reinterpret_cast<const float4*>(crow + c);
        s += qv.x * cv.x + qv.y * cv.y + qv.z * cv.z + qv.w * cv.w;
      }
      sm.scratch[SC_LG + px * 12 + 8] = s;
    }
  }
  __syncthreads();
  if (tid < 32) {
    const int px = tid;
    const int hu = hu0 + (px >> 3), wu = wu0 + (px & 7);
    float lg[9], mx = -1e30f;
#pragma unroll
    for (int kk = 0; kk < 9; ++kk) {
      lg[kk] = sm.scratch[SC_LG + px * 12 + kk] * 0.08838834764831845f;
      mx = fmaxf(mx, lg[kk]);
    }
    float sum = 0.f;
#pragma unroll
    for (int kk = 0; kk < 9; ++kk) { lg[kk] = __expf(lg[kk] - mx); sum += lg[kk]; }
    const float inv = 1.f / sum;
#pragma unroll
    for (int kk = 0; kk < 9; ++kk)
      out[((bz * 9 + kk) * HuC + hu) * WuC + wu] = lg[kk] * inv;
  }
}

}  // namespace

extern "C" void kernel_launch(void* const* d_in, const int* in_sizes, int n_in,
                              void* d_out, int out_size, void* d_ws, size_t ws_size,
                              hipStream_t stream) {
  const float* fm   = (const float*)d_in[0];
  const float* fmu  = (const float*)d_in[1];
  const float* nc_w = (const float*)d_in[2];
  const float* nc_b = (const float*)d_in[3];
  const float* wq   = (const float*)d_in[4];
  const float* bq   = (const float*)d_in[5];
  const float* wkv  = (const float*)d_in[6];
  const float* bkv  = (const float*)d_in[7];
  const float* wo   = (const float*)d_in[8];
  const float* bo   = (const float*)d_in[9];
  const float* w1   = (const float*)d_in[10];
  const float* b1   = (const float*)d_in[11];
  const float* w2   = (const float*)d_in[12];
  const float* b2   = (const float*)d_in[13];
  const float* wqf  = (const float*)d_in[14];
  const float* bqf  = (const float*)d_in[15];
  const float* wcf  = (const float*)d_in[16];
  const float* bcf  = (const float*)d_in[17];
  float* out = (float*)d_out;

  dim3 grid(24, 32, 2);
  if (ws_size >= WS_NEEDED) {
    unsigned short* wsp = (unsigned short*)d_ws;
    float* wsb = (float*)((char*)d_ws + (size_t)N_PANELS * PANEL_U16 * 2);
    prep_weights<<<dim3(106), dim3(THREADS), 0, stream>>>(
        nc_w, nc_b, wq, wkv, bkv, wo, w1, w2, wqf, wcf, wsp, wsb);
    fused_interp_mfma<<<grid, dim3(THREADS), 0, stream>>>(
        fm, fmu, bq, bo, b1, b2, bqf, bcf, wsp, wsb, out);
  } else {
    fused_interp_kernel<<<grid, dim3(THREADS), 0, stream>>>(
        fm, fmu, nc_w, nc_b, wq, bq, wkv, bkv, wo, bo, w1, b1, w2, b2,
        wqf, bqf, wcf, bcf, out);
  }
}

// Round 3
// 476.520 us; speedup vs baseline: 3.8313x; 1.1508x over previous
//
#include <hip/hip_runtime.h>

namespace {

constexpr int THREADS = 256;
constexpr int HdC = 64, WdC = 96, HuC = 128, WuC = 192;

// ======================= shared helpers =======================

__device__ __forceinline__ float gelu_tanh(float x) {
  float z = 0.7978845608028654f * (x + 0.044715f * x * x * x);
  float e = __expf(2.0f * z);
  float t = 1.0f - 2.0f / (e + 1.0f);
  return 0.5f * x * (1.0f + t);
}

__device__ __forceinline__ unsigned short f2bf(float f) {
  unsigned int u = __builtin_bit_cast(unsigned int, f);
  u = (u + 0x7FFFu + ((u >> 16) & 1u)) >> 16;  // RNE
  return (unsigned short)u;
}

__device__ __forceinline__ float bf2f(unsigned short u) {
  unsigned int x = ((unsigned int)u) << 16;
  return __builtin_bit_cast(float, x);
}

// ======================= fp32 fallback path (round-1, verified) =======================

constexpr int CTX_S = 80;
constexpr int KV_S  = 132;
constexpr int XS_S  = 132;
constexpr int XN_S  = 32;
constexpr int OB_S  = 144;

constexpr int SC_ATT = 0;
constexpr int SC_RED = 0;
constexpr int SC_MU  = 768;
constexpr int SC_RS  = 864;
constexpr int SC_NC  = 1152;
constexpr int SC_LG  = 0;

struct alignas(16) Smem {
  float ctxT[128 * CTX_S];
  float kvb[72 * KV_S];
  float xs[32 * XS_S];
  float xnT[128 * XN_S];
  float outb[32 * OB_S];
  float wbuf[32 * 128];
  float scratch[1536];
};
static_assert(sizeof(Smem) <= 160 * 1024, "LDS budget");

__device__ __forceinline__ void stage_w(const float* __restrict__ W, int wstride,
                                        int kc, float* wbuf, int tid) {
#pragma unroll
  for (int p = 0; p < 4; ++p) {
    int e = tid + p * THREADS;
    int r = e >> 5;
    int c4 = (e & 31) << 2;
    const float4 v = *reinterpret_cast<const float4*>(W + (kc * 32 + r) * wstride + c4);
    *reinterpret_cast<float4*>(wbuf + r * 128 + c4) = v;
  }
}

#define FMA_ROW(ac, s, w)                                            \
  {                                                                  \
    (ac)[0] += (s) * (w).x; (ac)[1] += (s) * (w).y;                  \
    (ac)[2] += (s) * (w).z; (ac)[3] += (s) * (w).w;                  \
  }

__device__ __forceinline__ void gemm32(const float* __restrict__ W, int wstride,
                                       const float* AT, float* wbuf, int tid,
                                       float acc[16]) {
  const int row0 = (tid >> 5) << 2;
  const int col0 = (tid & 31) << 2;
#pragma unroll
  for (int i = 0; i < 16; ++i) acc[i] = 0.f;
  for (int kc = 0; kc < 4; ++kc) {
    __syncthreads();
    stage_w(W, wstride, kc, wbuf, tid);
    __syncthreads();
#pragma unroll 4
    for (int cl = 0; cl < 32; ++cl) {
      const int c = (kc << 5) + cl;
      const float4 a = *reinterpret_cast<const float4*>(AT + c * XN_S + row0);
      const float4 w = *reinterpret_cast<const float4*>(wbuf + cl * 128 + col0);
      FMA_ROW(acc + 0, a.x, w);
      FMA_ROW(acc + 4, a.y, w);
      FMA_ROW(acc + 8, a.z, w);
      FMA_ROW(acc + 12, a.w, w);
    }
  }
}

template <bool NC>
__device__ __forceinline__ void gemm96(const float* __restrict__ W, int wstride,
                                       const float* ctxT, float* wbuf, float* kvb,
                                       const float* __restrict__ bias,
                                       const float* nc, int tid) {
  const int rt4 = (tid >> 5) << 2;
  const int col0 = (tid & 31) << 2;
  float acc[48];
#pragma unroll
  for (int i = 0; i < 48; ++i) acc[i] = 0.f;
  for (int kc = 0; kc < 4; ++kc) {
    __syncthreads();
    stage_w(W, wstride, kc, wbuf, tid);
    __syncthreads();
#pragma unroll 2
    for (int cl = 0; cl < 32; ++cl) {
      const int c = (kc << 5) + cl;
      const float4 w = *reinterpret_cast<const float4*>(wbuf + cl * 128 + col0);
      float s = 0.f, t = 0.f;
      if (NC) { s = nc[c]; t = nc[128 + c]; }
      const float* base = ctxT + c * CTX_S;
#pragma unroll
      for (int p = 0; p < 3; ++p) {
        int r0 = p * 32 + rt4;
        if (r0 > 76) r0 = 76;
        float4 a = *reinterpret_cast<const float4*>(base + r0);
        if (NC) {
          a.x = a.x * s + t; a.y = a.y * s + t;
          a.z = a.z * s + t; a.w = a.w * s + t;
        }
        float* ac = acc + p * 16;
        FMA_ROW(ac + 0, a.x, w);
        FMA_ROW(ac + 4, a.y, w);
        FMA_ROW(ac + 8, a.z, w);
        FMA_ROW(ac + 12, a.w, w);
      }
    }
  }
  const float4 bv = *reinterpret_cast<const float4*>(bias + col0);
#pragma unroll
  for (int p = 0; p < 3; ++p) {
    const int r0 = p * 32 + rt4;
    if (r0 < 72) {
#pragma unroll
      for (int i = 0; i < 4; ++i) {
        float4 o;
        o.x = acc[p * 16 + i * 4 + 0] + bv.x;
        o.y = acc[p * 16 + i * 4 + 1] + bv.y;
        o.z = acc[p * 16 + i * 4 + 2] + bv.z;
        o.w = acc[p * 16 + i * 4 + 3] + bv.w;
        *reinterpret_cast<float4*>(kvb + (r0 + i) * KV_S + col0) = o;
      }
    }
  }
}

__device__ __forceinline__ void layernorm_x(const float* xs, float* xnT,
                                            float* scratch, int tid) {
  const int px = tid & 31;
  const int cg = tid >> 5;
  float s1 = 0.f, s2 = 0.f;
#pragma unroll
  for (int i = 0; i < 16; ++i) {
    const float v = xs[px * XS_S + cg * 16 + i];
    s1 += v; s2 += v * v;
  }
  scratch[SC_RED + cg * 96 + px] = s1;
  scratch[SC_RED + cg * 96 + 48 + px] = s2;
  __syncthreads();
  if (tid < 32) {
    float a = 0.f, b = 0.f;
#pragma unroll
    for (int g = 0; g < 8; ++g) {
      a += scratch[SC_RED + g * 96 + tid];
      b += scratch[SC_RED + g * 96 + 48 + tid];
    }
    const float m = a * (1.f / 128.f);
    const float v = b * (1.f / 128.f) - m * m;
    scratch[SC_MU + tid] = m;
    scratch[SC_RS + tid] = rsqrtf(v + 1e-6f);
  }
  __syncthreads();
  const float m = scratch[SC_MU + px];
  const float r = scratch[SC_RS + px];
#pragma unroll
  for (int i = 0; i < 16; ++i) {
    const int c = cg * 16 + i;
    xnT[c * XN_S + px] = (xs[px * XS_S + c] - m) * r;
  }
}

__global__ __launch_bounds__(THREADS, 1) void fused_interp_kernel(
    const float* __restrict__ fm, const float* __restrict__ fmu,
    const float* __restrict__ nc_w, const float* __restrict__ nc_b,
    const float* __restrict__ wq, const float* __restrict__ bq,
    const float* __restrict__ wkv, const float* __restrict__ bkv,
    const float* __restrict__ wo, const float* __restrict__ bo,
    const float* __restrict__ w1, const float* __restrict__ b1,
    const float* __restrict__ w2, const float* __restrict__ b2,
    const float* __restrict__ wqf, const float* __restrict__ bqf,
    const float* __restrict__ wcf, const float* __restrict__ bcf,
    float* __restrict__ out) {
  __shared__ Smem sm;
  const int tid = threadIdx.x;
  const int bx = blockIdx.x;
  const int by = blockIdx.y;
  const int bz = blockIdx.z;
  const int lh0 = by * 2, lw0 = bx * 4;
  const int hu0 = by * 4, wu0 = bx * 8;

#pragma unroll
  for (int p = 0; p < 16; ++p) {
    const int idx = tid + p * THREADS;
    const int c = idx >> 5;
    const int px = idx & 31;
    const int hu = hu0 + (px >> 3);
    const int wu = wu0 + (px & 7);
    sm.xs[px * XS_S + c] = fmu[((bz * 128 + c) * HuC + hu) * WuC + wu];
  }

  for (int pass = 0; pass < 2; ++pass) {
    const int rl = tid >> 2;
    const int sub = tid & 3;
    const int r = pass * 64 + rl;
    const bool act = (r < 72);
    int base = 0;
    if (act) {
      const int lr = r / 9, kk = r % 9;
      const int hdp = lh0 + (lr >> 2);
      const int wdp = lw0 + (lr & 3);
      const int ki = kk / 3, kj = kk % 3;
      int hs = hdp + ki - 1; hs = hs < 0 ? 0 : (hs > HdC - 1 ? HdC - 1 : hs);
      int ws = wdp + kj - 1; ws = ws < 0 ? 0 : (ws > WdC - 1 ? WdC - 1 : ws);
      base = (bz * 128) * HdC * WdC + hs * WdC + ws;
      float s1 = 0.f, s2 = 0.f;
      for (int i = 0; i < 32; ++i) {
        const float v = fm[base + (sub * 32 + i) * (HdC * WdC)];
        s1 += v; s2 += v * v;
      }
      sm.scratch[SC_RED + sub * 64 + rl] = s1;
      sm.scratch[SC_RED + 384 + sub * 64 + rl] = s2;
    }
    __syncthreads();
    if (tid < 64 && pass * 64 + tid < 72) {
      float a = 0.f, b = 0.f;
#pragma unroll
      for (int s = 0; s < 4; ++s) {
        a += sm.scratch[SC_RED + s * 64 + tid];
        b += sm.scratch[SC_RED + 384 + s * 64 + tid];
      }
      const float m = a * (1.f / 128.f);
      const float v = b * (1.f / 128.f) - m * m;
      sm.scratch[SC_MU + pass * 64 + tid] = m;
      sm.scratch[SC_RS + pass * 64 + tid] = rsqrtf(v + 1e-6f);
    }
    __syncthreads();
    if (act) {
      const float m = sm.scratch[SC_MU + r];
      const float rr = sm.scratch[SC_RS + r];
      for (int i = 0; i < 32; ++i) {
        const int c = sub * 32 + i;
        const float v = fm[base + c * (HdC * WdC)];
        sm.ctxT[c * CTX_S + r] = (v - m) * rr;
      }
    }
    __syncthreads();
  }
  if (tid < 128) {
#pragma unroll
    for (int r = 72; r < 80; ++r) sm.ctxT[tid * CTX_S + r] = 0.f;
  }
  __syncthreads();

  const int row0 = (tid >> 5) << 2;
  const int col0 = (tid & 31) << 2;
  float acc[16];

  for (int l = 0; l < 2; ++l) {
    if (tid < 128) sm.scratch[SC_NC + tid] = nc_w[l * 128 + tid];
    else           sm.scratch[SC_NC + tid] = nc_b[l * 128 + (tid - 128)];

    layernorm_x(sm.xs, sm.xnT, sm.scratch, tid);
    gemm32(wq + l * 16384, 128, sm.xnT, sm.wbuf, tid, acc);
    {
      const float4 bv = *reinterpret_cast<const float4*>(bq + l * 128 + col0);
#pragma unroll
      for (int i = 0; i < 4; ++i) {
        float4 o;
        o.x = acc[i * 4 + 0] + bv.x; o.y = acc[i * 4 + 1] + bv.y;
        o.z = acc[i * 4 + 2] + bv.z; o.w = acc[i * 4 + 3] + bv.w;
        *reinterpret_cast<float4*>(sm.outb + (row0 + i) * OB_S + col0) = o;
      }
    }
    gemm96<true>(wkv + l * 32768, 256, sm.ctxT, sm.wbuf, sm.kvb,
                 bkv + l * 256, sm.scratch + SC_NC, tid);
    __syncthreads();
    if (tid < 128) {
      const int px = tid >> 2, h = tid & 3;
      const int lr = (((px >> 3) >> 1) << 2) | ((px & 7) >> 1);
      const float* qrow = sm.outb + px * OB_S + h * 32;
      float4 q[8];
#pragma unroll
      for (int d = 0; d < 8; ++d) q[d] = *reinterpret_cast<const float4*>(qrow + d * 4);
      float lg[9];
      float mx = -1e30f;
#pragma unroll
      for (int kk = 0; kk < 9; ++kk) {
        const float* krow = sm.kvb + (lr * 9 + kk) * KV_S + h * 32;
        float s = 0.f;
#pragma unroll
        for (int d = 0; d < 8; ++d) {
          const float4 kv = *reinterpret_cast<const float4*>(krow + d * 4);
          s += q[d].x * kv.x + q[d].y * kv.y + q[d].z * kv.z + q[d].w * kv.w;
        }
        s *= 0.17677669529663687f;
        lg[kk] = s;
        mx = fmaxf(mx, s);
      }
      float sum = 0.f;
#pragma unroll
      for (int kk = 0; kk < 9; ++kk) { lg[kk] = __expf(lg[kk] - mx); sum += lg[kk]; }
      const float inv = 1.f / sum;
#pragma unroll
      for (int kk = 0; kk < 9; ++kk)
        sm.scratch[SC_ATT + (px * 4 + h) * 9 + kk] = lg[kk] * inv;
    }
    __syncthreads();
    gemm96<true>(wkv + l * 32768 + 128, 256, sm.ctxT, sm.wbuf, sm.kvb,
                 bkv + l * 256 + 128, sm.scratch + SC_NC, tid);
    __syncthreads();
    {
      const int c = tid & 127, pg = tid >> 7;
      const int h = c >> 5;
#pragma unroll 4
      for (int i = 0; i < 16; ++i) {
        const int px = pg * 16 + i;
        const int lr = (((px >> 3) >> 1) << 2) | ((px & 7) >> 1);
        const float* aw = sm.scratch + SC_ATT + (px * 4 + h) * 9;
        float s = 0.f;
#pragma unroll
        for (int kk = 0; kk < 9; ++kk) s += aw[kk] * sm.kvb[(lr * 9 + kk) * KV_S + c];
        sm.xnT[c * XN_S + px] = s;
      }
    }
    gemm32(wo + l * 16384, 128, sm.xnT, sm.wbuf, tid, acc);
    {
      const float4 bv = *reinterpret_cast<const float4*>(bo + l * 128 + col0);
#pragma unroll
      for (int i = 0; i < 4; ++i) {
        float* xr = sm.xs + (row0 + i) * XS_S + col0;
        float4 x = *reinterpret_cast<float4*>(xr);
        x.x += acc[i * 4 + 0] + bv.x; x.y += acc[i * 4 + 1] + bv.y;
        x.z += acc[i * 4 + 2] + bv.z; x.w += acc[i * 4 + 3] + bv.w;
        *reinterpret_cast<float4*>(xr) = x;
      }
    }
    __syncthreads();
    layernorm_x(sm.xs, sm.xnT, sm.scratch, tid);
    float xd[16];
#pragma unroll
    for (int i = 0; i < 16; ++i) xd[i] = 0.f;
    for (int cc = 0; cc < 4; ++cc) {
      gemm32(w1 + l * 65536 + cc * 128, 512, sm.xnT, sm.wbuf, tid, acc);
      {
        const float4 bv = *reinterpret_cast<const float4*>(b1 + l * 512 + cc * 128 + col0);
#pragma unroll
        for (int i = 0; i < 4; ++i) {
          float4 o;
          o.x = gelu_tanh(acc[i * 4 + 0] + bv.x);
          o.y = gelu_tanh(acc[i * 4 + 1] + bv.y);
          o.z = gelu_tanh(acc[i * 4 + 2] + bv.z);
          o.w = gelu_tanh(acc[i * 4 + 3] + bv.w);
          *reinterpret_cast<float4*>(sm.outb + (row0 + i) * OB_S + col0) = o;
        }
      }
      __syncthreads();
      const float* w2c = w2 + l * 65536 + cc * 16384;
      for (int kc = 0; kc < 4; ++kc) {
        __syncthreads();
        stage_w(w2c, 128, kc, sm.wbuf, tid);
        __syncthreads();
#pragma unroll 4
        for (int cl = 0; cl < 32; ++cl) {
          const int c = (kc << 5) + cl;
          const float a0 = sm.outb[(row0 + 0) * OB_S + c];
          const float a1 = sm.outb[(row0 + 1) * OB_S + c];
          const float a2 = sm.outb[(row0 + 2) * OB_S + c];
          const float a3 = sm.outb[(row0 + 3) * OB_S + c];
          const float4 w = *reinterpret_cast<const float4*>(sm.wbuf + cl * 128 + col0);
          FMA_ROW(xd + 0, a0, w);
          FMA_ROW(xd + 4, a1, w);
          FMA_ROW(xd + 8, a2, w);
          FMA_ROW(xd + 12, a3, w);
        }
      }
    }
    {
      const float4 bv = *reinterpret_cast<const float4*>(b2 + l * 128 + col0);
#pragma unroll
      for (int i = 0; i < 4; ++i) {
        float* xr = sm.xs + (row0 + i) * XS_S + col0;
        float4 x = *reinterpret_cast<float4*>(xr);
        x.x += xd[i * 4 + 0] + bv.x; x.y += xd[i * 4 + 1] + bv.y;
        x.z += xd[i * 4 + 2] + bv.z; x.w += xd[i * 4 + 3] + bv.w;
        *reinterpret_cast<float4*>(xr) = x;
      }
    }
    __syncthreads();
  }

  layernorm_x(sm.xs, sm.xnT, sm.scratch, tid);
  gemm32(wqf, 128, sm.xnT, sm.wbuf, tid, acc);
  {
    const float4 bv = *reinterpret_cast<const float4*>(bqf + col0);
#pragma unroll
    for (int i = 0; i < 4; ++i) {
      float4 o;
      o.x = acc[i * 4 + 0] + bv.x; o.y = acc[i * 4 + 1] + bv.y;
      o.z = acc[i * 4 + 2] + bv.z; o.w = acc[i * 4 + 3] + bv.w;
      *reinterpret_cast<float4*>(sm.outb + (row0 + i) * OB_S + col0) = o;
    }
  }
  gemm96<false>(wcf, 128, sm.ctxT, sm.wbuf, sm.kvb, bcf, nullptr, tid);
  __syncthreads();
  {
    const int px = tid >> 3, sub = tid & 7;
    const int lr = (((px >> 3) >> 1) << 2) | ((px & 7) >> 1);
    const float* qrow = sm.outb + px * OB_S;
    {
      const float* crow = sm.kvb + (lr * 9 + sub) * KV_S;
      float s = 0.f;
#pragma unroll 8
      for (int c = 0; c < 128; c += 4) {
        const float4 qv = *reinterpret_cast<const float4*>(qrow + c);
        const float4 cv = *reinterpret_cast<const float4*>(crow + c);
        s += qv.x * cv.x + qv.y * cv.y + qv.z * cv.z + qv.w * cv.w;
      }
      sm.scratch[SC_LG + px * 12 + sub] = s;
    }
    if (sub == 0) {
      const float* crow = sm.kvb + (lr * 9 + 8) * KV_S;
      float s = 0.f;
#pragma unroll 8
      for (int c = 0; c < 128; c += 4) {
        const float4 qv = *reinterpret_cast<const float4*>(qrow + c);
        const float4 cv = *reinterpret_cast<const float4*>(crow + c);
        s += qv.x * cv.x + qv.y * cv.y + qv.z * cv.z + qv.w * cv.w;
      }
      sm.scratch[SC_LG + px * 12 + 8] = s;
    }
  }
  __syncthreads();
  if (tid < 32) {
    const int px = tid;
    const int hu = hu0 + (px >> 3), wu = wu0 + (px & 7);
    float lg[9], mx = -1e30f;
#pragma unroll
    for (int kk = 0; kk < 9; ++kk) {
      lg[kk] = sm.scratch[SC_LG + px * 12 + kk] * 0.08838834764831845f;
      mx = fmaxf(mx, lg[kk]);
    }
    float sum = 0.f;
#pragma unroll
    for (int kk = 0; kk < 9; ++kk) { lg[kk] = __expf(lg[kk] - mx); sum += lg[kk]; }
    const float inv = 1.f / sum;
#pragma unroll
    for (int kk = 0; kk < 9; ++kk)
      out[((bz * 9 + kk) * HuC + hu) * WuC + wu] = lg[kk] * inv;
  }
}

// ======================= MFMA path (v3) =======================
// 512 thr / 64 px / reg-resident x / weights direct global->VGPR (no staging barriers)

constexpr int TM = 512;                   // 8 waves
constexpr int PANEL = 16384;              // u16 per 128x128 panel, [n][k] layout
constexpr int N_PANELS = 26;
constexpr size_t WS_NEEDED = (size_t)N_PANELS * PANEL * 2 + 2048;
constexpr int CBS = 136;                  // bf16 LDS row stride
constexpr int XTS = 132;                  // fp32 temp stride

constexpr int MSC_ATT = 0;                // 2304: attn probs [px][h][9]; patch partials; final logits [px][12]
constexpr int MSC_LN  = 2304;             // 256: LN partials [px][4]
constexpr int MSC_ST  = 2560;             // 80: patch stats [40][2]
constexpr int MSC_N   = 2816;

typedef __attribute__((ext_vector_type(8))) short bf16x8;
typedef __attribute__((ext_vector_type(4))) float f32x4;
typedef __attribute__((ext_vector_type(8))) unsigned short u16x8;

struct alignas(16) SmemM {
  unsigned short ctxn[144 * CBS];   // 39168 B
  unsigned short kvb[144 * CBS];    // 39168 B; aliased: xtmp f32[64*132], patch f32[40*132]
  unsigned short xn[64 * CBS];      // 17408 B
  unsigned short hb[64 * CBS];      // 17408 B
  unsigned short outb[64 * CBS];    // 17408 B
  float scratch[MSC_N];             // 11264 B
};
static_assert(sizeof(SmemM) <= 160 * 1024, "LDS budget (mfma)");

__global__ void prep_weights(
    const float* __restrict__ nc_w, const float* __restrict__ nc_b,
    const float* __restrict__ wq, const float* __restrict__ wkv,
    const float* __restrict__ bkv,
    const float* __restrict__ wo, const float* __restrict__ w1,
    const float* __restrict__ w2, const float* __restrict__ wqf,
    const float* __restrict__ wcf,
    unsigned short* __restrict__ wsp, float* __restrict__ wsb) {
  const int b = blockIdx.x;
  const int t = threadIdx.x;
  if (b >= 104) {  // adjusted kv bias: b' = bkv + nc_b @ wkv
    const int l = b - 104;
    float acc = bkv[l * 256 + t];
    for (int k = 0; k < 128; ++k)
      acc += nc_b[l * 128 + k] * wkv[l * 32768 + k * 256 + t];
    wsb[l * 256 + t] = acc;
    return;
  }
  const int pid = b >> 2, qtr = b & 3;
  const float* src = wqf; int N = 128, koff = 0, noff = 0;
  const float* sc = nullptr;
  if (pid < 24) {
    const int l = pid / 12, loc = pid % 12;
    if (loc == 0)      { src = wq + l * 16384;  N = 128; }
    else if (loc == 1) { src = wkv + l * 32768; N = 256; sc = nc_w + l * 128; }
    else if (loc == 2) { src = wkv + l * 32768; N = 256; noff = 128; sc = nc_w + l * 128; }
    else if (loc == 3) { src = wo + l * 16384;  N = 128; }
    else if (loc < 8)  { src = w1 + l * 65536;  N = 512; noff = (loc - 4) * 128; }
    else               { src = w2 + l * 65536;  N = 128; koff = (loc - 8) * 128; }
  } else if (pid == 25) { src = wcf; }
  unsigned short* dst = wsp + pid * PANEL;
#pragma unroll
  for (int p = 0; p < 2; ++p) {
    const int e = t + p * 256;
    const int n = e & 127;
    const int kg = e >> 7;
    const int k0 = qtr * 32 + kg * 8;
    unsigned short tmp[8];
#pragma unroll
    for (int i = 0; i < 8; ++i) {
      const float s = sc ? sc[k0 + i] : 1.f;
      tmp[i] = f2bf(src[(k0 + i + koff) * N + noff + n] * s);
    }
    *reinterpret_cast<u16x8*>(dst + n * 128 + k0) = *reinterpret_cast<u16x8*>(tmp);
  }
}

__device__ __forceinline__ void mfma64(const unsigned short* A,
                                       const unsigned short* __restrict__ W,
                                       f32x4 acc[4], int nl, int q8, int rt, int ct0,
                                       bool init) {
  bf16x8 b[4][4];
#pragma unroll
  for (int t = 0; t < 4; ++t)
#pragma unroll
    for (int ks = 0; ks < 4; ++ks)
      b[t][ks] = *reinterpret_cast<const bf16x8*>(W + ((ct0 + t) * 16 + nl) * 128 + ks * 32 + q8);
  if (init) {
#pragma unroll
    for (int t = 0; t < 4; ++t) acc[t] = (f32x4){0.f, 0.f, 0.f, 0.f};
  }
#pragma unroll
  for (int ks = 0; ks < 4; ++ks) {
    const bf16x8 a = *reinterpret_cast<const bf16x8*>(A + (rt * 16 + nl) * CBS + ks * 32 + q8);
#pragma unroll
    for (int t = 0; t < 4; ++t)
      acc[t] = __builtin_amdgcn_mfma_f32_16x16x32_bf16(a, b[t][ks], acc[t], 0, 0, 0);
  }
}

__device__ __forceinline__ void mfma144(const unsigned short* Ctx,
                                        const unsigned short* __restrict__ W,
                                        f32x4 acc[9], int nl, int q8, int ctw) {
  bf16x8 b[4];
#pragma unroll
  for (int ks = 0; ks < 4; ++ks)
    b[ks] = *reinterpret_cast<const bf16x8*>(W + (ctw * 16 + nl) * 128 + ks * 32 + q8);
#pragma unroll
  for (int i = 0; i < 9; ++i) acc[i] = (f32x4){0.f, 0.f, 0.f, 0.f};
#pragma unroll
  for (int ks = 0; ks < 4; ++ks)
#pragma unroll
    for (int rt = 0; rt < 9; ++rt) {
      const bf16x8 a = *reinterpret_cast<const bf16x8*>(Ctx + (rt * 16 + nl) * CBS + ks * 32 + q8);
      acc[rt] = __builtin_amdgcn_mfma_f32_16x16x32_bf16(a, b[ks], acc[rt], 0, 0, 0);
    }
}

__device__ __forceinline__ void ln_x(const float (&xr)[4][4], unsigned short* xn,
                                     float* scratch, int wave, int rt, int ct0,
                                     int nl, int qm) {
  float s1[4], s2[4];
#pragma unroll
  for (int r = 0; r < 4; ++r) {
    s1[r] = xr[r][0] + xr[r][1] + xr[r][2] + xr[r][3];
    s2[r] = xr[r][0] * xr[r][0] + xr[r][1] * xr[r][1] +
            xr[r][2] * xr[r][2] + xr[r][3] * xr[r][3];
  }
#pragma unroll
  for (int m = 1; m < 16; m <<= 1) {
#pragma unroll
    for (int r = 0; r < 4; ++r) {
      s1[r] += __shfl_xor(s1[r], m, 64);
      s2[r] += __shfl_xor(s2[r], m, 64);
    }
  }
  if (nl == 0) {
#pragma unroll
    for (int r = 0; r < 4; ++r) {
      const int px = rt * 16 + qm + r;
      scratch[MSC_LN + px * 4 + (wave & 1) * 2 + 0] = s1[r];
      scratch[MSC_LN + px * 4 + (wave & 1) * 2 + 1] = s2[r];
    }
  }
  __syncthreads();
#pragma unroll
  for (int r = 0; r < 4; ++r) {
    const int px = rt * 16 + qm + r;
    const float a = scratch[MSC_LN + px * 4 + 0] + scratch[MSC_LN + px * 4 + 2];
    const float b = scratch[MSC_LN + px * 4 + 1] + scratch[MSC_LN + px * 4 + 3];
    const float m = a * (1.f / 128.f);
    const float v = b * (1.f / 128.f) - m * m;
    const float rs = rsqrtf(v + 1e-6f);
#pragma unroll
    for (int t = 0; t < 4; ++t)
      xn[px * CBS + (ct0 + t) * 16 + nl] = f2bf((xr[r][t] - m) * rs);
  }
  __syncthreads();
}

__global__ __launch_bounds__(TM, 1) void fused_interp_mfma(
    const float* __restrict__ fm, const float* __restrict__ fmu,
    const float* __restrict__ bq, const float* __restrict__ bo,
    const float* __restrict__ b1, const float* __restrict__ b2,
    const float* __restrict__ bqf, const float* __restrict__ bcf,
    const unsigned short* __restrict__ wsp, const float* __restrict__ wsb,
    float* __restrict__ out) {
  __shared__ SmemM sm;
  const int tid = threadIdx.x;
  const int bx = blockIdx.x, by = blockIdx.y, bz = blockIdx.z;
  const int lh0 = by * 2, lw0 = bx * 8;
  const int hu0 = by * 4, wu0 = bx * 16;

  const int lane = tid & 63;
  const int wave = tid >> 6;
  const int nl = lane & 15;
  const int q8 = (lane >> 4) * 8;
  const int qm = (lane >> 4) * 4;
  const int rt32 = wave >> 1;
  const int ct32 = (wave & 1) * 4;
  const int ctkv = wave;

  // ---- phase 0a: x tile -> xtmp (coalesced), then registers ----
  {
    float* xtmp = reinterpret_cast<float*>(sm.kvb);
#pragma unroll
    for (int p = 0; p < 16; ++p) {
      const int e = tid + p * TM;
      const int c = e >> 6;
      const int px = e & 63;
      const int hu = hu0 + (px >> 4);
      const int wu = wu0 + (px & 15);
      xtmp[px * XTS + c] = fmu[((bz * 128 + c) * HuC + hu) * WuC + wu];
    }
  }
  __syncthreads();
  float xr[4][4];
  {
    const float* xtmp = reinterpret_cast<const float*>(sm.kvb);
#pragma unroll
    for (int r = 0; r < 4; ++r)
#pragma unroll
      for (int t = 0; t < 4; ++t)
        xr[r][t] = xtmp[(rt32 * 16 + qm + r) * XTS + (ct32 + t) * 16 + nl];
  }
  __syncthreads();

  // ---- phase 0b: source patch (4 x 10 low-res px, edge-clamped) + context LN ----
  {
    float* patch = reinterpret_cast<float*>(sm.kvb);
#pragma unroll
    for (int p = 0; p < 10; ++p) {
      const int e = tid + p * TM;
      const int c = e / 40;
      const int rem = e - c * 40;
      const int hs_i = rem / 10;
      const int ws_i = rem - hs_i * 10;
      int hd = lh0 - 1 + hs_i; hd = hd < 0 ? 0 : (hd > HdC - 1 ? HdC - 1 : hd);
      int wd = lw0 - 1 + ws_i; wd = wd < 0 ? 0 : (wd > WdC - 1 ? WdC - 1 : wd);
      patch[(hs_i * 10 + ws_i) * XTS + c] = fm[((bz * 128 + c) * HdC + hd) * WdC + wd];
    }
  }
  __syncthreads();
  {
    const float* patch = reinterpret_cast<const float*>(sm.kvb);
    if (tid < 320) {
      const int pp = tid >> 3, part = tid & 7;
      float s1 = 0.f, s2 = 0.f;
#pragma unroll
      for (int i = 0; i < 16; ++i) {
        const float v = patch[pp * XTS + part * 16 + i];
        s1 += v; s2 += v * v;
      }
      sm.scratch[MSC_ATT + (pp * 8 + part) * 2 + 0] = s1;
      sm.scratch[MSC_ATT + (pp * 8 + part) * 2 + 1] = s2;
    }
    __syncthreads();
    if (tid < 40) {
      float a = 0.f, b = 0.f;
#pragma unroll
      for (int g = 0; g < 8; ++g) {
        a += sm.scratch[MSC_ATT + (tid * 8 + g) * 2 + 0];
        b += sm.scratch[MSC_ATT + (tid * 8 + g) * 2 + 1];
      }
      const float m = a * (1.f / 128.f);
      const float v = b * (1.f / 128.f) - m * m;
      sm.scratch[MSC_ST + tid * 2 + 0] = m;
      sm.scratch[MSC_ST + tid * 2 + 1] = rsqrtf(v + 1e-6f);
    }
    __syncthreads();
#pragma unroll
    for (int p = 0; p < 5; ++p) {
      const int e = tid + p * TM;
      if (e < 2304) {
        const int r = e >> 4, cg = e & 15;
        const int lr = r / 9;
        const int kk = r - lr * 9;
        const int ki = kk / 3, kj = kk - ki * 3;
        const int pp = ((lr >> 3) + ki) * 10 + (lr & 7) + kj;
        const float m = sm.scratch[MSC_ST + pp * 2 + 0];
        const float rs = sm.scratch[MSC_ST + pp * 2 + 1];
        unsigned short tmp[8];
#pragma unroll
        for (int j = 0; j < 8; ++j)
          tmp[j] = f2bf((patch[pp * XTS + cg * 8 + j] - m) * rs);
        *reinterpret_cast<u16x8*>(sm.ctxn + r * CBS + cg * 8) = *reinterpret_cast<u16x8*>(tmp);
      }
    }
  }
  __syncthreads();  // ctxn ready; patch dead -> kvb free

  f32x4 acc4[4];
  f32x4 acc9[9];

  for (int l = 0; l < 2; ++l) {
    const unsigned short* P = wsp + (l * 12) * PANEL;

    ln_x(xr, sm.xn, sm.scratch, wave, rt32, ct32, nl, qm);

    // q = LN(x) @ wq + bq -> outb bf16
    mfma64(sm.xn, P + 0 * PANEL, acc4, nl, q8, rt32, ct32, true);
#pragma unroll
    for (int t = 0; t < 4; ++t) {
      const int n = (ct32 + t) * 16 + nl;
      const float bb = bq[l * 128 + n];
#pragma unroll
      for (int r = 0; r < 4; ++r)
        sm.outb[(rt32 * 16 + qm + r) * CBS + n] = f2bf(acc4[t][r] + bb);
    }
    // k = ctx_n @ wkv[:, :128] + b' -> kvb bf16
    mfma144(sm.ctxn, P + 1 * PANEL, acc9, nl, q8, ctkv);
    {
      const float bb = wsb[l * 256 + ctkv * 16 + nl];
#pragma unroll
      for (int rt = 0; rt < 9; ++rt)
#pragma unroll
        for (int r = 0; r < 4; ++r)
          sm.kvb[(rt * 16 + qm + r) * CBS + ctkv * 16 + nl] = f2bf(acc9[rt][r] + bb);
    }
    __syncthreads();  // q, k visible

    // v compute (store deferred)
    mfma144(sm.ctxn, P + 2 * PANEL, acc9, nl, q8, ctkv);

    // attention softmax (64 px x 4 heads)
    if (tid < 256) {
      const int px = tid >> 2, h = tid & 3;
      const int lr = (px >> 5) * 8 + ((px & 15) >> 1);
      const unsigned short* qrow = sm.outb + px * CBS + h * 32;
      float qf[32];
#pragma unroll
      for (int c8 = 0; c8 < 4; ++c8) {
        const u16x8 qa = *reinterpret_cast<const u16x8*>(qrow + c8 * 8);
#pragma unroll
        for (int j = 0; j < 8; ++j) qf[c8 * 8 + j] = bf2f(qa[j]);
      }
      float lg[9], mx = -1e30f;
#pragma unroll
      for (int kk = 0; kk < 9; ++kk) {
        const unsigned short* krow = sm.kvb + (lr * 9 + kk) * CBS + h * 32;
        float s = 0.f;
#pragma unroll
        for (int c8 = 0; c8 < 4; ++c8) {
          const u16x8 ka = *reinterpret_cast<const u16x8*>(krow + c8 * 8);
#pragma unroll
          for (int j = 0; j < 8; ++j) s += qf[c8 * 8 + j] * bf2f(ka[j]);
        }
        s *= 0.17677669529663687f;
        lg[kk] = s;
        mx = fmaxf(mx, s);
      }
      float sum = 0.f;
#pragma unroll
      for (int kk = 0; kk < 9; ++kk) { lg[kk] = __expf(lg[kk] - mx); sum += lg[kk]; }
      const float inv = 1.f / sum;
#pragma unroll
      for (int kk = 0; kk < 9; ++kk)
        sm.scratch[MSC_ATT + (px * 4 + h) * 9 + kk] = lg[kk] * inv;
    }
    __syncthreads();  // probs written; k reads done

    // v store
    {
      const float bb = wsb[l * 256 + 128 + ctkv * 16 + nl];
#pragma unroll
      for (int rt = 0; rt < 9; ++rt)
#pragma unroll
        for (int r = 0; r < 4; ++r)
          sm.kvb[(rt * 16 + qm + r) * CBS + ctkv * 16 + nl] = f2bf(acc9[rt][r] + bb);
    }
    __syncthreads();  // v visible

    // o = attn @ v -> xn
    {
      const int px = tid >> 3, cg = tid & 7, c0 = cg * 16;
      const int lr = (px >> 5) * 8 + ((px & 15) >> 1);
      const float* aw = sm.scratch + MSC_ATT + (px * 4 + (cg >> 1)) * 9;
      float o[16];
#pragma unroll
      for (int j = 0; j < 16; ++j) o[j] = 0.f;
#pragma unroll
      for (int kk = 0; kk < 9; ++kk) {
        const float a = aw[kk];
        const unsigned short* vrow = sm.kvb + (lr * 9 + kk) * CBS + c0;
        const u16x8 v0 = *reinterpret_cast<const u16x8*>(vrow);
        const u16x8 v1 = *reinterpret_cast<const u16x8*>(vrow + 8);
#pragma unroll
        for (int j = 0; j < 8; ++j) {
          o[j] += a * bf2f(v0[j]);
          o[8 + j] += a * bf2f(v1[j]);
        }
      }
      unsigned short tmp[16];
#pragma unroll
      for (int j = 0; j < 16; ++j) tmp[j] = f2bf(o[j]);
      *reinterpret_cast<u16x8*>(sm.xn + px * CBS + c0) = *reinterpret_cast<u16x8*>(tmp);
      *reinterpret_cast<u16x8*>(sm.xn + px * CBS + c0 + 8) = *reinterpret_cast<u16x8*>(tmp + 8);
    }
    __syncthreads();  // xn(o) visible

    // x += o @ wo + bo
    mfma64(sm.xn, P + 3 * PANEL, acc4, nl, q8, rt32, ct32, true);
#pragma unroll
    for (int t = 0; t < 4; ++t) {
      const float bb = bo[l * 128 + (ct32 + t) * 16 + nl];
#pragma unroll
      for (int r = 0; r < 4; ++r) xr[r][t] += acc4[t][r] + bb;
    }

    // MLP
    ln_x(xr, sm.xn, sm.scratch, wave, rt32, ct32, nl, qm);
    f32x4 xd[4];
    for (int cc = 0; cc < 4; ++cc) {
      mfma64(sm.xn, P + (4 + cc) * PANEL, acc4, nl, q8, rt32, ct32, true);
#pragma unroll
      for (int t = 0; t < 4; ++t) {
        const int n = (ct32 + t) * 16 + nl;
        const float bb = b1[l * 512 + cc * 128 + n];
#pragma unroll
        for (int r = 0; r < 4; ++r)
          sm.hb[(rt32 * 16 + qm + r) * CBS + n] = f2bf(gelu_tanh(acc4[t][r] + bb));
      }
      __syncthreads();
      mfma64(sm.hb, P + (8 + cc) * PANEL, xd, nl, q8, rt32, ct32, cc == 0);
      if (cc < 3) __syncthreads();
    }
#pragma unroll
    for (int t = 0; t < 4; ++t) {
      const float bb = b2[l * 128 + (ct32 + t) * 16 + nl];
#pragma unroll
      for (int r = 0; r < 4; ++r) xr[r][t] += xd[t][r] + bb;
    }
  }  // layers

  // final
  ln_x(xr, sm.xn, sm.scratch, wave, rt32, ct32, nl, qm);
  mfma64(sm.xn, wsp + 24 * PANEL, acc4, nl, q8, rt32, ct32, true);
#pragma unroll
  for (int t = 0; t < 4; ++t) {
    const int n = (ct32 + t) * 16 + nl;
    const float bb = bqf[n];
#pragma unroll
    for (int r = 0; r < 4; ++r)
      sm.outb[(rt32 * 16 + qm + r) * CBS + n] = f2bf(acc4[t][r] + bb);
  }
  mfma144(sm.ctxn, wsp + 25 * PANEL, acc9, nl, q8, ctkv);
  {
    const float bb = bcf[ctkv * 16 + nl];
#pragma unroll
    for (int rt = 0; rt < 9; ++rt)
#pragma unroll
      for (int r = 0; r < 4; ++r)
        sm.kvb[(rt * 16 + qm + r) * CBS + ctkv * 16 + nl] = f2bf(acc9[rt][r] + bb);
  }
  __syncthreads();
  {
    const int px = tid >> 3, sub = tid & 7;
    const int lr = (px >> 5) * 8 + ((px & 15) >> 1);
    const unsigned short* qrow = sm.outb + px * CBS;
#pragma unroll
    for (int which = 0; which < 2; ++which) {
      if (which == 1 && sub != 0) break;
      const int kk = (which == 0) ? sub : 8;
      const unsigned short* crow = sm.kvb + (lr * 9 + kk) * CBS;
      float s = 0.f;
#pragma unroll
      for (int c8 = 0; c8 < 16; ++c8) {
        const u16x8 qa = *reinterpret_cast<const u16x8*>(qrow + c8 * 8);
        const u16x8 ca = *reinterpret_cast<const u16x8*>(crow + c8 * 8);
#pragma unroll
        for (int j = 0; j < 8; ++j) s += bf2f(qa[j]) * bf2f(ca[j]);
      }
      sm.scratch[MSC_ATT + px * 12 + kk] = s;
    }
  }
  __syncthreads();
  if (tid < 64) {
    const int px = tid;
    const int hu = hu0 + (px >> 4), wu = wu0 + (px & 15);
    float lg[9], mx = -1e30f;
#pragma unroll
    for (int kk = 0; kk < 9; ++kk) {
      lg[kk] = sm.scratch[MSC_ATT + px * 12 + kk] * 0.08838834764831845f;
      mx = fmaxf(mx, lg[kk]);
    }
    float sum = 0.f;
#pragma unroll
    for (int kk = 0; kk < 9; ++kk) { lg[kk] = __expf(lg[kk] - mx); sum += lg[kk]; }
    const float inv = 1.f / sum;
#pragma unroll
    for (int kk = 0; kk < 9; ++kk)
      out[((bz * 9 + kk) * HuC + hu) * WuC + wu] = lg[kk] * inv;
  }
}

}  // namespace

extern "C" void kernel_launch(void* const* d_in, const int* in_sizes, int n_in,
                              void* d_out, int out_size, void* d_ws, size_t ws_size,
                              hipStream_t stream) {
  const float* fm   = (const float*)d_in[0];
  const float* fmu  = (const float*)d_in[1];
  const float* nc_w = (const float*)d_in[2];
  const float* nc_b = (const float*)d_in[3];
  const float* wq   = (const float*)d_in[4];
  const float* bq   = (const float*)d_in[5];
  const float* wkv  = (const float*)d_in[6];
  const float* bkv  = (const float*)d_in[7];
  const float* wo   = (const float*)d_in[8];
  const float* bo   = (const float*)d_in[9];
  const float* w1   = (const float*)d_in[10];
  const float* b1   = (const float*)d_in[11];
  const float* w2   = (const float*)d_in[12];
  const float* b2   = (const float*)d_in[13];
  const float* wqf  = (const float*)d_in[14];
  const float* bqf  = (const float*)d_in[15];
  const float* wcf  = (const float*)d_in[16];
  const float* bcf  = (const float*)d_in[17];
  float* out = (float*)d_out;

  if (ws_size >= WS_NEEDED) {
    unsigned short* wsp = (unsigned short*)d_ws;
    float* wsb = (float*)((char*)d_ws + (size_t)N_PANELS * PANEL * 2);
    prep_weights<<<dim3(106), dim3(256), 0, stream>>>(
        nc_w, nc_b, wq, wkv, bkv, wo, w1, w2, wqf, wcf, wsp, wsb);
    dim3 grid(12, 32, 2);  // (192/16, 128/4, B): 4x16-pixel tiles
    fused_interp_mfma<<<grid, dim3(TM), 0, stream>>>(
        fm, fmu, bq, bo, b1, b2, bqf, bcf, wsp, wsb, out);
  } else {
    dim3 grid(24, 32, 2);
    fused_interp_kernel<<<grid, dim3(THREADS), 0, stream>>>(
        fm, fmu, nc_w, nc_b, wq, bq, wkv, bkv, wo, bo, w1, b1, w2, b2,
        wqf, bqf, wcf, bcf, out);
  }
}

// Round 4
// 436.102 us; speedup vs baseline: 4.1864x; 1.0927x over previous
//
#include <hip/hip_runtime.h>

namespace {

constexpr int THREADS = 256;
constexpr int HdC = 64, WdC = 96, HuC = 128, WuC = 192;

// ======================= shared helpers =======================

__device__ __forceinline__ float gelu_tanh(float x) {
  float z = 0.7978845608028654f * (x + 0.044715f * x * x * x);
  float e = __expf(2.0f * z);
  float t = 1.0f - 2.0f / (e + 1.0f);
  return 0.5f * x * (1.0f + t);
}

__device__ __forceinline__ unsigned short f2bf(float f) {
  unsigned int u = __builtin_bit_cast(unsigned int, f);
  u = (u + 0x7FFFu + ((u >> 16) & 1u)) >> 16;  // RNE
  return (unsigned short)u;
}

__device__ __forceinline__ float bf2f(unsigned short u) {
  unsigned int x = ((unsigned int)u) << 16;
  return __builtin_bit_cast(float, x);
}

// ======================= fp32 fallback path (round-1, verified) =======================

constexpr int CTX_S = 80;
constexpr int KV_S  = 132;
constexpr int XS_S  = 132;
constexpr int XN_S  = 32;
constexpr int OB_S  = 144;

constexpr int SC_ATT = 0;
constexpr int SC_RED = 0;
constexpr int SC_MU  = 768;
constexpr int SC_RS  = 864;
constexpr int SC_NC  = 1152;
constexpr int SC_LG  = 0;

struct alignas(16) Smem {
  float ctxT[128 * CTX_S];
  float kvb[72 * KV_S];
  float xs[32 * XS_S];
  float xnT[128 * XN_S];
  float outb[32 * OB_S];
  float wbuf[32 * 128];
  float scratch[1536];
};
static_assert(sizeof(Smem) <= 160 * 1024, "LDS budget");

__device__ __forceinline__ void stage_w(const float* __restrict__ W, int wstride,
                                        int kc, float* wbuf, int tid) {
#pragma unroll
  for (int p = 0; p < 4; ++p) {
    int e = tid + p * THREADS;
    int r = e >> 5;
    int c4 = (e & 31) << 2;
    const float4 v = *reinterpret_cast<const float4*>(W + (kc * 32 + r) * wstride + c4);
    *reinterpret_cast<float4*>(wbuf + r * 128 + c4) = v;
  }
}

#define FMA_ROW(ac, s, w)                                            \
  {                                                                  \
    (ac)[0] += (s) * (w).x; (ac)[1] += (s) * (w).y;                  \
    (ac)[2] += (s) * (w).z; (ac)[3] += (s) * (w).w;                  \
  }

__device__ __forceinline__ void gemm32(const float* __restrict__ W, int wstride,
                                       const float* AT, float* wbuf, int tid,
                                       float acc[16]) {
  const int row0 = (tid >> 5) << 2;
  const int col0 = (tid & 31) << 2;
#pragma unroll
  for (int i = 0; i < 16; ++i) acc[i] = 0.f;
  for (int kc = 0; kc < 4; ++kc) {
    __syncthreads();
    stage_w(W, wstride, kc, wbuf, tid);
    __syncthreads();
#pragma unroll 4
    for (int cl = 0; cl < 32; ++cl) {
      const int c = (kc << 5) + cl;
      const float4 a = *reinterpret_cast<const float4*>(AT + c * XN_S + row0);
      const float4 w = *reinterpret_cast<const float4*>(wbuf + cl * 128 + col0);
      FMA_ROW(acc + 0, a.x, w);
      FMA_ROW(acc + 4, a.y, w);
      FMA_ROW(acc + 8, a.z, w);
      FMA_ROW(acc + 12, a.w, w);
    }
  }
}

template <bool NC>
__device__ __forceinline__ void gemm96(const float* __restrict__ W, int wstride,
                                       const float* ctxT, float* wbuf, float* kvb,
                                       const float* __restrict__ bias,
                                       const float* nc, int tid) {
  const int rt4 = (tid >> 5) << 2;
  const int col0 = (tid & 31) << 2;
  float acc[48];
#pragma unroll
  for (int i = 0; i < 48; ++i) acc[i] = 0.f;
  for (int kc = 0; kc < 4; ++kc) {
    __syncthreads();
    stage_w(W, wstride, kc, wbuf, tid);
    __syncthreads();
#pragma unroll 2
    for (int cl = 0; cl < 32; ++cl) {
      const int c = (kc << 5) + cl;
      const float4 w = *reinterpret_cast<const float4*>(wbuf + cl * 128 + col0);
      float s = 0.f, t = 0.f;
      if (NC) { s = nc[c]; t = nc[128 + c]; }
      const float* base = ctxT + c * CTX_S;
#pragma unroll
      for (int p = 0; p < 3; ++p) {
        int r0 = p * 32 + rt4;
        if (r0 > 76) r0 = 76;
        float4 a = *reinterpret_cast<const float4*>(base + r0);
        if (NC) {
          a.x = a.x * s + t; a.y = a.y * s + t;
          a.z = a.z * s + t; a.w = a.w * s + t;
        }
        float* ac = acc + p * 16;
        FMA_ROW(ac + 0, a.x, w);
        FMA_ROW(ac + 4, a.y, w);
        FMA_ROW(ac + 8, a.z, w);
        FMA_ROW(ac + 12, a.w, w);
      }
    }
  }
  const float4 bv = *reinterpret_cast<const float4*>(bias + col0);
#pragma unroll
  for (int p = 0; p < 3; ++p) {
    const int r0 = p * 32 + rt4;
    if (r0 < 72) {
#pragma unroll
      for (int i = 0; i < 4; ++i) {
        float4 o;
        o.x = acc[p * 16 + i * 4 + 0] + bv.x;
        o.y = acc[p * 16 + i * 4 + 1] + bv.y;
        o.z = acc[p * 16 + i * 4 + 2] + bv.z;
        o.w = acc[p * 16 + i * 4 + 3] + bv.w;
        *reinterpret_cast<float4*>(kvb + (r0 + i) * KV_S + col0) = o;
      }
    }
  }
}

__device__ __forceinline__ void layernorm_x(const float* xs, float* xnT,
                                            float* scratch, int tid) {
  const int px = tid & 31;
  const int cg = tid >> 5;
  float s1 = 0.f, s2 = 0.f;
#pragma unroll
  for (int i = 0; i < 16; ++i) {
    const float v = xs[px * XS_S + cg * 16 + i];
    s1 += v; s2 += v * v;
  }
  scratch[SC_RED + cg * 96 + px] = s1;
  scratch[SC_RED + cg * 96 + 48 + px] = s2;
  __syncthreads();
  if (tid < 32) {
    float a = 0.f, b = 0.f;
#pragma unroll
    for (int g = 0; g < 8; ++g) {
      a += scratch[SC_RED + g * 96 + tid];
      b += scratch[SC_RED + g * 96 + 48 + tid];
    }
    const float m = a * (1.f / 128.f);
    const float v = b * (1.f / 128.f) - m * m;
    scratch[SC_MU + tid] = m;
    scratch[SC_RS + tid] = rsqrtf(v + 1e-6f);
  }
  __syncthreads();
  const float m = scratch[SC_MU + px];
  const float r = scratch[SC_RS + px];
#pragma unroll
  for (int i = 0; i < 16; ++i) {
    const int c = cg * 16 + i;
    xnT[c * XN_S + px] = (xs[px * XS_S + c] - m) * r;
  }
}

__global__ __launch_bounds__(THREADS, 1) void fused_interp_kernel(
    const float* __restrict__ fm, const float* __restrict__ fmu,
    const float* __restrict__ nc_w, const float* __restrict__ nc_b,
    const float* __restrict__ wq, const float* __restrict__ bq,
    const float* __restrict__ wkv, const float* __restrict__ bkv,
    const float* __restrict__ wo, const float* __restrict__ bo,
    const float* __restrict__ w1, const float* __restrict__ b1,
    const float* __restrict__ w2, const float* __restrict__ b2,
    const float* __restrict__ wqf, const float* __restrict__ bqf,
    const float* __restrict__ wcf, const float* __restrict__ bcf,
    float* __restrict__ out) {
  __shared__ Smem sm;
  const int tid = threadIdx.x;
  const int bx = blockIdx.x;
  const int by = blockIdx.y;
  const int bz = blockIdx.z;
  const int lh0 = by * 2, lw0 = bx * 4;
  const int hu0 = by * 4, wu0 = bx * 8;

#pragma unroll
  for (int p = 0; p < 16; ++p) {
    const int idx = tid + p * THREADS;
    const int c = idx >> 5;
    const int px = idx & 31;
    const int hu = hu0 + (px >> 3);
    const int wu = wu0 + (px & 7);
    sm.xs[px * XS_S + c] = fmu[((bz * 128 + c) * HuC + hu) * WuC + wu];
  }

  for (int pass = 0; pass < 2; ++pass) {
    const int rl = tid >> 2;
    const int sub = tid & 3;
    const int r = pass * 64 + rl;
    const bool act = (r < 72);
    int base = 0;
    if (act) {
      const int lr = r / 9, kk = r % 9;
      const int hdp = lh0 + (lr >> 2);
      const int wdp = lw0 + (lr & 3);
      const int ki = kk / 3, kj = kk % 3;
      int hs = hdp + ki - 1; hs = hs < 0 ? 0 : (hs > HdC - 1 ? HdC - 1 : hs);
      int ws = wdp + kj - 1; ws = ws < 0 ? 0 : (ws > WdC - 1 ? WdC - 1 : ws);
      base = (bz * 128) * HdC * WdC + hs * WdC + ws;
      float s1 = 0.f, s2 = 0.f;
      for (int i = 0; i < 32; ++i) {
        const float v = fm[base + (sub * 32 + i) * (HdC * WdC)];
        s1 += v; s2 += v * v;
      }
      sm.scratch[SC_RED + sub * 64 + rl] = s1;
      sm.scratch[SC_RED + 384 + sub * 64 + rl] = s2;
    }
    __syncthreads();
    if (tid < 64 && pass * 64 + tid < 72) {
      float a = 0.f, b = 0.f;
#pragma unroll
      for (int s = 0; s < 4; ++s) {
        a += sm.scratch[SC_RED + s * 64 + tid];
        b += sm.scratch[SC_RED + 384 + s * 64 + tid];
      }
      const float m = a * (1.f / 128.f);
      const float v = b * (1.f / 128.f) - m * m;
      sm.scratch[SC_MU + pass * 64 + tid] = m;
      sm.scratch[SC_RS + pass * 64 + tid] = rsqrtf(v + 1e-6f);
    }
    __syncthreads();
    if (act) {
      const float m = sm.scratch[SC_MU + r];
      const float rr = sm.scratch[SC_RS + r];
      for (int i = 0; i < 32; ++i) {
        const int c = sub * 32 + i;
        const float v = fm[base + c * (HdC * WdC)];
        sm.ctxT[c * CTX_S + r] = (v - m) * rr;
      }
    }
    __syncthreads();
  }
  if (tid < 128) {
#pragma unroll
    for (int r = 72; r < 80; ++r) sm.ctxT[tid * CTX_S + r] = 0.f;
  }
  __syncthreads();

  const int row0 = (tid >> 5) << 2;
  const int col0 = (tid & 31) << 2;
  float acc[16];

  for (int l = 0; l < 2; ++l) {
    if (tid < 128) sm.scratch[SC_NC + tid] = nc_w[l * 128 + tid];
    else           sm.scratch[SC_NC + tid] = nc_b[l * 128 + (tid - 128)];

    layernorm_x(sm.xs, sm.xnT, sm.scratch, tid);
    gemm32(wq + l * 16384, 128, sm.xnT, sm.wbuf, tid, acc);
    {
      const float4 bv = *reinterpret_cast<const float4*>(bq + l * 128 + col0);
#pragma unroll
      for (int i = 0; i < 4; ++i) {
        float4 o;
        o.x = acc[i * 4 + 0] + bv.x; o.y = acc[i * 4 + 1] + bv.y;
        o.z = acc[i * 4 + 2] + bv.z; o.w = acc[i * 4 + 3] + bv.w;
        *reinterpret_cast<float4*>(sm.outb + (row0 + i) * OB_S + col0) = o;
      }
    }
    gemm96<true>(wkv + l * 32768, 256, sm.ctxT, sm.wbuf, sm.kvb,
                 bkv + l * 256, sm.scratch + SC_NC, tid);
    __syncthreads();
    if (tid < 128) {
      const int px = tid >> 2, h = tid & 3;
      const int lr = (((px >> 3) >> 1) << 2) | ((px & 7) >> 1);
      const float* qrow = sm.outb + px * OB_S + h * 32;
      float4 q[8];
#pragma unroll
      for (int d = 0; d < 8; ++d) q[d] = *reinterpret_cast<const float4*>(qrow + d * 4);
      float lg[9];
      float mx = -1e30f;
#pragma unroll
      for (int kk = 0; kk < 9; ++kk) {
        const float* krow = sm.kvb + (lr * 9 + kk) * KV_S + h * 32;
        float s = 0.f;
#pragma unroll
        for (int d = 0; d < 8; ++d) {
          const float4 kv = *reinterpret_cast<const float4*>(krow + d * 4);
          s += q[d].x * kv.x + q[d].y * kv.y + q[d].z * kv.z + q[d].w * kv.w;
        }
        s *= 0.17677669529663687f;
        lg[kk] = s;
        mx = fmaxf(mx, s);
      }
      float sum = 0.f;
#pragma unroll
      for (int kk = 0; kk < 9; ++kk) { lg[kk] = __expf(lg[kk] - mx); sum += lg[kk]; }
      const float inv = 1.f / sum;
#pragma unroll
      for (int kk = 0; kk < 9; ++kk)
        sm.scratch[SC_ATT + (px * 4 + h) * 9 + kk] = lg[kk] * inv;
    }
    __syncthreads();
    gemm96<true>(wkv + l * 32768 + 128, 256, sm.ctxT, sm.wbuf, sm.kvb,
                 bkv + l * 256 + 128, sm.scratch + SC_NC, tid);
    __syncthreads();
    {
      const int c = tid & 127, pg = tid >> 7;
      const int h = c >> 5;
#pragma unroll 4
      for (int i = 0; i < 16; ++i) {
        const int px = pg * 16 + i;
        const int lr = (((px >> 3) >> 1) << 2) | ((px & 7) >> 1);
        const float* aw = sm.scratch + SC_ATT + (px * 4 + h) * 9;
        float s = 0.f;
#pragma unroll
        for (int kk = 0; kk < 9; ++kk) s += aw[kk] * sm.kvb[(lr * 9 + kk) * KV_S + c];
        sm.xnT[c * XN_S + px] = s;
      }
    }
    gemm32(wo + l * 16384, 128, sm.xnT, sm.wbuf, tid, acc);
    {
      const float4 bv = *reinterpret_cast<const float4*>(bo + l * 128 + col0);
#pragma unroll
      for (int i = 0; i < 4; ++i) {
        float* xr = sm.xs + (row0 + i) * XS_S + col0;
        float4 x = *reinterpret_cast<float4*>(xr);
        x.x += acc[i * 4 + 0] + bv.x; x.y += acc[i * 4 + 1] + bv.y;
        x.z += acc[i * 4 + 2] + bv.z; x.w += acc[i * 4 + 3] + bv.w;
        *reinterpret_cast<float4*>(xr) = x;
      }
    }
    __syncthreads();
    layernorm_x(sm.xs, sm.xnT, sm.scratch, tid);
    float xd[16];
#pragma unroll
    for (int i = 0; i < 16; ++i) xd[i] = 0.f;
    for (int cc = 0; cc < 4; ++cc) {
      gemm32(w1 + l * 65536 + cc * 128, 512, sm.xnT, sm.wbuf, tid, acc);
      {
        const float4 bv = *reinterpret_cast<const float4*>(b1 + l * 512 + cc * 128 + col0);
#pragma unroll
        for (int i = 0; i < 4; ++i) {
          float4 o;
          o.x = gelu_tanh(acc[i * 4 + 0] + bv.x);
          o.y = gelu_tanh(acc[i * 4 + 1] + bv.y);
          o.z = gelu_tanh(acc[i * 4 + 2] + bv.z);
          o.w = gelu_tanh(acc[i * 4 + 3] + bv.w);
          *reinterpret_cast<float4*>(sm.outb + (row0 + i) * OB_S + col0) = o;
        }
      }
      __syncthreads();
      const float* w2c = w2 + l * 65536 + cc * 16384;
      for (int kc = 0; kc < 4; ++kc) {
        __syncthreads();
        stage_w(w2c, 128, kc, sm.wbuf, tid);
        __syncthreads();
#pragma unroll 4
        for (int cl = 0; cl < 32; ++cl) {
          const int c = (kc << 5) + cl;
          const float a0 = sm.outb[(row0 + 0) * OB_S + c];
          const float a1 = sm.outb[(row0 + 1) * OB_S + c];
          const float a2 = sm.outb[(row0 + 2) * OB_S + c];
          const float a3 = sm.outb[(row0 + 3) * OB_S + c];
          const float4 w = *reinterpret_cast<const float4*>(sm.wbuf + cl * 128 + col0);
          FMA_ROW(xd + 0, a0, w);
          FMA_ROW(xd + 4, a1, w);
          FMA_ROW(xd + 8, a2, w);
          FMA_ROW(xd + 12, a3, w);
        }
      }
    }
    {
      const float4 bv = *reinterpret_cast<const float4*>(b2 + l * 128 + col0);
#pragma unroll
      for (int i = 0; i < 4; ++i) {
        float* xr = sm.xs + (row0 + i) * XS_S + col0;
        float4 x = *reinterpret_cast<float4*>(xr);
        x.x += xd[i * 4 + 0] + bv.x; x.y += xd[i * 4 + 1] + bv.y;
        x.z += xd[i * 4 + 2] + bv.z; x.w += xd[i * 4 + 3] + bv.w;
        *reinterpret_cast<float4*>(xr) = x;
      }
    }
    __syncthreads();
  }

  layernorm_x(sm.xs, sm.xnT, sm.scratch, tid);
  gemm32(wqf, 128, sm.xnT, sm.wbuf, tid, acc);
  {
    const float4 bv = *reinterpret_cast<const float4*>(bqf + col0);
#pragma unroll
    for (int i = 0; i < 4; ++i) {
      float4 o;
      o.x = acc[i * 4 + 0] + bv.x; o.y = acc[i * 4 + 1] + bv.y;
      o.z = acc[i * 4 + 2] + bv.z; o.w = acc[i * 4 + 3] + bv.w;
      *reinterpret_cast<float4*>(sm.outb + (row0 + i) * OB_S + col0) = o;
    }
  }
  gemm96<false>(wcf, 128, sm.ctxT, sm.wbuf, sm.kvb, bcf, nullptr, tid);
  __syncthreads();
  {
    const int px = tid >> 3, sub = tid & 7;
    const int lr = (((px >> 3) >> 1) << 2) | ((px & 7) >> 1);
    const float* qrow = sm.outb + px * OB_S;
    {
      const float* crow = sm.kvb + (lr * 9 + sub) * KV_S;
      float s = 0.f;
#pragma unroll 8
      for (int c = 0; c < 128; c += 4) {
        const float4 qv = *reinterpret_cast<const float4*>(qrow + c);
        const float4 cv = *reinterpret_cast<const float4*>(crow + c);
        s += qv.x * cv.x + qv.y * cv.y + qv.z * cv.z + qv.w * cv.w;
      }
      sm.scratch[SC_LG + px * 12 + sub] = s;
    }
    if (sub == 0) {
      const float* crow = sm.kvb + (lr * 9 + 8) * KV_S;
      float s = 0.f;
#pragma unroll 8
      for (int c = 0; c < 128; c += 4) {
        const float4 qv = *reinterpret_cast<const float4*>(qrow + c);
        const float4 cv = *reinterpret_cast<const float4*>(crow + c);
        s += qv.x * cv.x + qv.y * cv.y + qv.z * cv.z + qv.w * cv.w;
      }
      sm.scratch[SC_LG + px * 12 + 8] = s;
    }
  }
  __syncthreads();
  if (tid < 32) {
    const int px = tid;
    const int hu = hu0 + (px >> 3), wu = wu0 + (px & 7);
    float lg[9], mx = -1e30f;
#pragma unroll
    for (int kk = 0; kk < 9; ++kk) {
      lg[kk] = sm.scratch[SC_LG + px * 12 + kk] * 0.08838834764831845f;
      mx = fmaxf(mx, lg[kk]);
    }
    float sum = 0.f;
#pragma unroll
    for (int kk = 0; kk < 9; ++kk) { lg[kk] = __expf(lg[kk] - mx); sum += lg[kk]; }
    const float inv = 1.f / sum;
#pragma unroll
    for (int kk = 0; kk < 9; ++kk)
      out[((bz * 9 + kk) * HuC + hu) * WuC + wu] = lg[kk] * inv;
  }
}

// ======================= MFMA path (v4) =======================
// 256 thr / 32 px / 73 KB LDS -> 2 blocks/CU / reg-resident x / direct global B loads

constexpr int PANEL = 16384;              // u16 per 128x128 panel, [n][k] layout
constexpr int N_PANELS = 26;
constexpr size_t WS_NEEDED = (size_t)N_PANELS * PANEL * 2 + 2048;
constexpr int CBS = 136;                  // bf16 LDS row stride
constexpr int XTS = 132;                  // fp32 temp stride

constexpr int MSC_ATT = 0;                // 1152: attn probs [px][h][9]; patch partials; final logits [px][12]
constexpr int MSC_LN  = 1152;             // 128: LN partials [px][4]
constexpr int MSC_ST  = 1280;             // 48: patch stats [24][2]
constexpr int MSC_N   = 1344;

typedef __attribute__((ext_vector_type(8))) short bf16x8;
typedef __attribute__((ext_vector_type(4))) float f32x4;
typedef __attribute__((ext_vector_type(8))) unsigned short u16x8;

struct alignas(16) SmemM {
  unsigned short ctxn[80 * CBS];    // 21760 B; alias xtmp f32[32*132]
  unsigned short kvb[80 * CBS];     // 21760 B; alias patch f32[24*132]
  unsigned short xn[32 * CBS];      //  8704 B
  unsigned short hb[32 * CBS];      //  8704 B
  unsigned short outb[32 * CBS];    //  8704 B
  float scratch[MSC_N];             //  5376 B
};
static_assert(sizeof(SmemM) <= 80 * 1024, "LDS budget (need 2 blocks/CU)");

__global__ void prep_weights(
    const float* __restrict__ nc_w, const float* __restrict__ nc_b,
    const float* __restrict__ wq, const float* __restrict__ wkv,
    const float* __restrict__ bkv,
    const float* __restrict__ wo, const float* __restrict__ w1,
    const float* __restrict__ w2, const float* __restrict__ wqf,
    const float* __restrict__ wcf,
    unsigned short* __restrict__ wsp, float* __restrict__ wsb) {
  const int b = blockIdx.x;
  const int t = threadIdx.x;
  if (b >= 104) {  // adjusted kv bias: b' = bkv + nc_b @ wkv
    const int l = b - 104;
    float acc = bkv[l * 256 + t];
    for (int k = 0; k < 128; ++k)
      acc += nc_b[l * 128 + k] * wkv[l * 32768 + k * 256 + t];
    wsb[l * 256 + t] = acc;
    return;
  }
  const int pid = b >> 2, qtr = b & 3;
  const float* src = wqf; int N = 128, koff = 0, noff = 0;
  const float* sc = nullptr;
  if (pid < 24) {
    const int l = pid / 12, loc = pid % 12;
    if (loc == 0)      { src = wq + l * 16384;  N = 128; }
    else if (loc == 1) { src = wkv + l * 32768; N = 256; sc = nc_w + l * 128; }
    else if (loc == 2) { src = wkv + l * 32768; N = 256; noff = 128; sc = nc_w + l * 128; }
    else if (loc == 3) { src = wo + l * 16384;  N = 128; }
    else if (loc < 8)  { src = w1 + l * 65536;  N = 512; noff = (loc - 4) * 128; }
    else               { src = w2 + l * 65536;  N = 128; koff = (loc - 8) * 128; }
  } else if (pid == 25) { src = wcf; }
  unsigned short* dst = wsp + pid * PANEL;
#pragma unroll
  for (int p = 0; p < 2; ++p) {
    const int e = t + p * 256;
    const int n = e & 127;
    const int kg = e >> 7;
    const int k0 = qtr * 32 + kg * 8;
    unsigned short tmp[8];
#pragma unroll
    for (int i = 0; i < 8; ++i) {
      const float s = sc ? sc[k0 + i] : 1.f;
      tmp[i] = f2bf(src[(k0 + i + koff) * N + noff + n] * s);
    }
    *reinterpret_cast<u16x8*>(dst + n * 128 + k0) = *reinterpret_cast<u16x8*>(tmp);
  }
}

// load 4 col-tiles x 4 k-slices of B fragments from a global panel
__device__ __forceinline__ void load_b(const unsigned short* __restrict__ W,
                                       bf16x8 b[4][4], int nl, int q8, int ct0) {
#pragma unroll
  for (int t = 0; t < 4; ++t)
#pragma unroll
    for (int ks = 0; ks < 4; ++ks)
      b[t][ks] = *reinterpret_cast<const bf16x8*>(W + ((ct0 + t) * 16 + nl) * 128 + ks * 32 + q8);
}

// 32x128 @ 128x128 with preloaded B; wave covers row tile rt, col tiles ct0..+3
__device__ __forceinline__ void mfma32(const unsigned short* A, const bf16x8 b[4][4],
                                       f32x4 acc[4], int nl, int q8, int rt, bool init) {
  if (init) {
#pragma unroll
    for (int t = 0; t < 4; ++t) acc[t] = (f32x4){0.f, 0.f, 0.f, 0.f};
  }
#pragma unroll
  for (int ks = 0; ks < 4; ++ks) {
    const bf16x8 a = *reinterpret_cast<const bf16x8*>(A + (rt * 16 + nl) * CBS + ks * 32 + q8);
#pragma unroll
    for (int t = 0; t < 4; ++t)
      acc[t] = __builtin_amdgcn_mfma_f32_16x16x32_bf16(a, b[t][ks], acc[t], 0, 0, 0);
  }
}

// 72(->80)x128 @ 128x128; wave covers 2 col stripes (ctw, ctw+1), 5 row tiles
__device__ __forceinline__ void mfma72(const unsigned short* Ctx,
                                       const unsigned short* __restrict__ W,
                                       f32x4 acc[10], int nl, int q8, int ctw) {
  bf16x8 b[2][4];
#pragma unroll
  for (int t = 0; t < 2; ++t)
#pragma unroll
    for (int ks = 0; ks < 4; ++ks)
      b[t][ks] = *reinterpret_cast<const bf16x8*>(W + ((ctw + t) * 16 + nl) * 128 + ks * 32 + q8);
#pragma unroll
  for (int i = 0; i < 10; ++i) acc[i] = (f32x4){0.f, 0.f, 0.f, 0.f};
#pragma unroll
  for (int ks = 0; ks < 4; ++ks)
#pragma unroll
    for (int rt = 0; rt < 5; ++rt) {
      const bf16x8 a = *reinterpret_cast<const bf16x8*>(Ctx + (rt * 16 + nl) * CBS + ks * 32 + q8);
      acc[rt * 2 + 0] = __builtin_amdgcn_mfma_f32_16x16x32_bf16(a, b[0][ks], acc[rt * 2 + 0], 0, 0, 0);
      acc[rt * 2 + 1] = __builtin_amdgcn_mfma_f32_16x16x32_bf16(a, b[1][ks], acc[rt * 2 + 1], 0, 0, 0);
    }
}

// LN of register-resident x -> xn (bf16 A rows). half = wave>>1. 2 barriers.
__device__ __forceinline__ void ln_x(const float (&xr)[4][4], unsigned short* xn,
                                     float* scratch, int wave, int rt, int ct0,
                                     int nl, int qm) {
  float s1[4], s2[4];
#pragma unroll
  for (int r = 0; r < 4; ++r) {
    s1[r] = xr[r][0] + xr[r][1] + xr[r][2] + xr[r][3];
    s2[r] = xr[r][0] * xr[r][0] + xr[r][1] * xr[r][1] +
            xr[r][2] * xr[r][2] + xr[r][3] * xr[r][3];
  }
#pragma unroll
  for (int m = 1; m < 16; m <<= 1) {
#pragma unroll
    for (int r = 0; r < 4; ++r) {
      s1[r] += __shfl_xor(s1[r], m, 64);
      s2[r] += __shfl_xor(s2[r], m, 64);
    }
  }
  if (nl == 0) {
#pragma unroll
    for (int r = 0; r < 4; ++r) {
      const int px = rt * 16 + qm + r;
      scratch[MSC_LN + px * 4 + (wave >> 1) * 2 + 0] = s1[r];
      scratch[MSC_LN + px * 4 + (wave >> 1) * 2 + 1] = s2[r];
    }
  }
  __syncthreads();
#pragma unroll
  for (int r = 0; r < 4; ++r) {
    const int px = rt * 16 + qm + r;
    const float a = scratch[MSC_LN + px * 4 + 0] + scratch[MSC_LN + px * 4 + 2];
    const float b = scratch[MSC_LN + px * 4 + 1] + scratch[MSC_LN + px * 4 + 3];
    const float m = a * (1.f / 128.f);
    const float v = b * (1.f / 128.f) - m * m;
    const float rs = rsqrtf(v + 1e-6f);
#pragma unroll
    for (int t = 0; t < 4; ++t)
      xn[px * CBS + (ct0 + t) * 16 + nl] = f2bf((xr[r][t] - m) * rs);
  }
  __syncthreads();
}

__global__ __launch_bounds__(THREADS, 2) void fused_interp_mfma(
    const float* __restrict__ fm, const float* __restrict__ fmu,
    const float* __restrict__ bq, const float* __restrict__ bo,
    const float* __restrict__ b1, const float* __restrict__ b2,
    const float* __restrict__ bqf, const float* __restrict__ bcf,
    const unsigned short* __restrict__ wsp, const float* __restrict__ wsb,
    float* __restrict__ out) {
  __shared__ SmemM sm;
  const int tid = threadIdx.x;
  const int bx = blockIdx.x, by = blockIdx.y, bz = blockIdx.z;
  const int lh0 = by * 2, lw0 = bx * 4;
  const int hu0 = by * 4, wu0 = bx * 8;

  const int lane = tid & 63;
  const int wave = tid >> 6;            // 0..3
  const int nl = lane & 15;
  const int q8 = (lane >> 4) * 8;
  const int qm = (lane >> 4) * 4;
  const int rtx = wave & 1;             // 32-row gemm row tile
  const int cx0 = (wave >> 1) * 4;      // 32-row gemm col tiles
  const int ctw = wave * 2;             // 72-row gemm col stripes

  // ---- phase 0a: x tile -> xtmp (coalesced), then registers ----
  {
    float* xtmp = reinterpret_cast<float*>(sm.ctxn);
#pragma unroll
    for (int p = 0; p < 16; ++p) {
      const int e = tid + p * THREADS;
      const int c = e >> 5;
      const int px = e & 31;
      const int hu = hu0 + (px >> 3);
      const int wu = wu0 + (px & 7);
      xtmp[px * XTS + c] = fmu[((bz * 128 + c) * HuC + hu) * WuC + wu];
    }
  }
  __syncthreads();
  float xr[4][4];
  {
    const float* xtmp = reinterpret_cast<const float*>(sm.ctxn);
#pragma unroll
    for (int r = 0; r < 4; ++r)
#pragma unroll
      for (int t = 0; t < 4; ++t)
        xr[r][t] = xtmp[(rtx * 16 + qm + r) * XTS + (cx0 + t) * 16 + nl];
  }
  __syncthreads();

  // ---- phase 0b: patch (2+2 x 4+2 low-res px, edge-clamped) + context LN ----
  {
    float* patch = reinterpret_cast<float*>(sm.kvb);
#pragma unroll
    for (int p = 0; p < 12; ++p) {
      const int e = tid + p * THREADS;  // 0..3071
      const int c = e / 24;
      const int rem = e - c * 24;
      const int hs_i = rem / 6;
      const int ws_i = rem - hs_i * 6;
      int hd = lh0 - 1 + hs_i; hd = hd < 0 ? 0 : (hd > HdC - 1 ? HdC - 1 : hd);
      int wd = lw0 - 1 + ws_i; wd = wd < 0 ? 0 : (wd > WdC - 1 ? WdC - 1 : wd);
      patch[(hs_i * 6 + ws_i) * XTS + c] = fm[((bz * 128 + c) * HdC + hd) * WdC + wd];
    }
  }
  __syncthreads();
  {
    const float* patch = reinterpret_cast<const float*>(sm.kvb);
    if (tid < 192) {
      const int pp = tid >> 3, part = tid & 7;
      float s1 = 0.f, s2 = 0.f;
#pragma unroll
      for (int i = 0; i < 16; ++i) {
        const float v = patch[pp * XTS + part * 16 + i];
        s1 += v; s2 += v * v;
      }
      sm.scratch[MSC_ATT + tid * 2 + 0] = s1;
      sm.scratch[MSC_ATT + tid * 2 + 1] = s2;
    }
    __syncthreads();
    if (tid < 24) {
      float a = 0.f, b = 0.f;
#pragma unroll
      for (int g = 0; g < 8; ++g) {
        a += sm.scratch[MSC_ATT + (tid * 8 + g) * 2 + 0];
        b += sm.scratch[MSC_ATT + (tid * 8 + g) * 2 + 1];
      }
      const float m = a * (1.f / 128.f);
      const float v = b * (1.f / 128.f) - m * m;
      sm.scratch[MSC_ST + tid * 2 + 0] = m;
      sm.scratch[MSC_ST + tid * 2 + 1] = rsqrtf(v + 1e-6f);
    }
    __syncthreads();
#pragma unroll
    for (int p = 0; p < 5; ++p) {
      const int e = tid + p * THREADS;
      if (e < 1152) {
        const int r = e >> 4, cg = e & 15;
        const int lr = r / 9;
        const int kk = r - lr * 9;
        const int ki = kk / 3, kj = kk - ki * 3;
        const int pp = ((lr >> 2) + ki) * 6 + (lr & 3) + kj;
        const float m = sm.scratch[MSC_ST + pp * 2 + 0];
        const float rs = sm.scratch[MSC_ST + pp * 2 + 1];
        unsigned short tmp[8];
#pragma unroll
        for (int j = 0; j < 8; ++j)
          tmp[j] = f2bf((patch[pp * XTS + cg * 8 + j] - m) * rs);
        *reinterpret_cast<u16x8*>(sm.ctxn + r * CBS + cg * 8) = *reinterpret_cast<u16x8*>(tmp);
      }
    }
    if (tid < 128) {  // zero pad rows 72..79 (read as A by mfma72's rt=4)
      const int r = 72 + (tid >> 4), cg = tid & 15;
      *reinterpret_cast<u16x8*>(sm.ctxn + r * CBS + cg * 8) = (u16x8){0, 0, 0, 0, 0, 0, 0, 0};
    }
  }
  __syncthreads();  // ctxn ready; patch dead -> kvb free

  f32x4 acc4[4];
  f32x4 acc10[10];
  bf16x8 bfr[4][4];

  for (int l = 0; l < 2; ++l) {
    const unsigned short* P = wsp + (l * 12) * PANEL;

    ln_x(xr, sm.xn, sm.scratch, wave, rtx, cx0, nl, qm);

    // q = LN(x) @ wq + bq -> outb bf16
    load_b(P + 0 * PANEL, bfr, nl, q8, cx0);
    mfma32(sm.xn, bfr, acc4, nl, q8, rtx, true);
#pragma unroll
    for (int t = 0; t < 4; ++t) {
      const int n = (cx0 + t) * 16 + nl;
      const float bb = bq[l * 128 + n];
#pragma unroll
      for (int r = 0; r < 4; ++r)
        sm.outb[(rtx * 16 + qm + r) * CBS + n] = f2bf(acc4[t][r] + bb);
    }
    // k = ctx_n @ wkv[:, :128] + b' -> kvb bf16
    mfma72(sm.ctxn, P + 1 * PANEL, acc10, nl, q8, ctw);
#pragma unroll
    for (int t = 0; t < 2; ++t) {
      const int n = (ctw + t) * 16 + nl;
      const float bb = wsb[l * 256 + n];
#pragma unroll
      for (int rt = 0; rt < 5; ++rt)
#pragma unroll
        for (int r = 0; r < 4; ++r) {
          const int row = rt * 16 + qm + r;
          if (row < 72) sm.kvb[row * CBS + n] = f2bf(acc10[rt * 2 + t][r] + bb);
        }
    }
    __syncthreads();  // q, k visible

    // v compute (store deferred)
    mfma72(sm.ctxn, P + 2 * PANEL, acc10, nl, q8, ctw);

    // attention softmax (32 px x 4 heads)
    if (tid < 128) {
      const int px = tid >> 2, h = tid & 3;
      const int lr = (((px >> 3) >> 1) << 2) | ((px & 7) >> 1);
      const unsigned short* qrow = sm.outb + px * CBS + h * 32;
      float qf[32];
#pragma unroll
      for (int c8 = 0; c8 < 4; ++c8) {
        const u16x8 qa = *reinterpret_cast<const u16x8*>(qrow + c8 * 8);
#pragma unroll
        for (int j = 0; j < 8; ++j) qf[c8 * 8 + j] = bf2f(qa[j]);
      }
      float lg[9], mx = -1e30f;
#pragma unroll
      for (int kk = 0; kk < 9; ++kk) {
        const unsigned short* krow = sm.kvb + (lr * 9 + kk) * CBS + h * 32;
        float s = 0.f;
#pragma unroll
        for (int c8 = 0; c8 < 4; ++c8) {
          const u16x8 ka = *reinterpret_cast<const u16x8*>(krow + c8 * 8);
#pragma unroll
          for (int j = 0; j < 8; ++j) s += qf[c8 * 8 + j] * bf2f(ka[j]);
        }
        s *= 0.17677669529663687f;
        lg[kk] = s;
        mx = fmaxf(mx, s);
      }
      float sum = 0.f;
#pragma unroll
      for (int kk = 0; kk < 9; ++kk) { lg[kk] = __expf(lg[kk] - mx); sum += lg[kk]; }
      const float inv = 1.f / sum;
#pragma unroll
      for (int kk = 0; kk < 9; ++kk)
        sm.scratch[MSC_ATT + (px * 4 + h) * 9 + kk] = lg[kk] * inv;
    }
    __syncthreads();  // probs written; k reads done

    // v store
#pragma unroll
    for (int t = 0; t < 2; ++t) {
      const int n = (ctw + t) * 16 + nl;
      const float bb = wsb[l * 256 + 128 + n];
#pragma unroll
      for (int rt = 0; rt < 5; ++rt)
#pragma unroll
        for (int r = 0; r < 4; ++r) {
          const int row = rt * 16 + qm + r;
          if (row < 72) sm.kvb[row * CBS + n] = f2bf(acc10[rt * 2 + t][r] + bb);
        }
    }
    __syncthreads();  // v visible

    // o = attn @ v -> xn (bf16, A rows)
    {
      const int px = tid >> 3, cg = tid & 7, c0 = cg * 16;
      const int lr = (((px >> 3) >> 1) << 2) | ((px & 7) >> 1);
      const float* aw = sm.scratch + MSC_ATT + (px * 4 + (cg >> 1)) * 9;
      float o[16];
#pragma unroll
      for (int j = 0; j < 16; ++j) o[j] = 0.f;
#pragma unroll
      for (int kk = 0; kk < 9; ++kk) {
        const float a = aw[kk];
        const unsigned short* vrow = sm.kvb + (lr * 9 + kk) * CBS + c0;
        const u16x8 v0 = *reinterpret_cast<const u16x8*>(vrow);
        const u16x8 v1 = *reinterpret_cast<const u16x8*>(vrow + 8);
#pragma unroll
        for (int j = 0; j < 8; ++j) {
          o[j] += a * bf2f(v0[j]);
          o[8 + j] += a * bf2f(v1[j]);
        }
      }
      unsigned short tmp[16];
#pragma unroll
      for (int j = 0; j < 16; ++j) tmp[j] = f2bf(o[j]);
      *reinterpret_cast<u16x8*>(sm.xn + px * CBS + c0) = *reinterpret_cast<u16x8*>(tmp);
      *reinterpret_cast<u16x8*>(sm.xn + px * CBS + c0 + 8) = *reinterpret_cast<u16x8*>(tmp + 8);
    }
    __syncthreads();  // xn(o) visible

    // x += o @ wo + bo
    load_b(P + 3 * PANEL, bfr, nl, q8, cx0);
    mfma32(sm.xn, bfr, acc4, nl, q8, rtx, true);
#pragma unroll
    for (int t = 0; t < 4; ++t) {
      const float bb = bo[l * 128 + (cx0 + t) * 16 + nl];
#pragma unroll
      for (int r = 0; r < 4; ++r) xr[r][t] += acc4[t][r] + bb;
    }

    // MLP (w2 fragments prefetched before the h-store barrier)
    ln_x(xr, sm.xn, sm.scratch, wave, rtx, cx0, nl, qm);
    f32x4 xd[4];
    for (int cc = 0; cc < 4; ++cc) {
      bf16x8 bw2[4][4];
      load_b(P + (4 + cc) * PANEL, bfr, nl, q8, cx0);   // w1 chunk
      load_b(P + (8 + cc) * PANEL, bw2, nl, q8, cx0);   // w2 chunk (prefetch)
      mfma32(sm.xn, bfr, acc4, nl, q8, rtx, true);
#pragma unroll
      for (int t = 0; t < 4; ++t) {
        const int n = (cx0 + t) * 16 + nl;
        const float bb = b1[l * 512 + cc * 128 + n];
#pragma unroll
        for (int r = 0; r < 4; ++r)
          sm.hb[(rtx * 16 + qm + r) * CBS + n] = f2bf(gelu_tanh(acc4[t][r] + bb));
      }
      __syncthreads();
      mfma32(sm.hb, bw2, xd, nl, q8, rtx, cc == 0);
      if (cc < 3) __syncthreads();
    }
#pragma unroll
    for (int t = 0; t < 4; ++t) {
      const float bb = b2[l * 128 + (cx0 + t) * 16 + nl];
#pragma unroll
      for (int r = 0; r < 4; ++r) xr[r][t] += xd[t][r] + bb;
    }
  }  // layers

  // ---- final ----
  ln_x(xr, sm.xn, sm.scratch, wave, rtx, cx0, nl, qm);
  load_b(wsp + 24 * PANEL, bfr, nl, q8, cx0);
  mfma32(sm.xn, bfr, acc4, nl, q8, rtx, true);
#pragma unroll
  for (int t = 0; t < 4; ++t) {
    const int n = (cx0 + t) * 16 + nl;
    const float bb = bqf[n];
#pragma unroll
    for (int r = 0; r < 4; ++r)
      sm.outb[(rtx * 16 + qm + r) * CBS + n] = f2bf(acc4[t][r] + bb);
  }
  mfma72(sm.ctxn, wsp + 25 * PANEL, acc10, nl, q8, ctw);
#pragma unroll
  for (int t = 0; t < 2; ++t) {
    const int n = (ctw + t) * 16 + nl;
    const float bb = bcf[n];
#pragma unroll
    for (int rt = 0; rt < 5; ++rt)
#pragma unroll
      for (int r = 0; r < 4; ++r) {
        const int row = rt * 16 + qm + r;
        if (row < 72) sm.kvb[row * CBS + n] = f2bf(acc10[rt * 2 + t][r] + bb);
      }
  }
  __syncthreads();
  {
    const int px = tid >> 3, sub = tid & 7;
    const int lr = (((px >> 3) >> 1) << 2) | ((px & 7) >> 1);
    const unsigned short* qrow = sm.outb + px * CBS;
#pragma unroll
    for (int which = 0; which < 2; ++which) {
      if (which == 1 && sub != 0) break;
      const int kk = (which == 0) ? sub : 8;
      const unsigned short* crow = sm.kvb + (lr * 9 + kk) * CBS;
      float s = 0.f;
#pragma unroll
      for (int c8 = 0; c8 < 16; ++c8) {
        const u16x8 qa = *reinterpret_cast<const u16x8*>(qrow + c8 * 8);
        const u16x8 ca = *reinterpret_cast<const u16x8*>(crow + c8 * 8);
#pragma unroll
        for (int j = 0; j < 8; ++j) s += bf2f(qa[j]) * bf2f(ca[j]);
      }
      sm.scratch[MSC_ATT + px * 12 + kk] = s;
    }
  }
  __syncthreads();
  if (tid < 32) {
    const int px = tid;
    const int hu = hu0 + (px >> 3), wu = wu0 + (px & 7);
    float lg[9], mx = -1e30f;
#pragma unroll
    for (int kk = 0; kk < 9; ++kk) {
      lg[kk] = sm.scratch[MSC_ATT + px * 12 + kk] * 0.08838834764831845f;
      mx = fmaxf(mx, lg[kk]);
    }
    float sum = 0.f;
#pragma unroll
    for (int kk = 0; kk < 9; ++kk) { lg[kk] = __expf(lg[kk] - mx); sum += lg[kk]; }
    const float inv = 1.f / sum;
#pragma unroll
    for (int kk = 0; kk < 9; ++kk)
      out[((bz * 9 + kk) * HuC + hu) * WuC + wu] = lg[kk] * inv;
  }
}

}  // namespace

extern "C" void kernel_launch(void* const* d_in, const int* in_sizes, int n_in,
                              void* d_out, int out_size, void* d_ws, size_t ws_size,
                              hipStream_t stream) {
  const float* fm   = (const float*)d_in[0];
  const float* fmu  = (const float*)d_in[1];
  const float* nc_w = (const float*)d_in[2];
  const float* nc_b = (const float*)d_in[3];
  const float* wq   = (const float*)d_in[4];
  const float* bq   = (const float*)d_in[5];
  const float* wkv  = (const float*)d_in[6];
  const float* bkv  = (const float*)d_in[7];
  const float* wo   = (const float*)d_in[8];
  const float* bo   = (const float*)d_in[9];
  const float* w1   = (const float*)d_in[10];
  const float* b1   = (const float*)d_in[11];
  const float* w2   = (const float*)d_in[12];
  const float* b2   = (const float*)d_in[13];
  const float* wqf  = (const float*)d_in[14];
  const float* bqf  = (const float*)d_in[15];
  const float* wcf  = (const float*)d_in[16];
  const float* bcf  = (const float*)d_in[17];
  float* out = (float*)d_out;

  dim3 grid(24, 32, 2);  // 4x8-pixel tiles
  if (ws_size >= WS_NEEDED) {
    unsigned short* wsp = (unsigned short*)d_ws;
    float* wsb = (float*)((char*)d_ws + (size_t)N_PANELS * PANEL * 2);
    prep_weights<<<dim3(106), dim3(256), 0, stream>>>(
        nc_w, nc_b, wq, wkv, bkv, wo, w1, w2, wqf, wcf, wsp, wsb);
    fused_interp_mfma<<<grid, dim3(THREADS), 0, stream>>>(
        fm, fmu, bq, bo, b1, b2, bqf, bcf, wsp, wsb, out);
  } else {
    fused_interp_kernel<<<grid, dim3(THREADS), 0, stream>>>(
        fm, fmu, nc_w, nc_b, wq, bq, wkv, bkv, wo, bo, w1, b1, w2, b2,
        wqf, bqf, wcf, bcf, out);
  }
}

// Round 5
// 363.325 us; speedup vs baseline: 5.0250x; 1.2003x over previous
//
#include <hip/hip_runtime.h>

namespace {

constexpr int THREADS = 256;
constexpr int HdC = 64, WdC = 96, HuC = 128, WuC = 192;

// ======================= shared helpers =======================

__device__ __forceinline__ float gelu_tanh(float x) {
  float z = 0.7978845608028654f * (x + 0.044715f * x * x * x);
  float e = __expf(2.0f * z);
  float t = 1.0f - 2.0f / (e + 1.0f);
  return 0.5f * x * (1.0f + t);
}

__device__ __forceinline__ unsigned short f2bf(float f) {
  unsigned int u = __builtin_bit_cast(unsigned int, f);
  u = (u + 0x7FFFu + ((u >> 16) & 1u)) >> 16;  // RNE
  return (unsigned short)u;
}

__device__ __forceinline__ float bf2f(unsigned short u) {
  unsigned int x = ((unsigned int)u) << 16;
  return __builtin_bit_cast(float, x);
}

// ======================= fp32 fallback path (round-1, verified) =======================

constexpr int CTX_S = 80;
constexpr int KV_S  = 132;
constexpr int XS_S  = 132;
constexpr int XN_S  = 32;
constexpr int OB_S  = 144;

constexpr int SC_ATT = 0;
constexpr int SC_RED = 0;
constexpr int SC_MU  = 768;
constexpr int SC_RS  = 864;
constexpr int SC_NC  = 1152;
constexpr int SC_LG  = 0;

struct alignas(16) Smem {
  float ctxT[128 * CTX_S];
  float kvb[72 * KV_S];
  float xs[32 * XS_S];
  float xnT[128 * XN_S];
  float outb[32 * OB_S];
  float wbuf[32 * 128];
  float scratch[1536];
};
static_assert(sizeof(Smem) <= 160 * 1024, "LDS budget");

__device__ __forceinline__ void stage_w(const float* __restrict__ W, int wstride,
                                        int kc, float* wbuf, int tid) {
#pragma unroll
  for (int p = 0; p < 4; ++p) {
    int e = tid + p * THREADS;
    int r = e >> 5;
    int c4 = (e & 31) << 2;
    const float4 v = *reinterpret_cast<const float4*>(W + (kc * 32 + r) * wstride + c4);
    *reinterpret_cast<float4*>(wbuf + r * 128 + c4) = v;
  }
}

#define FMA_ROW(ac, s, w)                                            \
  {                                                                  \
    (ac)[0] += (s) * (w).x; (ac)[1] += (s) * (w).y;                  \
    (ac)[2] += (s) * (w).z; (ac)[3] += (s) * (w).w;                  \
  }

__device__ __forceinline__ void gemm32(const float* __restrict__ W, int wstride,
                                       const float* AT, float* wbuf, int tid,
                                       float acc[16]) {
  const int row0 = (tid >> 5) << 2;
  const int col0 = (tid & 31) << 2;
#pragma unroll
  for (int i = 0; i < 16; ++i) acc[i] = 0.f;
  for (int kc = 0; kc < 4; ++kc) {
    __syncthreads();
    stage_w(W, wstride, kc, wbuf, tid);
    __syncthreads();
#pragma unroll 4
    for (int cl = 0; cl < 32; ++cl) {
      const int c = (kc << 5) + cl;
      const float4 a = *reinterpret_cast<const float4*>(AT + c * XN_S + row0);
      const float4 w = *reinterpret_cast<const float4*>(wbuf + cl * 128 + col0);
      FMA_ROW(acc + 0, a.x, w);
      FMA_ROW(acc + 4, a.y, w);
      FMA_ROW(acc + 8, a.z, w);
      FMA_ROW(acc + 12, a.w, w);
    }
  }
}

template <bool NC>
__device__ __forceinline__ void gemm96(const float* __restrict__ W, int wstride,
                                       const float* ctxT, float* wbuf, float* kvb,
                                       const float* __restrict__ bias,
                                       const float* nc, int tid) {
  const int rt4 = (tid >> 5) << 2;
  const int col0 = (tid & 31) << 2;
  float acc[48];
#pragma unroll
  for (int i = 0; i < 48; ++i) acc[i] = 0.f;
  for (int kc = 0; kc < 4; ++kc) {
    __syncthreads();
    stage_w(W, wstride, kc, wbuf, tid);
    __syncthreads();
#pragma unroll 2
    for (int cl = 0; cl < 32; ++cl) {
      const int c = (kc << 5) + cl;
      const float4 w = *reinterpret_cast<const float4*>(wbuf + cl * 128 + col0);
      float s = 0.f, t = 0.f;
      if (NC) { s = nc[c]; t = nc[128 + c]; }
      const float* base = ctxT + c * CTX_S;
#pragma unroll
      for (int p = 0; p < 3; ++p) {
        int r0 = p * 32 + rt4;
        if (r0 > 76) r0 = 76;
        float4 a = *reinterpret_cast<const float4*>(base + r0);
        if (NC) {
          a.x = a.x * s + t; a.y = a.y * s + t;
          a.z = a.z * s + t; a.w = a.w * s + t;
        }
        float* ac = acc + p * 16;
        FMA_ROW(ac + 0, a.x, w);
        FMA_ROW(ac + 4, a.y, w);
        FMA_ROW(ac + 8, a.z, w);
        FMA_ROW(ac + 12, a.w, w);
      }
    }
  }
  const float4 bv = *reinterpret_cast<const float4*>(bias + col0);
#pragma unroll
  for (int p = 0; p < 3; ++p) {
    const int r0 = p * 32 + rt4;
    if (r0 < 72) {
#pragma unroll
      for (int i = 0; i < 4; ++i) {
        float4 o;
        o.x = acc[p * 16 + i * 4 + 0] + bv.x;
        o.y = acc[p * 16 + i * 4 + 1] + bv.y;
        o.z = acc[p * 16 + i * 4 + 2] + bv.z;
        o.w = acc[p * 16 + i * 4 + 3] + bv.w;
        *reinterpret_cast<float4*>(kvb + (r0 + i) * KV_S + col0) = o;
      }
    }
  }
}

__device__ __forceinline__ void layernorm_x(const float* xs, float* xnT,
                                            float* scratch, int tid) {
  const int px = tid & 31;
  const int cg = tid >> 5;
  float s1 = 0.f, s2 = 0.f;
#pragma unroll
  for (int i = 0; i < 16; ++i) {
    const float v = xs[px * XS_S + cg * 16 + i];
    s1 += v; s2 += v * v;
  }
  scratch[SC_RED + cg * 96 + px] = s1;
  scratch[SC_RED + cg * 96 + 48 + px] = s2;
  __syncthreads();
  if (tid < 32) {
    float a = 0.f, b = 0.f;
#pragma unroll
    for (int g = 0; g < 8; ++g) {
      a += scratch[SC_RED + g * 96 + tid];
      b += scratch[SC_RED + g * 96 + 48 + tid];
    }
    const float m = a * (1.f / 128.f);
    const float v = b * (1.f / 128.f) - m * m;
    scratch[SC_MU + tid] = m;
    scratch[SC_RS + tid] = rsqrtf(v + 1e-6f);
  }
  __syncthreads();
  const float m = scratch[SC_MU + px];
  const float r = scratch[SC_RS + px];
#pragma unroll
  for (int i = 0; i < 16; ++i) {
    const int c = cg * 16 + i;
    xnT[c * XN_S + px] = (xs[px * XS_S + c] - m) * r;
  }
}

__global__ __launch_bounds__(THREADS, 1) void fused_interp_kernel(
    const float* __restrict__ fm, const float* __restrict__ fmu,
    const float* __restrict__ nc_w, const float* __restrict__ nc_b,
    const float* __restrict__ wq, const float* __restrict__ bq,
    const float* __restrict__ wkv, const float* __restrict__ bkv,
    const float* __restrict__ wo, const float* __restrict__ bo,
    const float* __restrict__ w1, const float* __restrict__ b1,
    const float* __restrict__ w2, const float* __restrict__ b2,
    const float* __restrict__ wqf, const float* __restrict__ bqf,
    const float* __restrict__ wcf, const float* __restrict__ bcf,
    float* __restrict__ out) {
  __shared__ Smem sm;
  const int tid = threadIdx.x;
  const int bx = blockIdx.x;
  const int by = blockIdx.y;
  const int bz = blockIdx.z;
  const int lh0 = by * 2, lw0 = bx * 4;
  const int hu0 = by * 4, wu0 = bx * 8;

#pragma unroll
  for (int p = 0; p < 16; ++p) {
    const int idx = tid + p * THREADS;
    const int c = idx >> 5;
    const int px = idx & 31;
    const int hu = hu0 + (px >> 3);
    const int wu = wu0 + (px & 7);
    sm.xs[px * XS_S + c] = fmu[((bz * 128 + c) * HuC + hu) * WuC + wu];
  }

  for (int pass = 0; pass < 2; ++pass) {
    const int rl = tid >> 2;
    const int sub = tid & 3;
    const int r = pass * 64 + rl;
    const bool act = (r < 72);
    int base = 0;
    if (act) {
      const int lr = r / 9, kk = r % 9;
      const int hdp = lh0 + (lr >> 2);
      const int wdp = lw0 + (lr & 3);
      const int ki = kk / 3, kj = kk % 3;
      int hs = hdp + ki - 1; hs = hs < 0 ? 0 : (hs > HdC - 1 ? HdC - 1 : hs);
      int ws = wdp + kj - 1; ws = ws < 0 ? 0 : (ws > WdC - 1 ? WdC - 1 : ws);
      base = (bz * 128) * HdC * WdC + hs * WdC + ws;
      float s1 = 0.f, s2 = 0.f;
      for (int i = 0; i < 32; ++i) {
        const float v = fm[base + (sub * 32 + i) * (HdC * WdC)];
        s1 += v; s2 += v * v;
      }
      sm.scratch[SC_RED + sub * 64 + rl] = s1;
      sm.scratch[SC_RED + 384 + sub * 64 + rl] = s2;
    }
    __syncthreads();
    if (tid < 64 && pass * 64 + tid < 72) {
      float a = 0.f, b = 0.f;
#pragma unroll
      for (int s = 0; s < 4; ++s) {
        a += sm.scratch[SC_RED + s * 64 + tid];
        b += sm.scratch[SC_RED + 384 + s * 64 + tid];
      }
      const float m = a * (1.f / 128.f);
      const float v = b * (1.f / 128.f) - m * m;
      sm.scratch[SC_MU + pass * 64 + tid] = m;
      sm.scratch[SC_RS + pass * 64 + tid] = rsqrtf(v + 1e-6f);
    }
    __syncthreads();
    if (act) {
      const float m = sm.scratch[SC_MU + r];
      const float rr = sm.scratch[SC_RS + r];
      for (int i = 0; i < 32; ++i) {
        const int c = sub * 32 + i;
        const float v = fm[base + c * (HdC * WdC)];
        sm.ctxT[c * CTX_S + r] = (v - m) * rr;
      }
    }
    __syncthreads();
  }
  if (tid < 128) {
#pragma unroll
    for (int r = 72; r < 80; ++r) sm.ctxT[tid * CTX_S + r] = 0.f;
  }
  __syncthreads();

  const int row0 = (tid >> 5) << 2;
  const int col0 = (tid & 31) << 2;
  float acc[16];

  for (int l = 0; l < 2; ++l) {
    if (tid < 128) sm.scratch[SC_NC + tid] = nc_w[l * 128 + tid];
    else           sm.scratch[SC_NC + tid] = nc_b[l * 128 + (tid - 128)];

    layernorm_x(sm.xs, sm.xnT, sm.scratch, tid);
    gemm32(wq + l * 16384, 128, sm.xnT, sm.wbuf, tid, acc);
    {
      const float4 bv = *reinterpret_cast<const float4*>(bq + l * 128 + col0);
#pragma unroll
      for (int i = 0; i < 4; ++i) {
        float4 o;
        o.x = acc[i * 4 + 0] + bv.x; o.y = acc[i * 4 + 1] + bv.y;
        o.z = acc[i * 4 + 2] + bv.z; o.w = acc[i * 4 + 3] + bv.w;
        *reinterpret_cast<float4*>(sm.outb + (row0 + i) * OB_S + col0) = o;
      }
    }
    gemm96<true>(wkv + l * 32768, 256, sm.ctxT, sm.wbuf, sm.kvb,
                 bkv + l * 256, sm.scratch + SC_NC, tid);
    __syncthreads();
    if (tid < 128) {
      const int px = tid >> 2, h = tid & 3;
      const int lr = (((px >> 3) >> 1) << 2) | ((px & 7) >> 1);
      const float* qrow = sm.outb + px * OB_S + h * 32;
      float4 q[8];
#pragma unroll
      for (int d = 0; d < 8; ++d) q[d] = *reinterpret_cast<const float4*>(qrow + d * 4);
      float lg[9];
      float mx = -1e30f;
#pragma unroll
      for (int kk = 0; kk < 9; ++kk) {
        const float* krow = sm.kvb + (lr * 9 + kk) * KV_S + h * 32;
        float s = 0.f;
#pragma unroll
        for (int d = 0; d < 8; ++d) {
          const float4 kv = *reinterpret_cast<const float4*>(krow + d * 4);
          s += q[d].x * kv.x + q[d].y * kv.y + q[d].z * kv.z + q[d].w * kv.w;
        }
        s *= 0.17677669529663687f;
        lg[kk] = s;
        mx = fmaxf(mx, s);
      }
      float sum = 0.f;
#pragma unroll
      for (int kk = 0; kk < 9; ++kk) { lg[kk] = __expf(lg[kk] - mx); sum += lg[kk]; }
      const float inv = 1.f / sum;
#pragma unroll
      for (int kk = 0; kk < 9; ++kk)
        sm.scratch[SC_ATT + (px * 4 + h) * 9 + kk] = lg[kk] * inv;
    }
    __syncthreads();
    gemm96<true>(wkv + l * 32768 + 128, 256, sm.ctxT, sm.wbuf, sm.kvb,
                 bkv + l * 256 + 128, sm.scratch + SC_NC, tid);
    __syncthreads();
    {
      const int c = tid & 127, pg = tid >> 7;
      const int h = c >> 5;
#pragma unroll 4
      for (int i = 0; i < 16; ++i) {
        const int px = pg * 16 + i;
        const int lr = (((px >> 3) >> 1) << 2) | ((px & 7) >> 1);
        const float* aw = sm.scratch + SC_ATT + (px * 4 + h) * 9;
        float s = 0.f;
#pragma unroll
        for (int kk = 0; kk < 9; ++kk) s += aw[kk] * sm.kvb[(lr * 9 + kk) * KV_S + c];
        sm.xnT[c * XN_S + px] = s;
      }
    }
    gemm32(wo + l * 16384, 128, sm.xnT, sm.wbuf, tid, acc);
    {
      const float4 bv = *reinterpret_cast<const float4*>(bo + l * 128 + col0);
#pragma unroll
      for (int i = 0; i < 4; ++i) {
        float* xr = sm.xs + (row0 + i) * XS_S + col0;
        float4 x = *reinterpret_cast<float4*>(xr);
        x.x += acc[i * 4 + 0] + bv.x; x.y += acc[i * 4 + 1] + bv.y;
        x.z += acc[i * 4 + 2] + bv.z; x.w += acc[i * 4 + 3] + bv.w;
        *reinterpret_cast<float4*>(xr) = x;
      }
    }
    __syncthreads();
    layernorm_x(sm.xs, sm.xnT, sm.scratch, tid);
    float xd[16];
#pragma unroll
    for (int i = 0; i < 16; ++i) xd[i] = 0.f;
    for (int cc = 0; cc < 4; ++cc) {
      gemm32(w1 + l * 65536 + cc * 128, 512, sm.xnT, sm.wbuf, tid, acc);
      {
        const float4 bv = *reinterpret_cast<const float4*>(b1 + l * 512 + cc * 128 + col0);
#pragma unroll
        for (int i = 0; i < 4; ++i) {
          float4 o;
          o.x = gelu_tanh(acc[i * 4 + 0] + bv.x);
          o.y = gelu_tanh(acc[i * 4 + 1] + bv.y);
          o.z = gelu_tanh(acc[i * 4 + 2] + bv.z);
          o.w = gelu_tanh(acc[i * 4 + 3] + bv.w);
          *reinterpret_cast<float4*>(sm.outb + (row0 + i) * OB_S + col0) = o;
        }
      }
      __syncthreads();
      const float* w2c = w2 + l * 65536 + cc * 16384;
      for (int kc = 0; kc < 4; ++kc) {
        __syncthreads();
        stage_w(w2c, 128, kc, sm.wbuf, tid);
        __syncthreads();
#pragma unroll 4
        for (int cl = 0; cl < 32; ++cl) {
          const int c = (kc << 5) + cl;
          const float a0 = sm.outb[(row0 + 0) * OB_S + c];
          const float a1 = sm.outb[(row0 + 1) * OB_S + c];
          const float a2 = sm.outb[(row0 + 2) * OB_S + c];
          const float a3 = sm.outb[(row0 + 3) * OB_S + c];
          const float4 w = *reinterpret_cast<const float4*>(sm.wbuf + cl * 128 + col0);
          FMA_ROW(xd + 0, a0, w);
          FMA_ROW(xd + 4, a1, w);
          FMA_ROW(xd + 8, a2, w);
          FMA_ROW(xd + 12, a3, w);
        }
      }
    }
    {
      const float4 bv = *reinterpret_cast<const float4*>(b2 + l * 128 + col0);
#pragma unroll
      for (int i = 0; i < 4; ++i) {
        float* xr = sm.xs + (row0 + i) * XS_S + col0;
        float4 x = *reinterpret_cast<float4*>(xr);
        x.x += xd[i * 4 + 0] + bv.x; x.y += xd[i * 4 + 1] + bv.y;
        x.z += xd[i * 4 + 2] + bv.z; x.w += xd[i * 4 + 3] + bv.w;
        *reinterpret_cast<float4*>(xr) = x;
      }
    }
    __syncthreads();
  }

  layernorm_x(sm.xs, sm.xnT, sm.scratch, tid);
  gemm32(wqf, 128, sm.xnT, sm.wbuf, tid, acc);
  {
    const float4 bv = *reinterpret_cast<const float4*>(bqf + col0);
#pragma unroll
    for (int i = 0; i < 4; ++i) {
      float4 o;
      o.x = acc[i * 4 + 0] + bv.x; o.y = acc[i * 4 + 1] + bv.y;
      o.z = acc[i * 4 + 2] + bv.z; o.w = acc[i * 4 + 3] + bv.w;
      *reinterpret_cast<float4*>(sm.outb + (row0 + i) * OB_S + col0) = o;
    }
  }
  gemm96<false>(wcf, 128, sm.ctxT, sm.wbuf, sm.kvb, bcf, nullptr, tid);
  __syncthreads();
  {
    const int px = tid >> 3, sub = tid & 7;
    const int lr = (((px >> 3) >> 1) << 2) | ((px & 7) >> 1);
    const float* qrow = sm.outb + px * OB_S;
    {
      const float* crow = sm.kvb + (lr * 9 + sub) * KV_S;
      float s = 0.f;
#pragma unroll 8
      for (int c = 0; c < 128; c += 4) {
        const float4 qv = *reinterpret_cast<const float4*>(qrow + c);
        const float4 cv = *reinterpret_cast<const float4*>(crow + c);
        s += qv.x * cv.x + qv.y * cv.y + qv.z * cv.z + qv.w * cv.w;
      }
      sm.scratch[SC_LG + px * 12 + sub] = s;
    }
    if (sub == 0) {
      const float* crow = sm.kvb + (lr * 9 + 8) * KV_S;
      float s = 0.f;
#pragma unroll 8
      for (int c = 0; c < 128; c += 4) {
        const float4 qv = *reinterpret_cast<const float4*>(qrow + c);
        const float4 cv = *reinterpret_cast<const float4*>(crow + c);
        s += qv.x * cv.x + qv.y * cv.y + qv.z * cv.z + qv.w * cv.w;
      }
      sm.scratch[SC_LG + px * 12 + 8] = s;
    }
  }
  __syncthreads();
  if (tid < 32) {
    const int px = tid;
    const int hu = hu0 + (px >> 3), wu = wu0 + (px & 7);
    float lg[9], mx = -1e30f;
#pragma unroll
    for (int kk = 0; kk < 9; ++kk) {
      lg[kk] = sm.scratch[SC_LG + px * 12 + kk] * 0.08838834764831845f;
      mx = fmaxf(mx, lg[kk]);
    }
    float sum = 0.f;
#pragma unroll
    for (int kk = 0; kk < 9; ++kk) { lg[kk] = __expf(lg[kk] - mx); sum += lg[kk]; }
    const float inv = 1.f / sum;
#pragma unroll
    for (int kk = 0; kk < 9; ++kk)
      out[((bz * 9 + kk) * HuC + hu) * WuC + wu] = lg[kk] * inv;
  }
}

// ======================= MFMA path (v5) =======================
// 256 thr / 32 px / 2 blocks/CU. Wave = 2 col-tiles x all rows (B traffic halved
// on 32-row gemms, no duplicate fragments). All B loads software-pipelined one
// segment ahead. Softmax split across all 256 threads.

constexpr int PANEL = 16384;              // u16 per 128x128 panel, [n][k] layout
constexpr int N_PANELS = 26;
constexpr size_t WS_NEEDED = (size_t)N_PANELS * PANEL * 2 + 2048;
constexpr int CBS = 136;                  // bf16 LDS row stride
constexpr int XTS = 132;                  // fp32 temp stride

constexpr int MSC_ATT = 0;                // 1152: attn probs [px][h][9]; patch partials; final logits
constexpr int MSC_LN  = 1152;             // 256: LN partials [2][px][4]
constexpr int MSC_ST  = 1408;             // 48: patch stats
constexpr int MSC_N   = 1472;

typedef __attribute__((ext_vector_type(8))) short bf16x8;
typedef __attribute__((ext_vector_type(4))) float f32x4;
typedef __attribute__((ext_vector_type(8))) unsigned short u16x8;

struct alignas(16) SmemM {
  unsigned short ctxn[80 * CBS];    // 21760 B; alias xtmp f32[32*132]
  unsigned short kvb[80 * CBS];     // 21760 B; alias patch f32[24*132]
  unsigned short xn[32 * CBS];      //  8704 B
  unsigned short hb[32 * CBS];      //  8704 B
  unsigned short outb[32 * CBS];    //  8704 B
  float scratch[MSC_N];             //  5888 B
};
static_assert(sizeof(SmemM) <= 80 * 1024, "LDS budget (need 2 blocks/CU)");

__global__ void prep_weights(
    const float* __restrict__ nc_w, const float* __restrict__ nc_b,
    const float* __restrict__ wq, const float* __restrict__ wkv,
    const float* __restrict__ bkv,
    const float* __restrict__ wo, const float* __restrict__ w1,
    const float* __restrict__ w2, const float* __restrict__ wqf,
    const float* __restrict__ wcf,
    unsigned short* __restrict__ wsp, float* __restrict__ wsb) {
  const int b = blockIdx.x;
  const int t = threadIdx.x;
  if (b >= 104) {  // adjusted kv bias: b' = bkv + nc_b @ wkv
    const int l = b - 104;
    float acc = bkv[l * 256 + t];
    for (int k = 0; k < 128; ++k)
      acc += nc_b[l * 128 + k] * wkv[l * 32768 + k * 256 + t];
    wsb[l * 256 + t] = acc;
    return;
  }
  const int pid = b >> 2, qtr = b & 3;
  const float* src = wqf; int N = 128, koff = 0, noff = 0;
  const float* sc = nullptr;
  if (pid < 24) {
    const int l = pid / 12, loc = pid % 12;
    if (loc == 0)      { src = wq + l * 16384;  N = 128; }
    else if (loc == 1) { src = wkv + l * 32768; N = 256; sc = nc_w + l * 128; }
    else if (loc == 2) { src = wkv + l * 32768; N = 256; noff = 128; sc = nc_w + l * 128; }
    else if (loc == 3) { src = wo + l * 16384;  N = 128; }
    else if (loc < 8)  { src = w1 + l * 65536;  N = 512; noff = (loc - 4) * 128; }
    else               { src = w2 + l * 65536;  N = 128; koff = (loc - 8) * 128; }
  } else if (pid == 25) { src = wcf; }
  unsigned short* dst = wsp + pid * PANEL;
#pragma unroll
  for (int p = 0; p < 2; ++p) {
    const int e = t + p * 256;
    const int n = e & 127;
    const int kg = e >> 7;
    const int k0 = qtr * 32 + kg * 8;
    unsigned short tmp[8];
#pragma unroll
    for (int i = 0; i < 8; ++i) {
      const float s = sc ? sc[k0 + i] : 1.f;
      tmp[i] = f2bf(src[(k0 + i + koff) * N + noff + n] * s);
    }
    *reinterpret_cast<u16x8*>(dst + n * 128 + k0) = *reinterpret_cast<u16x8*>(tmp);
  }
}

// load 2 col-tiles x 4 k-slices of B fragments (tiles 2*wave, 2*wave+1)
__device__ __forceinline__ void load_b8(const unsigned short* __restrict__ W,
                                        bf16x8 b[2][4], int nl, int q8, int w2t) {
#pragma unroll
  for (int t = 0; t < 2; ++t)
#pragma unroll
    for (int ks = 0; ks < 4; ++ks)
      b[t][ks] = *reinterpret_cast<const bf16x8*>(
          W + ((w2t + t) * 16 + nl) * 128 + ks * 32 + q8);
}

// 32x128 @ 128x(2 tiles): acc[rt*2+t], both row tiles
__device__ __forceinline__ void mfma32v(const unsigned short* A, const bf16x8 b[2][4],
                                        f32x4 acc[4], int nl, int q8, bool init) {
  if (init) {
#pragma unroll
    for (int i = 0; i < 4; ++i) acc[i] = (f32x4){0.f, 0.f, 0.f, 0.f};
  }
#pragma unroll
  for (int ks = 0; ks < 4; ++ks) {
    const bf16x8 a0 = *reinterpret_cast<const bf16x8*>(A + nl * CBS + ks * 32 + q8);
    const bf16x8 a1 = *reinterpret_cast<const bf16x8*>(A + (16 + nl) * CBS + ks * 32 + q8);
    acc[0] = __builtin_amdgcn_mfma_f32_16x16x32_bf16(a0, b[0][ks], acc[0], 0, 0, 0);
    acc[1] = __builtin_amdgcn_mfma_f32_16x16x32_bf16(a0, b[1][ks], acc[1], 0, 0, 0);
    acc[2] = __builtin_amdgcn_mfma_f32_16x16x32_bf16(a1, b[0][ks], acc[2], 0, 0, 0);
    acc[3] = __builtin_amdgcn_mfma_f32_16x16x32_bf16(a1, b[1][ks], acc[3], 0, 0, 0);
  }
}

// 72(->80)x128 @ 128x(2 tiles): acc[rt*2+t], 5 row tiles (pad rows garbage, discarded)
__device__ __forceinline__ void mfma72v(const unsigned short* Ctx, const bf16x8 b[2][4],
                                        f32x4 acc[10], int nl, int q8) {
#pragma unroll
  for (int i = 0; i < 10; ++i) acc[i] = (f32x4){0.f, 0.f, 0.f, 0.f};
#pragma unroll
  for (int ks = 0; ks < 4; ++ks) {
    const bf16x8 b0 = b[0][ks], b1 = b[1][ks];
#pragma unroll
    for (int rt = 0; rt < 5; ++rt) {
      const bf16x8 a = *reinterpret_cast<const bf16x8*>(
          Ctx + (rt * 16 + nl) * CBS + ks * 32 + q8);
      acc[rt * 2 + 0] = __builtin_amdgcn_mfma_f32_16x16x32_bf16(a, b0, acc[rt * 2 + 0], 0, 0, 0);
      acc[rt * 2 + 1] = __builtin_amdgcn_mfma_f32_16x16x32_bf16(a, b1, acc[rt * 2 + 1], 0, 0, 0);
    }
  }
}

// LN of register-resident x (xr[rt][t][r]) -> xn bf16. 2 barriers.
__device__ __forceinline__ void ln_x(const float (&xr)[2][2][4], unsigned short* xn,
                                     float* scratch, int wave, int nl, int qm) {
#pragma unroll
  for (int rt = 0; rt < 2; ++rt)
#pragma unroll
    for (int r = 0; r < 4; ++r) {
      float s1 = xr[rt][0][r] + xr[rt][1][r];
      float s2 = xr[rt][0][r] * xr[rt][0][r] + xr[rt][1][r] * xr[rt][1][r];
#pragma unroll
      for (int m = 1; m < 16; m <<= 1) {
        s1 += __shfl_xor(s1, m, 64);
        s2 += __shfl_xor(s2, m, 64);
      }
      if (nl == 0) {
        const int px = rt * 16 + qm + r;
        scratch[MSC_LN + px * 4 + wave] = s1;
        scratch[MSC_LN + 128 + px * 4 + wave] = s2;
      }
    }
  __syncthreads();
#pragma unroll
  for (int rt = 0; rt < 2; ++rt)
#pragma unroll
    for (int r = 0; r < 4; ++r) {
      const int px = rt * 16 + qm + r;
      float a = 0.f, b = 0.f;
#pragma unroll
      for (int w = 0; w < 4; ++w) {
        a += scratch[MSC_LN + px * 4 + w];
        b += scratch[MSC_LN + 128 + px * 4 + w];
      }
      const float m = a * (1.f / 128.f);
      const float v = b * (1.f / 128.f) - m * m;
      const float rs = rsqrtf(v + 1e-6f);
#pragma unroll
      for (int t = 0; t < 2; ++t)
        xn[px * CBS + (wave * 2 + t) * 16 + nl] = f2bf((xr[rt][t][r] - m) * rs);
    }
  __syncthreads();
}

__global__ __launch_bounds__(THREADS, 2) void fused_interp_mfma(
    const float* __restrict__ fm, const float* __restrict__ fmu,
    const float* __restrict__ bq, const float* __restrict__ bo,
    const float* __restrict__ b1, const float* __restrict__ b2,
    const float* __restrict__ bqf, const float* __restrict__ bcf,
    const unsigned short* __restrict__ wsp, const float* __restrict__ wsb,
    float* __restrict__ out) {
  __shared__ SmemM sm;
  const int tid = threadIdx.x;
  const int bx = blockIdx.x, by = blockIdx.y, bz = blockIdx.z;
  const int lh0 = by * 2, lw0 = bx * 4;
  const int hu0 = by * 4, wu0 = bx * 8;

  const int lane = tid & 63;
  const int wave = tid >> 6;            // 0..3
  const int nl = lane & 15;
  const int q8 = (lane >> 4) * 8;
  const int qm = (lane >> 4) * 4;
  const int w2t = wave * 2;             // this wave's 2 col tiles / stripes

  // ---- phase 0a: x tile -> xtmp (float2 coalesced), then registers ----
  {
    float* xtmp = reinterpret_cast<float*>(sm.ctxn);
#pragma unroll
    for (int p = 0; p < 8; ++p) {
      const int e = tid + p * THREADS;   // 0..2047
      const int pe = e & 15;             // pair id: hu = pe>>2, wu-pair = pe&3
      const int c = e >> 4;              // 0..127
      const int hu = hu0 + (pe >> 2);
      const int wu = wu0 + (pe & 3) * 2;
      const float2 v = *reinterpret_cast<const float2*>(
          &fmu[((bz * 128 + c) * HuC + hu) * WuC + wu]);
      const int px = (pe >> 2) * 8 + (pe & 3) * 2;
      xtmp[px * XTS + c] = v.x;
      xtmp[(px + 1) * XTS + c] = v.y;
    }
  }
  __syncthreads();
  float xr[2][2][4];
  {
    const float* xtmp = reinterpret_cast<const float*>(sm.ctxn);
#pragma unroll
    for (int rt = 0; rt < 2; ++rt)
#pragma unroll
      for (int t = 0; t < 2; ++t)
#pragma unroll
        for (int r = 0; r < 4; ++r)
          xr[rt][t][r] = xtmp[(rt * 16 + qm + r) * XTS + (w2t + t) * 16 + nl];
  }
  __syncthreads();

  // prefetch layer-0 q/k panels + biases (in flight during phase 0b)
  bf16x8 Bq[2][4], Bk[2][4], Bv[2][4], Bo[2][4], B1[2][4], B2[2][4];
  load_b8(wsp + 0 * PANEL, Bq, nl, q8, w2t);
  load_b8(wsp + 1 * PANEL, Bk, nl, q8, w2t);

  // ---- phase 0b: patch (4 x 6 low-res px, edge-clamped) + context LN ----
  {
    float* patch = reinterpret_cast<float*>(sm.kvb);
#pragma unroll
    for (int p = 0; p < 12; ++p) {
      const int e = tid + p * THREADS;  // 0..3071
      const int c = e / 24;
      const int rem = e - c * 24;
      const int hs_i = rem / 6;
      const int ws_i = rem - hs_i * 6;
      int hd = lh0 - 1 + hs_i; hd = hd < 0 ? 0 : (hd > HdC - 1 ? HdC - 1 : hd);
      int wd = lw0 - 1 + ws_i; wd = wd < 0 ? 0 : (wd > WdC - 1 ? WdC - 1 : wd);
      patch[(hs_i * 6 + ws_i) * XTS + c] = fm[((bz * 128 + c) * HdC + hd) * WdC + wd];
    }
  }
  __syncthreads();
  {
    const float* patch = reinterpret_cast<const float*>(sm.kvb);
    if (tid < 192) {
      const int pp = tid >> 3, part = tid & 7;
      float s1 = 0.f, s2 = 0.f;
#pragma unroll
      for (int i = 0; i < 16; ++i) {
        const float v = patch[pp * XTS + part * 16 + i];
        s1 += v; s2 += v * v;
      }
      sm.scratch[MSC_ATT + tid * 2 + 0] = s1;
      sm.scratch[MSC_ATT + tid * 2 + 1] = s2;
    }
    __syncthreads();
    if (tid < 24) {
      float a = 0.f, b = 0.f;
#pragma unroll
      for (int g = 0; g < 8; ++g) {
        a += sm.scratch[MSC_ATT + (tid * 8 + g) * 2 + 0];
        b += sm.scratch[MSC_ATT + (tid * 8 + g) * 2 + 1];
      }
      const float m = a * (1.f / 128.f);
      const float v = b * (1.f / 128.f) - m * m;
      sm.scratch[MSC_ST + tid * 2 + 0] = m;
      sm.scratch[MSC_ST + tid * 2 + 1] = rsqrtf(v + 1e-6f);
    }
    __syncthreads();
#pragma unroll
    for (int p = 0; p < 5; ++p) {
      const int e = tid + p * THREADS;
      if (e < 1152) {
        const int r = e >> 4, cg = e & 15;
        const int lr = r / 9;
        const int kk = r - lr * 9;
        const int ki = kk / 3, kj = kk - ki * 3;
        const int pp = ((lr >> 2) + ki) * 6 + (lr & 3) + kj;
        const float m = sm.scratch[MSC_ST + pp * 2 + 0];
        const float rs = sm.scratch[MSC_ST + pp * 2 + 1];
        unsigned short tmp[8];
#pragma unroll
        for (int j = 0; j < 8; ++j)
          tmp[j] = f2bf((patch[pp * XTS + cg * 8 + j] - m) * rs);
        *reinterpret_cast<u16x8*>(sm.ctxn + r * CBS + cg * 8) = *reinterpret_cast<u16x8*>(tmp);
      }
    }
  }
  __syncthreads();  // ctxn rows 0..71 ready (72..79 garbage: harmless, outputs discarded)

  f32x4 acc4[4];
  f32x4 acc10[10];

  for (int l = 0; l < 2; ++l) {
    const unsigned short* P = wsp + (l * 12) * PANEL;

    // preload biases for this layer (latency hidden by ln_x)
    float kb[2], vb[2], bqr[2], bor[2], b2r[2], b1r[4][2];
#pragma unroll
    for (int t = 0; t < 2; ++t) {
      const int n = (w2t + t) * 16 + nl;
      kb[t] = wsb[l * 256 + n];
      vb[t] = wsb[l * 256 + 128 + n];
      bqr[t] = bq[l * 128 + n];
      bor[t] = bo[l * 128 + n];
      b2r[t] = b2[l * 128 + n];
#pragma unroll
      for (int cc = 0; cc < 4; ++cc) b1r[cc][t] = b1[l * 512 + cc * 128 + n];
    }

    ln_x(xr, sm.xn, sm.scratch, wave, nl, qm);

    // q = LN(x) @ wq + bq -> outb bf16   (Bq prefetched)
    mfma32v(sm.xn, Bq, acc4, nl, q8, true);
#pragma unroll
    for (int rt = 0; rt < 2; ++rt)
#pragma unroll
      for (int t = 0; t < 2; ++t) {
        const int n = (w2t + t) * 16 + nl;
#pragma unroll
        for (int r = 0; r < 4; ++r)
          sm.outb[(rt * 16 + qm + r) * CBS + n] = f2bf(acc4[rt * 2 + t][r] + bqr[t]);
      }
    // k = ctx_n @ wkv_k + b' -> kvb bf16   (Bk prefetched)
    mfma72v(sm.ctxn, Bk, acc10, nl, q8);
    load_b8(P + 2 * PANEL, Bv, nl, q8, w2t);  // prefetch v panel
#pragma unroll
    for (int t = 0; t < 2; ++t) {
      const int n = (w2t + t) * 16 + nl;
#pragma unroll
      for (int rt = 0; rt < 5; ++rt)
#pragma unroll
        for (int r = 0; r < 4; ++r) {
          const int row = rt * 16 + qm + r;
          if (row < 72) sm.kvb[row * CBS + n] = f2bf(acc10[rt * 2 + t][r] + kb[t]);
        }
    }
    __syncthreads();  // q, k visible

    // v compute (store deferred until k reads done)
    mfma72v(sm.ctxn, Bv, acc10, nl, q8);
    load_b8(P + 3 * PANEL, Bo, nl, q8, w2t);  // prefetch wo panel

    // attention softmax: all 256 threads, 2 per (px,h), kk split 5/4
    {
      const int u = tid >> 1, sub = tid & 1;
      const int px = u >> 2, h = u & 3;
      const int lr = (((px >> 3) >> 1) << 2) | ((px & 7) >> 1);
      const unsigned short* qrow = sm.outb + px * CBS + h * 32;
      float qf[32];
#pragma unroll
      for (int c8 = 0; c8 < 4; ++c8) {
        const u16x8 qa = *reinterpret_cast<const u16x8*>(qrow + c8 * 8);
#pragma unroll
        for (int j = 0; j < 8; ++j) qf[c8 * 8 + j] = bf2f(qa[j]);
      }
      const int base = sub ? 5 : 0;
      const int cnt = sub ? 4 : 5;
      float mine[5];
#pragma unroll
      for (int i = 0; i < 5; ++i) {
        float s = 0.f;
        if (i < cnt) {
          const unsigned short* krow = sm.kvb + (lr * 9 + base + i) * CBS + h * 32;
#pragma unroll
          for (int c8 = 0; c8 < 4; ++c8) {
            const u16x8 ka = *reinterpret_cast<const u16x8*>(krow + c8 * 8);
#pragma unroll
            for (int j = 0; j < 8; ++j) s += qf[c8 * 8 + j] * bf2f(ka[j]);
          }
          s *= 0.17677669529663687f;  // 1/sqrt(32)
        }
        mine[i] = s;
      }
      float other[5];
#pragma unroll
      for (int i = 0; i < 5; ++i) other[i] = __shfl_xor(mine[i], 1, 64);
      float lg[9];
#pragma unroll
      for (int j = 0; j < 5; ++j) lg[j] = sub ? other[j] : mine[j];
#pragma unroll
      for (int j = 0; j < 4; ++j) lg[5 + j] = sub ? mine[j] : other[j];
      float mx = -1e30f;
#pragma unroll
      for (int kk = 0; kk < 9; ++kk) mx = fmaxf(mx, lg[kk]);
      float sum = 0.f;
#pragma unroll
      for (int kk = 0; kk < 9; ++kk) { lg[kk] = __expf(lg[kk] - mx); sum += lg[kk]; }
      const float inv = 1.f / sum;
#pragma unroll
      for (int j = 0; j < 5; ++j)
        if (j < cnt) sm.scratch[MSC_ATT + (px * 4 + h) * 9 + base + j] = lg[base + j] * inv;
    }
    __syncthreads();  // probs written; k reads done

    // v store
#pragma unroll
    for (int t = 0; t < 2; ++t) {
      const int n = (w2t + t) * 16 + nl;
#pragma unroll
      for (int rt = 0; rt < 5; ++rt)
#pragma unroll
        for (int r = 0; r < 4; ++r) {
          const int row = rt * 16 + qm + r;
          if (row < 72) sm.kvb[row * CBS + n] = f2bf(acc10[rt * 2 + t][r] + vb[t]);
        }
    }
    __syncthreads();  // v visible

    // o = attn @ v -> xn (bf16, A rows)
    {
      const int px = tid >> 3, cg = tid & 7, c0 = cg * 16;
      const int lr = (((px >> 3) >> 1) << 2) | ((px & 7) >> 1);
      const float* aw = sm.scratch + MSC_ATT + (px * 4 + (cg >> 1)) * 9;
      float o[16];
#pragma unroll
      for (int j = 0; j < 16; ++j) o[j] = 0.f;
#pragma unroll
      for (int kk = 0; kk < 9; ++kk) {
        const float a = aw[kk];
        const unsigned short* vrow = sm.kvb + (lr * 9 + kk) * CBS + c0;
        const u16x8 v0 = *reinterpret_cast<const u16x8*>(vrow);
        const u16x8 v1 = *reinterpret_cast<const u16x8*>(vrow + 8);
#pragma unroll
        for (int j = 0; j < 8; ++j) {
          o[j] += a * bf2f(v0[j]);
          o[8 + j] += a * bf2f(v1[j]);
        }
      }
      unsigned short tmp[16];
#pragma unroll
      for (int j = 0; j < 16; ++j) tmp[j] = f2bf(o[j]);
      *reinterpret_cast<u16x8*>(sm.xn + px * CBS + c0) = *reinterpret_cast<u16x8*>(tmp);
      *reinterpret_cast<u16x8*>(sm.xn + px * CBS + c0 + 8) = *reinterpret_cast<u16x8*>(tmp + 8);
    }
    load_b8(P + 4 * PANEL, B1, nl, q8, w2t);  // prefetch w1 chunk 0
    __syncthreads();  // xn(o) visible

    // x += o @ wo + bo   (Bo prefetched)
    mfma32v(sm.xn, Bo, acc4, nl, q8, true);
#pragma unroll
    for (int rt = 0; rt < 2; ++rt)
#pragma unroll
      for (int t = 0; t < 2; ++t)
#pragma unroll
        for (int r = 0; r < 4; ++r)
          xr[rt][t][r] += acc4[rt * 2 + t][r] + bor[t];

    // MLP with w1/w2 pipelined
    ln_x(xr, sm.xn, sm.scratch, wave, nl, qm);
    f32x4 xd[4];
    for (int cc = 0; cc < 4; ++cc) {
      mfma32v(sm.xn, B1, acc4, nl, q8, true);
      load_b8(P + (8 + cc) * PANEL, B2, nl, q8, w2t);  // prefetch w2 chunk cc
#pragma unroll
      for (int rt = 0; rt < 2; ++rt)
#pragma unroll
        for (int t = 0; t < 2; ++t) {
          const int n = (w2t + t) * 16 + nl;
#pragma unroll
          for (int r = 0; r < 4; ++r)
            sm.hb[(rt * 16 + qm + r) * CBS + n] =
                f2bf(gelu_tanh(acc4[rt * 2 + t][r] + b1r[cc][t]));
        }
      __syncthreads();  // hb visible
      if (cc < 3) load_b8(P + (5 + cc) * PANEL, B1, nl, q8, w2t);  // prefetch next w1
      mfma32v(sm.hb, B2, xd, nl, q8, cc == 0);
      if (cc < 3) __syncthreads();  // hb reads done before next overwrite
    }
#pragma unroll
    for (int rt = 0; rt < 2; ++rt)
#pragma unroll
      for (int t = 0; t < 2; ++t)
#pragma unroll
        for (int r = 0; r < 4; ++r)
          xr[rt][t][r] += xd[rt * 2 + t][r] + b2r[t];

    // prefetch next layer's (or final's) q/k panels during residual update
    if (l == 0) {
      load_b8(wsp + 12 * PANEL, Bq, nl, q8, w2t);
      load_b8(wsp + 13 * PANEL, Bk, nl, q8, w2t);
    } else {
      load_b8(wsp + 24 * PANEL, Bq, nl, q8, w2t);  // wqf
      load_b8(wsp + 25 * PANEL, Bk, nl, q8, w2t);  // wcf
    }
  }  // layers

  // ---- final: xq = LN(x)@wqf+bqf ; ctxp = LN(ctx)@wcf+bcf ; softmax over 9 ----
  float bqfr[2], bcfr[2];
#pragma unroll
  for (int t = 0; t < 2; ++t) {
    const int n = (w2t + t) * 16 + nl;
    bqfr[t] = bqf[n];
    bcfr[t] = bcf[n];
  }
  ln_x(xr, sm.xn, sm.scratch, wave, nl, qm);
  mfma32v(sm.xn, Bq, acc4, nl, q8, true);
#pragma unroll
  for (int rt = 0; rt < 2; ++rt)
#pragma unroll
    for (int t = 0; t < 2; ++t) {
      const int n = (w2t + t) * 16 + nl;
#pragma unroll
      for (int r = 0; r < 4; ++r)
        sm.outb[(rt * 16 + qm + r) * CBS + n] = f2bf(acc4[rt * 2 + t][r] + bqfr[t]);
    }
  mfma72v(sm.ctxn, Bk, acc10, nl, q8);
#pragma unroll
  for (int t = 0; t < 2; ++t) {
    const int n = (w2t + t) * 16 + nl;
#pragma unroll
    for (int rt = 0; rt < 5; ++rt)
#pragma unroll
      for (int r = 0; r < 4; ++r) {
        const int row = rt * 16 + qm + r;
        if (row < 72) sm.kvb[row * CBS + n] = f2bf(acc10[rt * 2 + t][r] + bcfr[t]);
      }
  }
  __syncthreads();
  {
    const int px = tid >> 3, sub = tid & 7;
    const int lr = (((px >> 3) >> 1) << 2) | ((px & 7) >> 1);
    const unsigned short* qrow = sm.outb + px * CBS;
#pragma unroll
    for (int which = 0; which < 2; ++which) {
      if (which == 1 && sub != 0) break;
      const int kk = (which == 0) ? sub : 8;
      const unsigned short* crow = sm.kvb + (lr * 9 + kk) * CBS;
      float s = 0.f;
#pragma unroll
      for (int c8 = 0; c8 < 16; ++c8) {
        const u16x8 qa = *reinterpret_cast<const u16x8*>(qrow + c8 * 8);
        const u16x8 ca = *reinterpret_cast<const u16x8*>(crow + c8 * 8);
#pragma unroll
        for (int j = 0; j < 8; ++j) s += bf2f(qa[j]) * bf2f(ca[j]);
      }
      sm.scratch[MSC_ATT + px * 12 + kk] = s;
    }
  }
  __syncthreads();
  if (tid < 32) {
    const int px = tid;
    const int hu = hu0 + (px >> 3), wu = wu0 + (px & 7);
    float lg[9], mx = -1e30f;
#pragma unroll
    for (int kk = 0; kk < 9; ++kk) {
      lg[kk] = sm.scratch[MSC_ATT + px * 12 + kk] * 0.08838834764831845f;
      mx = fmaxf(mx, lg[kk]);
    }
    float sum = 0.f;
#pragma unroll
    for (int kk = 0; kk < 9; ++kk) { lg[kk] = __expf(lg[kk] - mx); sum += lg[kk]; }
    const float inv = 1.f / sum;
#pragma unroll
    for (int kk = 0; kk < 9; ++kk)
      out[((bz * 9 + kk) * HuC + hu) * WuC + wu] = lg[kk] * inv;
  }
}

}  // namespace

extern "C" void kernel_launch(void* const* d_in, const int* in_sizes, int n_in,
                              void* d_out, int out_size, void* d_ws, size_t ws_size,
                              hipStream_t stream) {
  const float* fm   = (const float*)d_in[0];
  const float* fmu  = (const float*)d_in[1];
  const float* nc_w = (const float*)d_in[2];
  const float* nc_b = (const float*)d_in[3];
  const float* wq   = (const float*)d_in[4];
  const float* bq   = (const float*)d_in[5];
  const float* wkv  = (const float*)d_in[6];
  const float* bkv  = (const float*)d_in[7];
  const float* wo   = (const float*)d_in[8];
  const float* bo   = (const float*)d_in[9];
  const float* w1   = (const float*)d_in[10];
  const float* b1   = (const float*)d_in[11];
  const float* w2   = (const float*)d_in[12];
  const float* b2   = (const float*)d_in[13];
  const float* wqf  = (const float*)d_in[14];
  const float* bqf  = (const float*)d_in[15];
  const float* wcf  = (const float*)d_in[16];
  const float* bcf  = (const float*)d_in[17];
  float* out = (float*)d_out;

  dim3 grid(24, 32, 2);  // 4x8-pixel tiles
  if (ws_size >= WS_NEEDED) {
    unsigned short* wsp = (unsigned short*)d_ws;
    float* wsb = (float*)((char*)d_ws + (size_t)N_PANELS * PANEL * 2);
    prep_weights<<<dim3(106), dim3(256), 0, stream>>>(
        nc_w, nc_b, wq, wkv, bkv, wo, w1, w2, wqf, wcf, wsp, wsb);
    fused_interp_mfma<<<grid, dim3(THREADS), 0, stream>>>(
        fm, fmu, bq, bo, b1, b2, bqf, bcf, wsp, wsb, out);
  } else {
    fused_interp_kernel<<<grid, dim3(THREADS), 0, stream>>>(
        fm, fmu, nc_w, nc_b, wq, bq, wkv, bkv, wo, bo, w1, b1, w2, b2,
        wqf, bqf, wcf, bcf, out);
  }
}